// Round 1
// baseline (993.568 us; speedup 1.0000x reference)
//
#include <hip/hip_runtime.h>

// TMMixer: B=64, T=64, S=256, DIM=768, H=12, HD=64, RANK=64
// Pipeline (all bf16 MFMA GEMMs, f32 accumulation):
//  1. transpose weights -> bf16 (Bt layout: [n][k])
//  2. LN1(z_rgb,z_dte,x_rgb,x_dte) -> bf16
//  3. q/k/v projections (6 GEMMs, cross-stream kv)
//  4. attention per (s,b,h): softmax + PV + affinity atomicAdd
//  5. lora-z down (gelu), wo GEMM (+z residual), lora-z up (accum)
//  6. fusion: colmax -> num=exp(aff-12)*mask -> apply
//  7. LN2 + mlp lora (gelu down, accum up) into d_out

typedef __bf16 bf8_t __attribute__((ext_vector_type(8)));
typedef float f4_t __attribute__((ext_vector_type(4)));
typedef unsigned short u16;

__device__ __forceinline__ float bf2f(u16 h) {
    return __uint_as_float(((unsigned int)h) << 16);
}
__device__ __forceinline__ u16 f2bf(float f) {
    unsigned int u = __float_as_uint(f);
    u += 0x7fffu + ((u >> 16) & 1u);
    return (u16)(u >> 16);
}
__device__ __forceinline__ float gelu_tanh(float x) {
    float t = tanhf(0.7978845608028654f * (x + 0.044715f * x * x * x));
    return 0.5f * x * (1.0f + t);
}

// ---------------- weight prep: dst[C][R] = bf16(src[R][C]) ----------------
__global__ __launch_bounds__(256) void transpose_to_bf16(
    const float* __restrict__ src, u16* __restrict__ dst, int R, int C) {
    int idx = blockIdx.x * 256 + threadIdx.x;
    if (idx >= R * C) return;
    int c = idx / R, r = idx - c * R;
    dst[idx] = f2bf(src[(size_t)r * C + c]);
}

// ---------------- LN1: 40960 rows; z rows then x rows per stream ----------
__global__ __launch_bounds__(256) void ln1_kernel(
    const float* __restrict__ x0, const float* __restrict__ x1,
    const float* __restrict__ w, const float* __restrict__ b,
    u16* __restrict__ lnZ, u16* __restrict__ lnX) {
    int rid = blockIdx.x;
    int s = rid / 20480;
    int r2 = rid - s * 20480;
    const float* srcBase = (s == 0) ? x0 : x1;
    const float* src; u16* dst;
    if (r2 < 4096) {
        int bb = r2 >> 6, t = r2 & 63;
        src = srcBase + ((size_t)(bb * 320 + t)) * 768;
        dst = lnZ + ((size_t)(s * 4096 + r2)) * 768;
    } else {
        int rx = r2 - 4096;
        int bb = rx >> 8, sx = rx & 255;
        src = srcBase + ((size_t)(bb * 320 + 64 + sx)) * 768;
        dst = lnX + ((size_t)(s * 16384 + rx)) * 768;
    }
    int tid = threadIdx.x;
    float xv0 = src[tid], xv1 = src[tid + 256], xv2 = src[tid + 512];
    float s1 = xv0 + xv1 + xv2;
    float s2 = xv0 * xv0 + xv1 * xv1 + xv2 * xv2;
    #pragma unroll
    for (int o = 1; o < 64; o <<= 1) { s1 += __shfl_xor(s1, o); s2 += __shfl_xor(s2, o); }
    __shared__ float red[2][4];
    int wv = tid >> 6;
    if ((tid & 63) == 0) { red[0][wv] = s1; red[1][wv] = s2; }
    __syncthreads();
    s1 = red[0][0] + red[0][1] + red[0][2] + red[0][3];
    s2 = red[1][0] + red[1][1] + red[1][2] + red[1][3];
    float mean = s1 * (1.0f / 768.0f);
    float var = s2 * (1.0f / 768.0f) - mean * mean;
    float rstd = rsqrtf(var + 1e-5f);
    dst[tid]       = f2bf((xv0 - mean) * rstd * w[tid]       + b[tid]);
    dst[tid + 256] = f2bf((xv1 - mean) * rstd * w[tid + 256] + b[tid + 256]);
    dst[tid + 512] = f2bf((xv2 - mean) * rstd * w[tid + 512] + b[tid + 512]);
}

// ---------------- LN2: contiguous rows from d_out ----------
__global__ __launch_bounds__(256) void ln2_kernel(
    const float* __restrict__ src0, const float* __restrict__ w,
    const float* __restrict__ b, u16* __restrict__ dst0) {
    int rid = blockIdx.x;
    const float* src = src0 + (size_t)rid * 768;
    u16* dst = dst0 + (size_t)rid * 768;
    int tid = threadIdx.x;
    float xv0 = src[tid], xv1 = src[tid + 256], xv2 = src[tid + 512];
    float s1 = xv0 + xv1 + xv2;
    float s2 = xv0 * xv0 + xv1 * xv1 + xv2 * xv2;
    #pragma unroll
    for (int o = 1; o < 64; o <<= 1) { s1 += __shfl_xor(s1, o); s2 += __shfl_xor(s2, o); }
    __shared__ float red[2][4];
    int wv = tid >> 6;
    if ((tid & 63) == 0) { red[0][wv] = s1; red[1][wv] = s2; }
    __syncthreads();
    s1 = red[0][0] + red[0][1] + red[0][2] + red[0][3];
    s2 = red[1][0] + red[1][1] + red[1][2] + red[1][3];
    float mean = s1 * (1.0f / 768.0f);
    float var = s2 * (1.0f / 768.0f) - mean * mean;
    float rstd = rsqrtf(var + 1e-5f);
    dst[tid]       = f2bf((xv0 - mean) * rstd * w[tid]       + b[tid]);
    dst[tid + 256] = f2bf((xv1 - mean) * rstd * w[tid + 256] + b[tid + 256]);
    dst[tid + 512] = f2bf((xv2 - mean) * rstd * w[tid + 512] + b[tid + 512]);
}

// ---------------- MFMA GEMM: C = A(MxK) * Bt(NxK)^T, epilogues -----------
enum { EPI_BF16 = 0, EPI_RESID = 1, EPI_GELU = 2, EPI_ACCUM = 3 };

template <int BM, int BN, int WR, int WC, int EPI>
__global__ __launch_bounds__(WR * WC * 64, 1) void gemm_bt(
    const u16* __restrict__ A, const u16* __restrict__ Bt,
    int M, int N, int K,
    float* __restrict__ Cf, u16* __restrict__ Cbf,
    const float* __restrict__ resid) {
    constexpr int THREADS = WR * WC * 64;
    constexpr int BK = 64;
    __shared__ alignas(16) u16 As[BM][BK + 8];
    __shared__ alignas(16) u16 Bs[BN][BK + 8];

    const int tid = threadIdx.x;
    const int lane = tid & 63;
    const int w = tid >> 6;
    const int wr = w / WC, wc = w % WC;
    const int r = lane & 15, g = lane >> 4;
    const int brow = blockIdx.y * BM;
    const int bcol = blockIdx.x * BN;

    f4_t acc[4][4];
    f4_t zero = {0.f, 0.f, 0.f, 0.f};
    #pragma unroll
    for (int m = 0; m < 4; m++)
        #pragma unroll
        for (int n = 0; n < 4; n++) acc[m][n] = zero;

    for (int k0 = 0; k0 < K; k0 += BK) {
        constexpr int CA = BM * BK / 8;
        #pragma unroll
        for (int i = 0; i < CA / THREADS; i++) {
            int c = tid + THREADS * i;
            int row = c >> 3, kc = (c & 7) * 8;
            bf8_t val = *reinterpret_cast<const bf8_t*>(A + (size_t)(brow + row) * K + k0 + kc);
            *reinterpret_cast<bf8_t*>(&As[row][kc]) = val;
        }
        constexpr int CB = BN * BK / 8;
        #pragma unroll
        for (int i = 0; i < CB / THREADS; i++) {
            int c = tid + THREADS * i;
            int row = c >> 3, kc = (c & 7) * 8;
            bf8_t val = *reinterpret_cast<const bf8_t*>(Bt + (size_t)(bcol + row) * K + k0 + kc);
            *reinterpret_cast<bf8_t*>(&Bs[row][kc]) = val;
        }
        __syncthreads();
        #pragma unroll
        for (int ks = 0; ks < BK; ks += 32) {
            bf8_t af[4], bfr[4];
            #pragma unroll
            for (int m = 0; m < 4; m++)
                af[m] = *reinterpret_cast<const bf8_t*>(&As[wr * 64 + m * 16 + r][ks + g * 8]);
            #pragma unroll
            for (int n = 0; n < 4; n++)
                bfr[n] = *reinterpret_cast<const bf8_t*>(&Bs[wc * 64 + n * 16 + r][ks + g * 8]);
            #pragma unroll
            for (int m = 0; m < 4; m++)
                #pragma unroll
                for (int n = 0; n < 4; n++)
                    acc[m][n] = __builtin_amdgcn_mfma_f32_16x16x32_bf16(af[m], bfr[n], acc[m][n], 0, 0, 0);
        }
        __syncthreads();
    }

    #pragma unroll
    for (int m = 0; m < 4; m++) {
        #pragma unroll
        for (int n = 0; n < 4; n++) {
            int col = bcol + wc * 64 + n * 16 + r;
            #pragma unroll
            for (int i = 0; i < 4; i++) {
                int row = brow + wr * 64 + m * 16 + g * 4 + i;
                float val = acc[m][n][i];
                if constexpr (EPI == EPI_BF16) {
                    Cbf[(size_t)row * N + col] = f2bf(val);
                } else if constexpr (EPI == EPI_RESID) {
                    float rs = resid[(size_t)((row >> 6) * 320 + (row & 63)) * 768 + col];
                    Cf[(size_t)row * N + col] = val + rs;
                } else if constexpr (EPI == EPI_GELU) {
                    Cbf[(size_t)row * N + col] = f2bf(gelu_tanh(val));
                } else {
                    Cf[(size_t)row * N + col] += val;
                }
            }
        }
    }
}

// ---------------- attention per (s,b,h) --------------------------------
__global__ __launch_bounds__(256, 1) void attn_kernel(
    const u16* __restrict__ q, const u16* __restrict__ k,
    const u16* __restrict__ v, u16* __restrict__ attnout,
    float* __restrict__ aff) {
    __shared__ alignas(16) u16 kp[256 * 64];  // K, then P[k][q]
    __shared__ alignas(16) u16 vs[256 * 64];
    int bid = blockIdx.x;
    int s = bid / 768;
    int rem = bid - s * 768;
    int b = rem / 12, h = rem - (rem / 12) * 12;
    int tid = threadIdx.x;

    const size_t kvbase = ((size_t)(s * 16384 + b * 256)) * 768 + h * 64;
    #pragma unroll
    for (int i = 0; i < 8; i++) {
        int c = tid + 256 * i;
        int row = c >> 3, kc = (c & 7) * 8;
        *reinterpret_cast<bf8_t*>(&kp[row * 64 + kc]) =
            *reinterpret_cast<const bf8_t*>(k + kvbase + (size_t)row * 768 + kc);
        *reinterpret_cast<bf8_t*>(&vs[row * 64 + kc]) =
            *reinterpret_cast<const bf8_t*>(v + kvbase + (size_t)row * 768 + kc);
    }
    __syncthreads();

    int qi = tid >> 2, ks = tid & 3;
    const u16* qrow = q + ((size_t)(s * 4096 + b * 64 + qi)) * 768 + h * 64;
    float lg[64];
    #pragma unroll
    for (int j = 0; j < 64; j++) lg[j] = 0.f;
    for (int d0 = 0; d0 < 64; d0 += 16) {
        bf8_t qa = *reinterpret_cast<const bf8_t*>(qrow + d0);
        bf8_t qb = *reinterpret_cast<const bf8_t*>(qrow + d0 + 8);
        float qc[16];
        #pragma unroll
        for (int i = 0; i < 8; i++) { qc[i] = (float)qa[i]; qc[8 + i] = (float)qb[i]; }
        #pragma unroll
        for (int j = 0; j < 64; j++) {
            int kk = (ks << 6) + j;
            bf8_t ka = *reinterpret_cast<const bf8_t*>(&kp[kk * 64 + d0]);
            bf8_t kb = *reinterpret_cast<const bf8_t*>(&kp[kk * 64 + d0 + 8]);
            float a = 0.f;
            #pragma unroll
            for (int i = 0; i < 8; i++) a += qc[i] * (float)ka[i] + qc[8 + i] * (float)kb[i];
            lg[j] += a;
        }
    }
    float mx = -1e30f;
    #pragma unroll
    for (int j = 0; j < 64; j++) { lg[j] *= 0.125f; mx = fmaxf(mx, lg[j]); }
    mx = fmaxf(mx, __shfl_xor(mx, 1));
    mx = fmaxf(mx, __shfl_xor(mx, 2));
    float sm = 0.f;
    #pragma unroll
    for (int j = 0; j < 64; j++) { float p = __expf(lg[j] - mx); lg[j] = p; sm += p; }
    sm += __shfl_xor(sm, 1);
    sm += __shfl_xor(sm, 2);
    float inv = 1.0f / sm;
    __syncthreads();  // done reading K
    float* affp = aff + ((size_t)(s * 64 + b)) * (256 * 64);
    #pragma unroll
    for (int j = 0; j < 64; j++) {
        int kk = (ks << 6) + j;
        float p = lg[j] * inv;
        kp[kk * 64 + qi] = f2bf(p);
        atomicAdd(&affp[kk * 64 + qi], p);
    }
    __syncthreads();

    int d0 = (tid & 3) << 4;
    float oacc[16];
    #pragma unroll
    for (int i = 0; i < 16; i++) oacc[i] = 0.f;
    for (int kk = 0; kk < 256; kk++) {
        float p = bf2f(kp[kk * 64 + qi]);
        bf8_t va = *reinterpret_cast<const bf8_t*>(&vs[kk * 64 + d0]);
        bf8_t vb = *reinterpret_cast<const bf8_t*>(&vs[kk * 64 + d0 + 8]);
        #pragma unroll
        for (int i = 0; i < 8; i++) { oacc[i] += p * (float)va[i]; oacc[8 + i] += p * (float)vb[i]; }
    }
    u16* op = attnout + ((size_t)(s * 4096 + b * 64 + qi)) * 768 + h * 64 + d0;
    #pragma unroll
    for (int i = 0; i < 16; i++) op[i] = f2bf(oacc[i]);
}

// ---------------- fusion prep: colmax, num, den ----------------
__global__ __launch_bounds__(64) void fusion_prep(float* __restrict__ aff, float* __restrict__ den) {
    int sb = blockIdx.x;  // 0..127 = s*64+b
    float* ap = aff + (size_t)sb * 256 * 64;
    int t = threadIdx.x;
    float mx = -1e30f;
    for (int kk = 0; kk < 256; kk++) mx = fmaxf(mx, ap[kk * 64 + t]);
    for (int kk = 0; kk < 256; kk++) {
        float val = ap[kk * 64 + t];
        float nu = (val == mx) ? __expf(val - 12.0f) : 0.f;
        ap[kk * 64 + t] = nu;
        float rs = nu;
        #pragma unroll
        for (int o = 1; o < 64; o <<= 1) rs += __shfl_xor(rs, o);
        if (t == 0) den[sb * 256 + kk] = 1.0f + rs;
    }
}

// ---------------- fusion apply: write all of y ----------------
__global__ __launch_bounds__(256) void fusion_apply(
    const float* __restrict__ x0, const float* __restrict__ x1,
    const float* __restrict__ fz, const float* __restrict__ aff,
    const float* __restrict__ den, float* __restrict__ out) {
    int bid = blockIdx.x;  // s*20480 + b*320 + n
    int s = bid / 20480;
    int r2 = bid - s * 20480;
    int b = r2 / 320, n = r2 - (r2 / 320) * 320;
    int tid = threadIdx.x;
    float* orow = out + (size_t)bid * 768;
    const float* fzs = fz + (size_t)s * 4096 * 768;
    if (n < 64) {
        const float* zrow = fzs + ((size_t)(b * 64 + n)) * 768;
        orow[tid] = zrow[tid];
        orow[tid + 256] = zrow[tid + 256];
        orow[tid + 512] = zrow[tid + 512];
    } else {
        int sx = n - 64;
        const float* xrow = ((s == 0) ? x0 : x1) + ((size_t)(b * 320 + n)) * 768;
        float invd = 1.0f / den[(s * 64 + b) * 256 + sx];
        __shared__ float nush[64];
        if (tid < 64) nush[tid] = aff[(((size_t)(s * 64 + b)) * 256 + sx) * 64 + tid];
        __syncthreads();
        float a0 = xrow[tid] * invd;
        float a1 = xrow[tid + 256] * invd;
        float a2 = xrow[tid + 512] * invd;
        for (int t = 0; t < 64; t++) {
            float nu = nush[t];
            if (nu != 0.f) {
                float wgt = nu * invd;
                const float* zr = fzs + ((size_t)(b * 64 + t)) * 768;
                a0 += wgt * zr[tid];
                a1 += wgt * zr[tid + 256];
                a2 += wgt * zr[tid + 512];
            }
        }
        orow[tid] = a0; orow[tid + 256] = a1; orow[tid + 512] = a2;
    }
}

extern "C" void kernel_launch(void* const* d_in, const int* in_sizes, int n_in,
                              void* d_out, int out_size, void* d_ws, size_t ws_size,
                              hipStream_t stream) {
    (void)in_sizes; (void)n_in; (void)out_size;
    const float* x0 = (const float*)d_in[0];
    const float* x1 = (const float*)d_in[1];
    const float* ln1w = (const float*)d_in[2];
    const float* ln1b = (const float*)d_in[3];
    const float* ln2w = (const float*)d_in[4];
    const float* ln2b = (const float*)d_in[5];
    const float* wq = (const float*)d_in[6];
    const float* wk = (const float*)d_in[7];
    const float* wv = (const float*)d_in[8];
    const float* wo = (const float*)d_in[9];
    const float* lora_down = (const float*)d_in[10];
    const float* lora_up = (const float*)d_in[11];
    const float* mlp_down = (const float*)d_in[12];
    const float* mlp_up = (const float*)d_in[13];
    float* out = (float*)d_out;

    char* ws = (char*)d_ws;
    size_t off = 0;
    auto alloc = [&](size_t bytes) -> char* {
        char* p = ws + off;
        off = (off + bytes + 255) & ~(size_t)255;
        return p;
    };
    u16* wtq = (u16*)alloc(768 * 768 * 2);
    u16* wtk = (u16*)alloc(768 * 768 * 2);
    u16* wtv = (u16*)alloc(768 * 768 * 2);
    u16* wto = (u16*)alloc(768 * 768 * 2);
    u16* dT  = (u16*)alloc(768 * 64 * 2);
    u16* uT  = (u16*)alloc(768 * 64 * 2);
    u16* mdT = (u16*)alloc(768 * 64 * 2);
    u16* muT = (u16*)alloc(768 * 64 * 2);
    u16* lnZ = (u16*)alloc((size_t)2 * 4096 * 768 * 2);    // region B start
    u16* lnX = (u16*)alloc((size_t)2 * 16384 * 768 * 2);   // contiguous with lnZ
    u16* qb  = (u16*)alloc((size_t)2 * 4096 * 768 * 2);    // region C (h2 aliases)
    u16* kb  = (u16*)alloc((size_t)2 * 16384 * 768 * 2);   // region D (fz aliases)
    u16* vb  = (u16*)alloc((size_t)2 * 16384 * 768 * 2);
    u16* ao  = (u16*)alloc((size_t)2 * 4096 * 768 * 2);
    float* aff = (float*)alloc((size_t)2 * 64 * 256 * 64 * 4);
    float* den = (float*)alloc((size_t)2 * 64 * 256 * 4);
    u16* h01 = (u16*)alloc((size_t)2 * 4096 * 64 * 2);
    // aliases (lifetimes disjoint by stream order):
    u16* ln2y = lnZ;               // 40960*768*2 == lnZ+lnX exactly
    u16* h2 = qb;                  // 40960*64*2  <= q region
    float* fz = (float*)kb;        // 2*4096*768*4 <= k region
    if (ws_size < off) return;     // ws too small -> leave poison (diagnosable)

    u16* lnZ0 = lnZ, *lnZ1 = lnZ + (size_t)4096 * 768;
    u16* lnX0 = lnX, *lnX1 = lnX + (size_t)16384 * 768;
    u16* q0p = qb, *q1p = qb + (size_t)4096 * 768;
    u16* k0p = kb, *k1p = kb + (size_t)16384 * 768;
    u16* v0p = vb, *v1p = vb + (size_t)16384 * 768;
    u16* ao0 = ao, *ao1 = ao + (size_t)4096 * 768;
    u16* h0 = h01, *h1 = h01 + (size_t)4096 * 64;
    float* fz0 = fz, *fz1 = fz + (size_t)4096 * 768;

    // 1. weight prep
    transpose_to_bf16<<<2304, 256, 0, stream>>>(wq, wtq, 768, 768);
    transpose_to_bf16<<<2304, 256, 0, stream>>>(wk, wtk, 768, 768);
    transpose_to_bf16<<<2304, 256, 0, stream>>>(wv, wtv, 768, 768);
    transpose_to_bf16<<<2304, 256, 0, stream>>>(wo, wto, 768, 768);
    transpose_to_bf16<<<192, 256, 0, stream>>>(lora_down, dT, 768, 64);
    transpose_to_bf16<<<192, 256, 0, stream>>>(lora_up, uT, 64, 768);
    transpose_to_bf16<<<192, 256, 0, stream>>>(mlp_down, mdT, 768, 64);
    transpose_to_bf16<<<192, 256, 0, stream>>>(mlp_up, muT, 64, 768);
    hipMemsetAsync(aff, 0, (size_t)2 * 64 * 256 * 64 * 4, stream);
    // 2. LN1
    ln1_kernel<<<40960, 256, 0, stream>>>(x0, x1, ln1w, ln1b, lnZ, lnX);
    // 3. projections (kv is cross-stream: s0 kv from x_dte=lnX1, s1 from x_rgb=lnX0)
    gemm_bt<128, 128, 2, 2, EPI_BF16><<<dim3(6, 32), 256, 0, stream>>>(lnZ0, wtq, 4096, 768, 768, nullptr, q0p, nullptr);
    gemm_bt<128, 128, 2, 2, EPI_BF16><<<dim3(6, 32), 256, 0, stream>>>(lnZ1, wtq, 4096, 768, 768, nullptr, q1p, nullptr);
    gemm_bt<128, 128, 2, 2, EPI_BF16><<<dim3(6, 128), 256, 0, stream>>>(lnX1, wtk, 16384, 768, 768, nullptr, k0p, nullptr);
    gemm_bt<128, 128, 2, 2, EPI_BF16><<<dim3(6, 128), 256, 0, stream>>>(lnX1, wtv, 16384, 768, 768, nullptr, v0p, nullptr);
    gemm_bt<128, 128, 2, 2, EPI_BF16><<<dim3(6, 128), 256, 0, stream>>>(lnX0, wtk, 16384, 768, 768, nullptr, k1p, nullptr);
    gemm_bt<128, 128, 2, 2, EPI_BF16><<<dim3(6, 128), 256, 0, stream>>>(lnX0, wtv, 16384, 768, 768, nullptr, v1p, nullptr);
    // 4. attention
    attn_kernel<<<1536, 256, 0, stream>>>(qb, kb, vb, ao, aff);
    // 5. lora-z down (cross: s0 uses lnZ1), wo GEMM + residual, lora-z up
    gemm_bt<128, 64, 2, 1, EPI_GELU><<<dim3(1, 32), 128, 0, stream>>>(lnZ1, dT, 4096, 64, 768, nullptr, h0, nullptr);
    gemm_bt<128, 64, 2, 1, EPI_GELU><<<dim3(1, 32), 128, 0, stream>>>(lnZ0, dT, 4096, 64, 768, nullptr, h1, nullptr);
    gemm_bt<128, 128, 2, 2, EPI_RESID><<<dim3(6, 32), 256, 0, stream>>>(ao0, wto, 4096, 768, 768, fz0, nullptr, x0);
    gemm_bt<128, 128, 2, 2, EPI_RESID><<<dim3(6, 32), 256, 0, stream>>>(ao1, wto, 4096, 768, 768, fz1, nullptr, x1);
    gemm_bt<128, 128, 2, 2, EPI_ACCUM><<<dim3(6, 32), 256, 0, stream>>>(h0, uT, 4096, 768, 64, fz0, nullptr, nullptr);
    gemm_bt<128, 128, 2, 2, EPI_ACCUM><<<dim3(6, 32), 256, 0, stream>>>(h1, uT, 4096, 768, 64, fz1, nullptr, nullptr);
    // 6. fusion
    fusion_prep<<<128, 64, 0, stream>>>(aff, den);
    fusion_apply<<<40960, 256, 0, stream>>>(x0, x1, fz, aff, den, out);
    // 7. LN2 + mlp lora
    ln2_kernel<<<40960, 256, 0, stream>>>(out, ln2w, ln2b, ln2y);
    gemm_bt<128, 64, 2, 1, EPI_GELU><<<dim3(1, 320), 128, 0, stream>>>(ln2y, mdT, 40960, 64, 768, nullptr, h2, nullptr);
    gemm_bt<128, 128, 2, 2, EPI_ACCUM><<<dim3(6, 320), 256, 0, stream>>>(h2, muT, 40960, 768, 64, out, nullptr, nullptr);
}

// Round 2
// 992.167 us; speedup vs baseline: 1.0014x; 1.0014x over previous
//
#include <hip/hip_runtime.h>

// TMMixer: B=64, T=64, S=256, DIM=768, H=12, HD=64, RANK=64
// Pipeline (all bf16 MFMA GEMMs, f32 accumulation):
//  1. transpose weights -> bf16 (Bt layout: [n][k]) [2 batched kernels]
//  2. LN1 -> bf16
//  3. q/k/v projections (3 combined GEMMs; cross-stream via row^XORBIT)
//  4. attention per (s,b,h): MFMA QK^T -> wave-local softmax -> MFMA PV
//  5. lora-z down (gelu), wo GEMM (+resid), lora-z up (accum) [combined]
//  6. fusion: colmax -> num=exp(aff-12)*mask -> apply
//  7. LN2 + mlp lora into d_out

typedef __bf16 bf8_t __attribute__((ext_vector_type(8)));
typedef float f4_t __attribute__((ext_vector_type(4)));
typedef unsigned short u16;
typedef unsigned int u32;
typedef unsigned short us8_t __attribute__((ext_vector_type(8)));

__device__ __forceinline__ float bf2f(u16 h) {
    return __uint_as_float(((unsigned int)h) << 16);
}
__device__ __forceinline__ u16 f2bf(float f) {
    unsigned int u = __float_as_uint(f);
    u += 0x7fffu + ((u >> 16) & 1u);
    return (u16)(u >> 16);
}
__device__ __forceinline__ float gelu_tanh(float x) {
    float t = tanhf(0.7978845608028654f * (x + 0.044715f * x * x * x));
    return 0.5f * x * (1.0f + t);
}

// ---------------- weight prep: dst[C][R] = bf16(src[R][C]) ----------------
struct TPack {
    const float* s0; const float* s1; const float* s2; const float* s3;
    u16* d0; u16* d1; u16* d2; u16* d3;
};
__global__ __launch_bounds__(256) void transpose_big(TPack p) {
    int which = blockIdx.y;
    const float* src = which == 0 ? p.s0 : which == 1 ? p.s1 : which == 2 ? p.s2 : p.s3;
    u16* dst = which == 0 ? p.d0 : which == 1 ? p.d1 : which == 2 ? p.d2 : p.d3;
    int idx = blockIdx.x * 256 + threadIdx.x;  // 768*768
    int c = idx / 768, r = idx - c * 768;
    dst[idx] = f2bf(src[(size_t)r * 768 + c]);
}
__global__ __launch_bounds__(256) void transpose_small(TPack p) {
    int which = blockIdx.y;
    const float* src = which == 0 ? p.s0 : which == 1 ? p.s1 : which == 2 ? p.s2 : p.s3;
    u16* dst = which == 0 ? p.d0 : which == 1 ? p.d1 : which == 2 ? p.d2 : p.d3;
    int R = (which & 1) ? 64 : 768;
    int C = (which & 1) ? 768 : 64;
    int idx = blockIdx.x * 256 + threadIdx.x;  // 49152
    int c = idx / R, r = idx - c * R;
    dst[idx] = f2bf(src[(size_t)r * C + c]);
}

// ---------------- LN1: 40960 rows; z rows then x rows per stream ----------
__global__ __launch_bounds__(256) void ln1_kernel(
    const float* __restrict__ x0, const float* __restrict__ x1,
    const float* __restrict__ w, const float* __restrict__ b,
    u16* __restrict__ lnZ, u16* __restrict__ lnX) {
    int rid = blockIdx.x;
    int s = rid / 20480;
    int r2 = rid - s * 20480;
    const float* srcBase = (s == 0) ? x0 : x1;
    const float* src; u16* dst;
    if (r2 < 4096) {
        int bb = r2 >> 6, t = r2 & 63;
        src = srcBase + ((size_t)(bb * 320 + t)) * 768;
        dst = lnZ + ((size_t)(s * 4096 + r2)) * 768;
    } else {
        int rx = r2 - 4096;
        int bb = rx >> 8, sx = rx & 255;
        src = srcBase + ((size_t)(bb * 320 + 64 + sx)) * 768;
        dst = lnX + ((size_t)(s * 16384 + rx)) * 768;
    }
    int tid = threadIdx.x;
    float xv0 = src[tid], xv1 = src[tid + 256], xv2 = src[tid + 512];
    float s1 = xv0 + xv1 + xv2;
    float s2 = xv0 * xv0 + xv1 * xv1 + xv2 * xv2;
    #pragma unroll
    for (int o = 1; o < 64; o <<= 1) { s1 += __shfl_xor(s1, o); s2 += __shfl_xor(s2, o); }
    __shared__ float red[2][4];
    int wv = tid >> 6;
    if ((tid & 63) == 0) { red[0][wv] = s1; red[1][wv] = s2; }
    __syncthreads();
    s1 = red[0][0] + red[0][1] + red[0][2] + red[0][3];
    s2 = red[1][0] + red[1][1] + red[1][2] + red[1][3];
    float mean = s1 * (1.0f / 768.0f);
    float var = s2 * (1.0f / 768.0f) - mean * mean;
    float rstd = rsqrtf(var + 1e-5f);
    dst[tid]       = f2bf((xv0 - mean) * rstd * w[tid]       + b[tid]);
    dst[tid + 256] = f2bf((xv1 - mean) * rstd * w[tid + 256] + b[tid + 256]);
    dst[tid + 512] = f2bf((xv2 - mean) * rstd * w[tid + 512] + b[tid + 512]);
}

// ---------------- LN2: contiguous rows from d_out ----------
__global__ __launch_bounds__(256) void ln2_kernel(
    const float* __restrict__ src0, const float* __restrict__ w,
    const float* __restrict__ b, u16* __restrict__ dst0) {
    int rid = blockIdx.x;
    const float* src = src0 + (size_t)rid * 768;
    u16* dst = dst0 + (size_t)rid * 768;
    int tid = threadIdx.x;
    float xv0 = src[tid], xv1 = src[tid + 256], xv2 = src[tid + 512];
    float s1 = xv0 + xv1 + xv2;
    float s2 = xv0 * xv0 + xv1 * xv1 + xv2 * xv2;
    #pragma unroll
    for (int o = 1; o < 64; o <<= 1) { s1 += __shfl_xor(s1, o); s2 += __shfl_xor(s2, o); }
    __shared__ float red[2][4];
    int wv = tid >> 6;
    if ((tid & 63) == 0) { red[0][wv] = s1; red[1][wv] = s2; }
    __syncthreads();
    s1 = red[0][0] + red[0][1] + red[0][2] + red[0][3];
    s2 = red[1][0] + red[1][1] + red[1][2] + red[1][3];
    float mean = s1 * (1.0f / 768.0f);
    float var = s2 * (1.0f / 768.0f) - mean * mean;
    float rstd = rsqrtf(var + 1e-5f);
    dst[tid]       = f2bf((xv0 - mean) * rstd * w[tid]       + b[tid]);
    dst[tid + 256] = f2bf((xv1 - mean) * rstd * w[tid + 256] + b[tid + 256]);
    dst[tid + 512] = f2bf((xv2 - mean) * rstd * w[tid + 512] + b[tid + 512]);
}

// ---------------- MFMA GEMM: C = A(MxK) * Bt(NxK)^T, epilogues -----------
// Output row is (row ^ XB) to implement cross-stream half-swaps for free.
enum { EPI_BF16 = 0, EPI_RESID = 1, EPI_GELU = 2, EPI_ACCUM = 3 };

template <int BM, int BN, int WR, int WC, int EPI, int XB>
__global__ __launch_bounds__(WR * WC * 64, 1) void gemm_bt(
    const u16* __restrict__ A, const u16* __restrict__ Bt,
    int M, int N, int K,
    float* __restrict__ Cf, u16* __restrict__ Cbf,
    const float* __restrict__ resid0, const float* __restrict__ resid1) {
    constexpr int THREADS = WR * WC * 64;
    constexpr int BK = 64;
    __shared__ alignas(16) u16 As[BM][BK + 8];
    __shared__ alignas(16) u16 Bs[BN][BK + 8];

    const int tid = threadIdx.x;
    const int lane = tid & 63;
    const int w = tid >> 6;
    const int wr = w / WC, wc = w % WC;
    const int r = lane & 15, g = lane >> 4;
    const int brow = blockIdx.y * BM;
    const int bcol = blockIdx.x * BN;

    f4_t acc[4][4];
    f4_t zero = {0.f, 0.f, 0.f, 0.f};
    #pragma unroll
    for (int m = 0; m < 4; m++)
        #pragma unroll
        for (int n = 0; n < 4; n++) acc[m][n] = zero;

    for (int k0 = 0; k0 < K; k0 += BK) {
        constexpr int CA = BM * BK / 8;
        #pragma unroll
        for (int i = 0; i < CA / THREADS; i++) {
            int c = tid + THREADS * i;
            int row = c >> 3, kc = (c & 7) * 8;
            bf8_t val = *reinterpret_cast<const bf8_t*>(A + (size_t)(brow + row) * K + k0 + kc);
            *reinterpret_cast<bf8_t*>(&As[row][kc]) = val;
        }
        constexpr int CB = BN * BK / 8;
        #pragma unroll
        for (int i = 0; i < CB / THREADS; i++) {
            int c = tid + THREADS * i;
            int row = c >> 3, kc = (c & 7) * 8;
            bf8_t val = *reinterpret_cast<const bf8_t*>(Bt + (size_t)(bcol + row) * K + k0 + kc);
            *reinterpret_cast<bf8_t*>(&Bs[row][kc]) = val;
        }
        __syncthreads();
        #pragma unroll
        for (int ks = 0; ks < BK; ks += 32) {
            bf8_t af[4], bfr[4];
            #pragma unroll
            for (int m = 0; m < 4; m++)
                af[m] = *reinterpret_cast<const bf8_t*>(&As[wr * 64 + m * 16 + r][ks + g * 8]);
            #pragma unroll
            for (int n = 0; n < 4; n++)
                bfr[n] = *reinterpret_cast<const bf8_t*>(&Bs[wc * 64 + n * 16 + r][ks + g * 8]);
            #pragma unroll
            for (int m = 0; m < 4; m++)
                #pragma unroll
                for (int n = 0; n < 4; n++)
                    acc[m][n] = __builtin_amdgcn_mfma_f32_16x16x32_bf16(af[m], bfr[n], acc[m][n], 0, 0, 0);
        }
        __syncthreads();
    }

    #pragma unroll
    for (int m = 0; m < 4; m++) {
        #pragma unroll
        for (int n = 0; n < 4; n++) {
            int col = bcol + wc * 64 + n * 16 + r;
            #pragma unroll
            for (int i = 0; i < 4; i++) {
                int row = brow + wr * 64 + m * 16 + g * 4 + i;
                int orow = row ^ XB;
                float val = acc[m][n][i];
                if constexpr (EPI == EPI_BF16) {
                    Cbf[(size_t)orow * N + col] = f2bf(val);
                } else if constexpr (EPI == EPI_RESID) {
                    const float* rp = (orow & 4096) ? resid1 : resid0;
                    int rr = orow & 4095;
                    float rs = rp[(size_t)((rr >> 6) * 320 + (rr & 63)) * 768 + col];
                    Cf[(size_t)orow * N + col] = val + rs;
                } else if constexpr (EPI == EPI_GELU) {
                    Cbf[(size_t)orow * N + col] = f2bf(gelu_tanh(val));
                } else {
                    Cf[(size_t)orow * N + col] += val;
                }
            }
        }
    }
}

// ---------------- MFMA attention per (s,b,h) ------------------------------
// 4 waves; wave w owns q rows [w*16, w*16+16) x all 256 k cols.
// Ks[256][72] staged; Vt[64][264] = V transposed; P tiles alias Ks after sync.
__global__ __launch_bounds__(256, 2) void attn_mfma(
    const u16* __restrict__ q, const u16* __restrict__ k,
    const u16* __restrict__ v, u16* __restrict__ attnout,
    float* __restrict__ aff) {
    __shared__ alignas(16) u16 Ks[256][72];   // 36,864 B (P tiles alias after sync)
    __shared__ alignas(16) u16 Vt[64][264];   // 33,792 B
    int bid = blockIdx.x;
    int s = bid / 768;
    int rem = bid - s * 768;
    int b = rem / 12, h = rem - (rem / 12) * 12;
    int tid = threadIdx.x, lane = tid & 63, w = tid >> 6;
    int r = lane & 15, g = lane >> 4;

    size_t kvbase = ((size_t)(s * 16384 + b * 256)) * 768 + h * 64;

    // Q fragments direct from global (read once, L2-resident)
    const u16* qrow = q + ((size_t)(s * 4096 + b * 64 + w * 16 + r)) * 768 + h * 64 + g * 8;
    bf8_t qf0 = *reinterpret_cast<const bf8_t*>(qrow);
    bf8_t qf1 = *reinterpret_cast<const bf8_t*>(qrow + 32);

    // stage K [256][64] -> Ks
    #pragma unroll
    for (int i = 0; i < 8; i++) {
        int c = tid + 256 * i;
        int row = c >> 3, kc = (c & 7) * 8;
        *reinterpret_cast<bf8_t*>(&Ks[row][kc]) =
            *reinterpret_cast<const bf8_t*>(k + kvbase + (size_t)row * 768 + kc);
    }
    // stage V transposed: Vt[d][kk] = V[kk][d], u32 pair-writes (kk even|odd)
    u32* vt32 = reinterpret_cast<u32*>(&Vt[0][0]);  // row stride 132 u32
    #pragma unroll
    for (int i = 0; i < 4; i++) {
        int c = tid + 256 * i;
        int kp = c >> 3, d0 = (c & 7) * 8;
        const u16* vr = v + kvbase + (size_t)(2 * kp) * 768 + d0;
        us8_t va = *reinterpret_cast<const us8_t*>(vr);
        us8_t vb = *reinterpret_cast<const us8_t*>(vr + 768);
        #pragma unroll
        for (int j = 0; j < 8; j++)
            vt32[(d0 + j) * 132 + kp] = (u32)va[j] | ((u32)vb[j] << 16);
    }
    __syncthreads();

    // QK^T: acc[n] = S[q=w*16+g*4+i][k=n*16+r]
    f4_t acc[16];
    f4_t zero = {0.f, 0.f, 0.f, 0.f};
    #pragma unroll
    for (int n = 0; n < 16; n++) acc[n] = zero;
    #pragma unroll
    for (int n = 0; n < 16; n++) {
        bf8_t b0 = *reinterpret_cast<const bf8_t*>(&Ks[n * 16 + r][g * 8]);
        acc[n] = __builtin_amdgcn_mfma_f32_16x16x32_bf16(qf0, b0, acc[n], 0, 0, 0);
        bf8_t b1 = *reinterpret_cast<const bf8_t*>(&Ks[n * 16 + r][32 + g * 8]);
        acc[n] = __builtin_amdgcn_mfma_f32_16x16x32_bf16(qf1, b1, acc[n], 0, 0, 0);
    }

    // wave-local softmax over k (row spread over 16 regs x 16 lanes within g)
    float mx[4] = {-1e30f, -1e30f, -1e30f, -1e30f};
    #pragma unroll
    for (int n = 0; n < 16; n++)
        #pragma unroll
        for (int i = 0; i < 4; i++) {
            acc[n][i] *= 0.125f;
            mx[i] = fmaxf(mx[i], acc[n][i]);
        }
    #pragma unroll
    for (int i = 0; i < 4; i++) {
        mx[i] = fmaxf(mx[i], __shfl_xor(mx[i], 1));
        mx[i] = fmaxf(mx[i], __shfl_xor(mx[i], 2));
        mx[i] = fmaxf(mx[i], __shfl_xor(mx[i], 4));
        mx[i] = fmaxf(mx[i], __shfl_xor(mx[i], 8));
    }
    float sm[4] = {0.f, 0.f, 0.f, 0.f};
    #pragma unroll
    for (int n = 0; n < 16; n++)
        #pragma unroll
        for (int i = 0; i < 4; i++) {
            float e = __expf(acc[n][i] - mx[i]);
            acc[n][i] = e;
            sm[i] += e;
        }
    #pragma unroll
    for (int i = 0; i < 4; i++) {
        sm[i] += __shfl_xor(sm[i], 1);
        sm[i] += __shfl_xor(sm[i], 2);
        sm[i] += __shfl_xor(sm[i], 4);
        sm[i] += __shfl_xor(sm[i], 8);
    }
    float inv[4];
    #pragma unroll
    for (int i = 0; i < 4; i++) inv[i] = 1.0f / sm[i];

    __syncthreads();  // all waves done reading Ks; safe to overwrite with P

    // P tile per wave: 16 rows x 256 cols, stride 264, aliasing Ks rows [w*64, w*64+64)
    u16* Pw = &Ks[w * 64][0];
    float* affp = aff + (size_t)(s * 64 + b) * (256 * 64);
    #pragma unroll
    for (int n = 0; n < 16; n++) {
        int kcol = n * 16 + r;
        #pragma unroll
        for (int i = 0; i < 4; i++) {
            float p = acc[n][i] * inv[i];
            Pw[(g * 4 + i) * 264 + kcol] = f2bf(p);
            atomicAdd(&affp[kcol * 64 + (w * 16 + g * 4 + i)], p);
        }
    }

    // PV: out[q][d] = sum_k P[q][k] * Vt[d][k]
    f4_t acc2[4];
    #pragma unroll
    for (int n = 0; n < 4; n++) acc2[n] = zero;
    #pragma unroll
    for (int k2 = 0; k2 < 8; k2++) {
        bf8_t pa = *reinterpret_cast<const bf8_t*>(&Pw[r * 264 + k2 * 32 + g * 8]);
        #pragma unroll
        for (int n2 = 0; n2 < 4; n2++) {
            bf8_t vbf = *reinterpret_cast<const bf8_t*>(&Vt[n2 * 16 + r][k2 * 32 + g * 8]);
            acc2[n2] = __builtin_amdgcn_mfma_f32_16x16x32_bf16(pa, vbf, acc2[n2], 0, 0, 0);
        }
    }
    u16* op = attnout + ((size_t)(s * 4096 + b * 64 + w * 16 + g * 4)) * 768 + h * 64;
    #pragma unroll
    for (int n2 = 0; n2 < 4; n2++)
        #pragma unroll
        for (int i = 0; i < 4; i++)
            op[(size_t)i * 768 + n2 * 16 + r] = f2bf(acc2[n2][i]);
}

// ---------------- fusion prep: colmax, num, den ----------------
__global__ __launch_bounds__(64) void fusion_prep(float* __restrict__ aff, float* __restrict__ den) {
    int sb = blockIdx.x;  // 0..127 = s*64+b
    float* ap = aff + (size_t)sb * 256 * 64;
    int t = threadIdx.x;
    float mx = -1e30f;
    for (int kk = 0; kk < 256; kk++) mx = fmaxf(mx, ap[kk * 64 + t]);
    for (int kk = 0; kk < 256; kk++) {
        float val = ap[kk * 64 + t];
        float nu = (val == mx) ? __expf(val - 12.0f) : 0.f;
        ap[kk * 64 + t] = nu;
        float rs = nu;
        #pragma unroll
        for (int o = 1; o < 64; o <<= 1) rs += __shfl_xor(rs, o);
        if (t == 0) den[sb * 256 + kk] = 1.0f + rs;
    }
}

// ---------------- fusion apply: write all of y ----------------
__global__ __launch_bounds__(256) void fusion_apply(
    const float* __restrict__ x0, const float* __restrict__ x1,
    const float* __restrict__ fz, const float* __restrict__ aff,
    const float* __restrict__ den, float* __restrict__ out) {
    int bid = blockIdx.x;  // s*20480 + b*320 + n
    int s = bid / 20480;
    int r2 = bid - s * 20480;
    int b = r2 / 320, n = r2 - (r2 / 320) * 320;
    int tid = threadIdx.x;
    float* orow = out + (size_t)bid * 768;
    const float* fzs = fz + (size_t)s * 4096 * 768;
    if (n < 64) {
        const float* zrow = fzs + ((size_t)(b * 64 + n)) * 768;
        orow[tid] = zrow[tid];
        orow[tid + 256] = zrow[tid + 256];
        orow[tid + 512] = zrow[tid + 512];
    } else {
        int sx = n - 64;
        const float* xrow = ((s == 0) ? x0 : x1) + ((size_t)(b * 320 + n)) * 768;
        float invd = 1.0f / den[(s * 64 + b) * 256 + sx];
        __shared__ float nush[64];
        if (tid < 64) nush[tid] = aff[(((size_t)(s * 64 + b)) * 256 + sx) * 64 + tid];
        __syncthreads();
        float a0 = xrow[tid] * invd;
        float a1 = xrow[tid + 256] * invd;
        float a2 = xrow[tid + 512] * invd;
        for (int t = 0; t < 64; t++) {
            float nu = nush[t];
            if (nu != 0.f) {
                float wgt = nu * invd;
                const float* zr = fzs + ((size_t)(b * 64 + t)) * 768;
                a0 += wgt * zr[tid];
                a1 += wgt * zr[tid + 256];
                a2 += wgt * zr[tid + 512];
            }
        }
        orow[tid] = a0; orow[tid + 256] = a1; orow[tid + 512] = a2;
    }
}

extern "C" void kernel_launch(void* const* d_in, const int* in_sizes, int n_in,
                              void* d_out, int out_size, void* d_ws, size_t ws_size,
                              hipStream_t stream) {
    (void)in_sizes; (void)n_in; (void)out_size;
    const float* x0 = (const float*)d_in[0];
    const float* x1 = (const float*)d_in[1];
    const float* ln1w = (const float*)d_in[2];
    const float* ln1b = (const float*)d_in[3];
    const float* ln2w = (const float*)d_in[4];
    const float* ln2b = (const float*)d_in[5];
    const float* wq = (const float*)d_in[6];
    const float* wk = (const float*)d_in[7];
    const float* wv = (const float*)d_in[8];
    const float* wo = (const float*)d_in[9];
    const float* lora_down = (const float*)d_in[10];
    const float* lora_up = (const float*)d_in[11];
    const float* mlp_down = (const float*)d_in[12];
    const float* mlp_up = (const float*)d_in[13];
    float* out = (float*)d_out;

    char* ws = (char*)d_ws;
    size_t off = 0;
    auto alloc = [&](size_t bytes) -> char* {
        char* p = ws + off;
        off = (off + bytes + 255) & ~(size_t)255;
        return p;
    };
    u16* wtq = (u16*)alloc(768 * 768 * 2);
    u16* wtk = (u16*)alloc(768 * 768 * 2);
    u16* wtv = (u16*)alloc(768 * 768 * 2);
    u16* wto = (u16*)alloc(768 * 768 * 2);
    u16* dT  = (u16*)alloc(768 * 64 * 2);
    u16* uT  = (u16*)alloc(768 * 64 * 2);
    u16* mdT = (u16*)alloc(768 * 64 * 2);
    u16* muT = (u16*)alloc(768 * 64 * 2);
    u16* lnZ = (u16*)alloc((size_t)2 * 4096 * 768 * 2);    // region B start
    u16* lnX = (u16*)alloc((size_t)2 * 16384 * 768 * 2);   // contiguous with lnZ
    u16* qb  = (u16*)alloc((size_t)2 * 4096 * 768 * 2);    // region C (h2 aliases)
    u16* kb  = (u16*)alloc((size_t)2 * 16384 * 768 * 2);   // region D (fz aliases)
    u16* vb  = (u16*)alloc((size_t)2 * 16384 * 768 * 2);
    u16* ao  = (u16*)alloc((size_t)2 * 4096 * 768 * 2);
    float* aff = (float*)alloc((size_t)2 * 64 * 256 * 64 * 4);
    float* den = (float*)alloc((size_t)2 * 64 * 256 * 4);
    u16* h01 = (u16*)alloc((size_t)2 * 4096 * 64 * 2);
    // aliases (lifetimes disjoint by stream order):
    u16* ln2y = lnZ;               // 40960*768*2 == lnZ+lnX exactly
    u16* h2 = qb;                  // 40960*64*2  <= q region
    float* fz = (float*)kb;        // 2*4096*768*4 <= k region
    if (ws_size < off) return;     // ws too small -> leave poison (diagnosable)

    // 1. weight prep (batched)
    TPack big = {wq, wk, wv, wo, wtq, wtk, wtv, wto};
    transpose_big<<<dim3(2304, 4), 256, 0, stream>>>(big);
    TPack small = {lora_down, lora_up, mlp_down, mlp_up, dT, uT, mdT, muT};
    transpose_small<<<dim3(192, 4), 256, 0, stream>>>(small);
    hipMemsetAsync(aff, 0, (size_t)2 * 64 * 256 * 64 * 4, stream);
    // 2. LN1
    ln1_kernel<<<40960, 256, 0, stream>>>(x0, x1, ln1w, ln1b, lnZ, lnX);
    // 3. projections; kv cross-stream via row^16384 on output
    gemm_bt<128, 128, 2, 2, EPI_BF16, 0><<<dim3(6, 64), 256, 0, stream>>>(
        lnZ, wtq, 8192, 768, 768, nullptr, qb, nullptr, nullptr);
    gemm_bt<128, 128, 2, 2, EPI_BF16, 16384><<<dim3(6, 256), 256, 0, stream>>>(
        lnX, wtk, 32768, 768, 768, nullptr, kb, nullptr, nullptr);
    gemm_bt<128, 128, 2, 2, EPI_BF16, 16384><<<dim3(6, 256), 256, 0, stream>>>(
        lnX, wtv, 32768, 768, 768, nullptr, vb, nullptr, nullptr);
    // 4. attention (MFMA)
    attn_mfma<<<1536, 256, 0, stream>>>(qb, kb, vb, ao, aff);
    // 5. lora-z down -> hx = [gelu(lnZ0@dT); gelu(lnZ1@dT)]; wo+resid; up with row^4096
    gemm_bt<128, 64, 2, 1, EPI_GELU, 0><<<dim3(1, 64), 128, 0, stream>>>(
        lnZ, dT, 8192, 64, 768, nullptr, h01, nullptr, nullptr);
    gemm_bt<128, 128, 2, 2, EPI_RESID, 0><<<dim3(6, 64), 256, 0, stream>>>(
        ao, wto, 8192, 768, 768, fz, nullptr, x0, x1);
    gemm_bt<128, 128, 2, 2, EPI_ACCUM, 4096><<<dim3(6, 64), 256, 0, stream>>>(
        h01, uT, 8192, 768, 64, fz, nullptr, nullptr, nullptr);
    // 6. fusion
    fusion_prep<<<128, 64, 0, stream>>>(aff, den);
    fusion_apply<<<40960, 256, 0, stream>>>(x0, x1, fz, aff, den, out);
    // 7. LN2 + mlp lora
    ln2_kernel<<<40960, 256, 0, stream>>>(out, ln2w, ln2b, ln2y);
    gemm_bt<128, 64, 2, 1, EPI_GELU, 0><<<dim3(1, 320), 128, 0, stream>>>(
        ln2y, mdT, 40960, 64, 768, nullptr, h2, nullptr, nullptr);
    gemm_bt<128, 128, 2, 2, EPI_ACCUM, 0><<<dim3(6, 320), 256, 0, stream>>>(
        h2, muT, 40960, 768, 64, out, nullptr, nullptr, nullptr);
}

// Round 3
// 578.895 us; speedup vs baseline: 1.7163x; 1.7139x over previous
//
#include <hip/hip_runtime.h>

// TMMixer: B=64, T=64, S=256, DIM=768, H=12, HD=64, RANK=64
// Pipeline (all bf16 MFMA GEMMs, f32 accumulation):
//  1. transpose weights -> bf16 (Bt layout: [n][k]) [2 batched kernels]
//  2. LN1 -> bf16
//  3. q/k/v projections (3 combined GEMMs; cross-stream via row^XORBIT)
//  4. attention per (s,b,h): MFMA QK^T -> wave-local softmax -> MFMA PV;
//     P dumped as bf16 to paff[sbh][q][k] (NO global atomics)
//  5. fusion_prep2: h-sum reduce -> colmax -> nu, den partials
//  6. lora-z down (gelu), wo GEMM (+resid), lora-z up (accum) [combined]
//  7. fusion apply
//  8. LN2 + mlp lora into d_out

typedef __bf16 bf8_t __attribute__((ext_vector_type(8)));
typedef float f4_t __attribute__((ext_vector_type(4)));
typedef unsigned short u16;
typedef unsigned int u32;
typedef unsigned short us8_t __attribute__((ext_vector_type(8)));

__device__ __forceinline__ float bf2f(u16 h) {
    return __uint_as_float(((unsigned int)h) << 16);
}
__device__ __forceinline__ u16 f2bf(float f) {
    unsigned int u = __float_as_uint(f);
    u += 0x7fffu + ((u >> 16) & 1u);
    return (u16)(u >> 16);
}
__device__ __forceinline__ float gelu_tanh(float x) {
    float t = tanhf(0.7978845608028654f * (x + 0.044715f * x * x * x));
    return 0.5f * x * (1.0f + t);
}

// ---------------- weight prep: dst[C][R] = bf16(src[R][C]) ----------------
struct TPack {
    const float* s0; const float* s1; const float* s2; const float* s3;
    u16* d0; u16* d1; u16* d2; u16* d3;
};
__global__ __launch_bounds__(256) void transpose_big(TPack p) {
    int which = blockIdx.y;
    const float* src = which == 0 ? p.s0 : which == 1 ? p.s1 : which == 2 ? p.s2 : p.s3;
    u16* dst = which == 0 ? p.d0 : which == 1 ? p.d1 : which == 2 ? p.d2 : p.d3;
    int idx = blockIdx.x * 256 + threadIdx.x;  // 768*768
    int c = idx / 768, r = idx - c * 768;
    dst[idx] = f2bf(src[(size_t)r * 768 + c]);
}
__global__ __launch_bounds__(256) void transpose_small(TPack p) {
    int which = blockIdx.y;
    const float* src = which == 0 ? p.s0 : which == 1 ? p.s1 : which == 2 ? p.s2 : p.s3;
    u16* dst = which == 0 ? p.d0 : which == 1 ? p.d1 : which == 2 ? p.d2 : p.d3;
    int R = (which & 1) ? 64 : 768;
    int C = (which & 1) ? 768 : 64;
    int idx = blockIdx.x * 256 + threadIdx.x;  // 49152
    int c = idx / R, r = idx - c * R;
    dst[idx] = f2bf(src[(size_t)r * C + c]);
}

// ---------------- LN1: 40960 rows; z rows then x rows per stream ----------
__global__ __launch_bounds__(256) void ln1_kernel(
    const float* __restrict__ x0, const float* __restrict__ x1,
    const float* __restrict__ w, const float* __restrict__ b,
    u16* __restrict__ lnZ, u16* __restrict__ lnX) {
    int rid = blockIdx.x;
    int s = rid / 20480;
    int r2 = rid - s * 20480;
    const float* srcBase = (s == 0) ? x0 : x1;
    const float* src; u16* dst;
    if (r2 < 4096) {
        int bb = r2 >> 6, t = r2 & 63;
        src = srcBase + ((size_t)(bb * 320 + t)) * 768;
        dst = lnZ + ((size_t)(s * 4096 + r2)) * 768;
    } else {
        int rx = r2 - 4096;
        int bb = rx >> 8, sx = rx & 255;
        src = srcBase + ((size_t)(bb * 320 + 64 + sx)) * 768;
        dst = lnX + ((size_t)(s * 16384 + rx)) * 768;
    }
    int tid = threadIdx.x;
    float xv0 = src[tid], xv1 = src[tid + 256], xv2 = src[tid + 512];
    float s1 = xv0 + xv1 + xv2;
    float s2 = xv0 * xv0 + xv1 * xv1 + xv2 * xv2;
    #pragma unroll
    for (int o = 1; o < 64; o <<= 1) { s1 += __shfl_xor(s1, o); s2 += __shfl_xor(s2, o); }
    __shared__ float red[2][4];
    int wv = tid >> 6;
    if ((tid & 63) == 0) { red[0][wv] = s1; red[1][wv] = s2; }
    __syncthreads();
    s1 = red[0][0] + red[0][1] + red[0][2] + red[0][3];
    s2 = red[1][0] + red[1][1] + red[1][2] + red[1][3];
    float mean = s1 * (1.0f / 768.0f);
    float var = s2 * (1.0f / 768.0f) - mean * mean;
    float rstd = rsqrtf(var + 1e-5f);
    dst[tid]       = f2bf((xv0 - mean) * rstd * w[tid]       + b[tid]);
    dst[tid + 256] = f2bf((xv1 - mean) * rstd * w[tid + 256] + b[tid + 256]);
    dst[tid + 512] = f2bf((xv2 - mean) * rstd * w[tid + 512] + b[tid + 512]);
}

// ---------------- LN2: contiguous rows from d_out ----------
__global__ __launch_bounds__(256) void ln2_kernel(
    const float* __restrict__ src0, const float* __restrict__ w,
    const float* __restrict__ b, u16* __restrict__ dst0) {
    int rid = blockIdx.x;
    const float* src = src0 + (size_t)rid * 768;
    u16* dst = dst0 + (size_t)rid * 768;
    int tid = threadIdx.x;
    float xv0 = src[tid], xv1 = src[tid + 256], xv2 = src[tid + 512];
    float s1 = xv0 + xv1 + xv2;
    float s2 = xv0 * xv0 + xv1 * xv1 + xv2 * xv2;
    #pragma unroll
    for (int o = 1; o < 64; o <<= 1) { s1 += __shfl_xor(s1, o); s2 += __shfl_xor(s2, o); }
    __shared__ float red[2][4];
    int wv = tid >> 6;
    if ((tid & 63) == 0) { red[0][wv] = s1; red[1][wv] = s2; }
    __syncthreads();
    s1 = red[0][0] + red[0][1] + red[0][2] + red[0][3];
    s2 = red[1][0] + red[1][1] + red[1][2] + red[1][3];
    float mean = s1 * (1.0f / 768.0f);
    float var = s2 * (1.0f / 768.0f) - mean * mean;
    float rstd = rsqrtf(var + 1e-5f);
    dst[tid]       = f2bf((xv0 - mean) * rstd * w[tid]       + b[tid]);
    dst[tid + 256] = f2bf((xv1 - mean) * rstd * w[tid + 256] + b[tid + 256]);
    dst[tid + 512] = f2bf((xv2 - mean) * rstd * w[tid + 512] + b[tid + 512]);
}

// ---------------- MFMA GEMM: C = A(MxK) * Bt(NxK)^T, epilogues -----------
enum { EPI_BF16 = 0, EPI_RESID = 1, EPI_GELU = 2, EPI_ACCUM = 3 };

template <int BM, int BN, int WR, int WC, int EPI, int XB>
__global__ __launch_bounds__(WR * WC * 64, 1) void gemm_bt(
    const u16* __restrict__ A, const u16* __restrict__ Bt,
    int M, int N, int K,
    float* __restrict__ Cf, u16* __restrict__ Cbf,
    const float* __restrict__ resid0, const float* __restrict__ resid1) {
    constexpr int THREADS = WR * WC * 64;
    constexpr int BK = 64;
    __shared__ alignas(16) u16 As[BM][BK + 8];
    __shared__ alignas(16) u16 Bs[BN][BK + 8];

    const int tid = threadIdx.x;
    const int lane = tid & 63;
    const int w = tid >> 6;
    const int wr = w / WC, wc = w % WC;
    const int r = lane & 15, g = lane >> 4;
    const int brow = blockIdx.y * BM;
    const int bcol = blockIdx.x * BN;

    f4_t acc[4][4];
    f4_t zero = {0.f, 0.f, 0.f, 0.f};
    #pragma unroll
    for (int m = 0; m < 4; m++)
        #pragma unroll
        for (int n = 0; n < 4; n++) acc[m][n] = zero;

    for (int k0 = 0; k0 < K; k0 += BK) {
        constexpr int CA = BM * BK / 8;
        #pragma unroll
        for (int i = 0; i < CA / THREADS; i++) {
            int c = tid + THREADS * i;
            int row = c >> 3, kc = (c & 7) * 8;
            bf8_t val = *reinterpret_cast<const bf8_t*>(A + (size_t)(brow + row) * K + k0 + kc);
            *reinterpret_cast<bf8_t*>(&As[row][kc]) = val;
        }
        constexpr int CB = BN * BK / 8;
        #pragma unroll
        for (int i = 0; i < CB / THREADS; i++) {
            int c = tid + THREADS * i;
            int row = c >> 3, kc = (c & 7) * 8;
            bf8_t val = *reinterpret_cast<const bf8_t*>(Bt + (size_t)(bcol + row) * K + k0 + kc);
            *reinterpret_cast<bf8_t*>(&Bs[row][kc]) = val;
        }
        __syncthreads();
        #pragma unroll
        for (int ks = 0; ks < BK; ks += 32) {
            bf8_t af[4], bfr[4];
            #pragma unroll
            for (int m = 0; m < 4; m++)
                af[m] = *reinterpret_cast<const bf8_t*>(&As[wr * 64 + m * 16 + r][ks + g * 8]);
            #pragma unroll
            for (int n = 0; n < 4; n++)
                bfr[n] = *reinterpret_cast<const bf8_t*>(&Bs[wc * 64 + n * 16 + r][ks + g * 8]);
            #pragma unroll
            for (int m = 0; m < 4; m++)
                #pragma unroll
                for (int n = 0; n < 4; n++)
                    acc[m][n] = __builtin_amdgcn_mfma_f32_16x16x32_bf16(af[m], bfr[n], acc[m][n], 0, 0, 0);
        }
        __syncthreads();
    }

    #pragma unroll
    for (int m = 0; m < 4; m++) {
        #pragma unroll
        for (int n = 0; n < 4; n++) {
            int col = bcol + wc * 64 + n * 16 + r;
            #pragma unroll
            for (int i = 0; i < 4; i++) {
                int row = brow + wr * 64 + m * 16 + g * 4 + i;
                int orow = row ^ XB;
                float val = acc[m][n][i];
                if constexpr (EPI == EPI_BF16) {
                    Cbf[(size_t)orow * N + col] = f2bf(val);
                } else if constexpr (EPI == EPI_RESID) {
                    const float* rp = (orow & 4096) ? resid1 : resid0;
                    int rr = orow & 4095;
                    float rs = rp[(size_t)((rr >> 6) * 320 + (rr & 63)) * 768 + col];
                    Cf[(size_t)orow * N + col] = val + rs;
                } else if constexpr (EPI == EPI_GELU) {
                    Cbf[(size_t)orow * N + col] = f2bf(gelu_tanh(val));
                } else {
                    Cf[(size_t)orow * N + col] += val;
                }
            }
        }
    }
}

// ---------------- MFMA attention per (s,b,h) ------------------------------
// 4 waves; wave w owns q rows [w*16, w*16+16) x all 256 k cols.
// Ks[256][72] staged; Vt[64][264] = V transposed; P tiles alias Ks after sync.
// P also dumped coalesced (bf16) into paff[sbh][q][k] — no global atomics.
__global__ __launch_bounds__(256, 2) void attn_mfma(
    const u16* __restrict__ q, const u16* __restrict__ k,
    const u16* __restrict__ v, u16* __restrict__ attnout,
    u16* __restrict__ paff) {
    __shared__ alignas(16) u16 Ks[256][72];   // 36,864 B (P tiles alias after sync)
    __shared__ alignas(16) u16 Vt[64][264];   // 33,792 B
    int bid = blockIdx.x;
    int s = bid / 768;
    int rem = bid - s * 768;
    int b = rem / 12, h = rem - (rem / 12) * 12;
    int tid = threadIdx.x, lane = tid & 63, w = tid >> 6;
    int r = lane & 15, g = lane >> 4;

    size_t kvbase = ((size_t)(s * 16384 + b * 256)) * 768 + h * 64;

    // Q fragments direct from global (read once, L2-resident)
    const u16* qrow = q + ((size_t)(s * 4096 + b * 64 + w * 16 + r)) * 768 + h * 64 + g * 8;
    bf8_t qf0 = *reinterpret_cast<const bf8_t*>(qrow);
    bf8_t qf1 = *reinterpret_cast<const bf8_t*>(qrow + 32);

    // stage K [256][64] -> Ks
    #pragma unroll
    for (int i = 0; i < 8; i++) {
        int c = tid + 256 * i;
        int row = c >> 3, kc = (c & 7) * 8;
        *reinterpret_cast<bf8_t*>(&Ks[row][kc]) =
            *reinterpret_cast<const bf8_t*>(k + kvbase + (size_t)row * 768 + kc);
    }
    // stage V transposed: Vt[d][kk] = V[kk][d], u32 pair-writes (kk even|odd)
    u32* vt32 = reinterpret_cast<u32*>(&Vt[0][0]);  // row stride 132 u32
    #pragma unroll
    for (int i = 0; i < 4; i++) {
        int c = tid + 256 * i;
        int kp = c >> 3, d0 = (c & 7) * 8;
        const u16* vr = v + kvbase + (size_t)(2 * kp) * 768 + d0;
        us8_t va = *reinterpret_cast<const us8_t*>(vr);
        us8_t vb = *reinterpret_cast<const us8_t*>(vr + 768);
        #pragma unroll
        for (int j = 0; j < 8; j++)
            vt32[(d0 + j) * 132 + kp] = (u32)va[j] | ((u32)vb[j] << 16);
    }
    __syncthreads();

    // QK^T: acc[n] = S[q=w*16+g*4+i][k=n*16+r]
    f4_t acc[16];
    f4_t zero = {0.f, 0.f, 0.f, 0.f};
    #pragma unroll
    for (int n = 0; n < 16; n++) acc[n] = zero;
    #pragma unroll
    for (int n = 0; n < 16; n++) {
        bf8_t b0 = *reinterpret_cast<const bf8_t*>(&Ks[n * 16 + r][g * 8]);
        acc[n] = __builtin_amdgcn_mfma_f32_16x16x32_bf16(qf0, b0, acc[n], 0, 0, 0);
        bf8_t b1 = *reinterpret_cast<const bf8_t*>(&Ks[n * 16 + r][32 + g * 8]);
        acc[n] = __builtin_amdgcn_mfma_f32_16x16x32_bf16(qf1, b1, acc[n], 0, 0, 0);
    }

    // wave-local softmax over k (row spread over 16 regs x 16 lanes within g)
    float mx[4] = {-1e30f, -1e30f, -1e30f, -1e30f};
    #pragma unroll
    for (int n = 0; n < 16; n++)
        #pragma unroll
        for (int i = 0; i < 4; i++) {
            acc[n][i] *= 0.125f;
            mx[i] = fmaxf(mx[i], acc[n][i]);
        }
    #pragma unroll
    for (int i = 0; i < 4; i++) {
        mx[i] = fmaxf(mx[i], __shfl_xor(mx[i], 1));
        mx[i] = fmaxf(mx[i], __shfl_xor(mx[i], 2));
        mx[i] = fmaxf(mx[i], __shfl_xor(mx[i], 4));
        mx[i] = fmaxf(mx[i], __shfl_xor(mx[i], 8));
    }
    float sm[4] = {0.f, 0.f, 0.f, 0.f};
    #pragma unroll
    for (int n = 0; n < 16; n++)
        #pragma unroll
        for (int i = 0; i < 4; i++) {
            float e = __expf(acc[n][i] - mx[i]);
            acc[n][i] = e;
            sm[i] += e;
        }
    #pragma unroll
    for (int i = 0; i < 4; i++) {
        sm[i] += __shfl_xor(sm[i], 1);
        sm[i] += __shfl_xor(sm[i], 2);
        sm[i] += __shfl_xor(sm[i], 4);
        sm[i] += __shfl_xor(sm[i], 8);
    }
    float inv[4];
    #pragma unroll
    for (int i = 0; i < 4; i++) inv[i] = 1.0f / sm[i];

    __syncthreads();  // all waves done reading Ks; safe to overwrite with P

    // P tile per wave: 16 rows x 256 cols, stride 264, aliasing Ks rows [w*64, w*64+64)
    u16* Pw = &Ks[w * 64][0];
    u16* pout = paff + ((size_t)bid * 64 + w * 16) * 256;
    #pragma unroll
    for (int n = 0; n < 16; n++) {
        int kcol = n * 16 + r;
        #pragma unroll
        for (int i = 0; i < 4; i++) {
            u16 pb = f2bf(acc[n][i] * inv[i]);
            Pw[(g * 4 + i) * 264 + kcol] = pb;
            pout[(g * 4 + i) * 256 + kcol] = pb;
        }
    }

    // PV: out[q][d] = sum_k P[q][k] * Vt[d][k]
    f4_t acc2[4];
    #pragma unroll
    for (int n = 0; n < 4; n++) acc2[n] = zero;
    #pragma unroll
    for (int k2 = 0; k2 < 8; k2++) {
        bf8_t pa = *reinterpret_cast<const bf8_t*>(&Pw[r * 264 + k2 * 32 + g * 8]);
        #pragma unroll
        for (int n2 = 0; n2 < 4; n2++) {
            bf8_t vbf = *reinterpret_cast<const bf8_t*>(&Vt[n2 * 16 + r][k2 * 32 + g * 8]);
            acc2[n2] = __builtin_amdgcn_mfma_f32_16x16x32_bf16(pa, vbf, acc2[n2], 0, 0, 0);
        }
    }
    u16* op = attnout + ((size_t)(s * 4096 + b * 64 + w * 16 + g * 4)) * 768 + h * 64;
    #pragma unroll
    for (int n2 = 0; n2 < 4; n2++)
        #pragma unroll
        for (int i = 0; i < 4; i++)
            op[(size_t)i * 768 + n2 * 16 + r] = f2bf(acc2[n2][i]);
}

// ---------------- fusion_prep2: h-sum -> colmax -> nu, den partials -------
// grid (128 sb, 4 qc) x 256 threads; thread t owns k=t, 16 q-values.
__global__ __launch_bounds__(256) void fusion_prep2(
    const u16* __restrict__ paff, float* __restrict__ aff, float* __restrict__ den) {
    int sb = blockIdx.x, qc = blockIdx.y;
    int t = threadIdx.x, lane = t & 63, w = t >> 6;
    int q0 = qc * 16;
    float a[16];
    #pragma unroll
    for (int j = 0; j < 16; j++) a[j] = 0.f;
    size_t base = ((size_t)sb * 12 * 64 + q0) * 256 + t;
    for (int h = 0; h < 12; h++) {
        size_t hb = base + (size_t)h * 64 * 256;
        #pragma unroll
        for (int j = 0; j < 16; j++) a[j] += bf2f(paff[hb + j * 256]);
    }
    // colmax over k (all 256 threads) per q
    float m[16];
    #pragma unroll
    for (int j = 0; j < 16; j++) {
        float v = a[j];
        #pragma unroll
        for (int o = 1; o < 64; o <<= 1) v = fmaxf(v, __shfl_xor(v, o));
        m[j] = v;
    }
    __shared__ float red[16][4];
    if (lane == 0) {
        #pragma unroll
        for (int j = 0; j < 16; j++) red[j][w] = m[j];
    }
    __syncthreads();
    float dsum = 0.f;
    float nu[16];
    #pragma unroll
    for (int j = 0; j < 16; j++) {
        float cm = fmaxf(fmaxf(red[j][0], red[j][1]), fmaxf(red[j][2], red[j][3]));
        nu[j] = (a[j] == cm) ? __expf(a[j] - 12.0f) : 0.f;
        dsum += nu[j];
    }
    atomicAdd(&den[sb * 256 + t], dsum);
    float* ap = aff + ((size_t)sb * 256 + t) * 64 + q0;
    #pragma unroll
    for (int j = 0; j < 16; j++) ap[j] = nu[j];
}

// ---------------- fusion apply: write all of y ----------------
__global__ __launch_bounds__(256) void fusion_apply(
    const float* __restrict__ x0, const float* __restrict__ x1,
    const float* __restrict__ fz, const float* __restrict__ aff,
    const float* __restrict__ den, float* __restrict__ out) {
    int bid = blockIdx.x;  // s*20480 + b*320 + n
    int s = bid / 20480;
    int r2 = bid - s * 20480;
    int b = r2 / 320, n = r2 - (r2 / 320) * 320;
    int tid = threadIdx.x;
    float* orow = out + (size_t)bid * 768;
    const float* fzs = fz + (size_t)s * 4096 * 768;
    if (n < 64) {
        const float* zrow = fzs + ((size_t)(b * 64 + n)) * 768;
        orow[tid] = zrow[tid];
        orow[tid + 256] = zrow[tid + 256];
        orow[tid + 512] = zrow[tid + 512];
    } else {
        int sx = n - 64;
        const float* xrow = ((s == 0) ? x0 : x1) + ((size_t)(b * 320 + n)) * 768;
        float invd = 1.0f / (1.0f + den[(s * 64 + b) * 256 + sx]);
        __shared__ float nush[64];
        if (tid < 64) nush[tid] = aff[(((size_t)(s * 64 + b)) * 256 + sx) * 64 + tid];
        __syncthreads();
        float a0 = xrow[tid] * invd;
        float a1 = xrow[tid + 256] * invd;
        float a2 = xrow[tid + 512] * invd;
        for (int t = 0; t < 64; t++) {
            float nu = nush[t];
            if (nu != 0.f) {
                float wgt = nu * invd;
                const float* zr = fzs + ((size_t)(b * 64 + t)) * 768;
                a0 += wgt * zr[tid];
                a1 += wgt * zr[tid + 256];
                a2 += wgt * zr[tid + 512];
            }
        }
        orow[tid] = a0; orow[tid + 256] = a1; orow[tid + 512] = a2;
    }
}

extern "C" void kernel_launch(void* const* d_in, const int* in_sizes, int n_in,
                              void* d_out, int out_size, void* d_ws, size_t ws_size,
                              hipStream_t stream) {
    (void)in_sizes; (void)n_in; (void)out_size;
    const float* x0 = (const float*)d_in[0];
    const float* x1 = (const float*)d_in[1];
    const float* ln1w = (const float*)d_in[2];
    const float* ln1b = (const float*)d_in[3];
    const float* ln2w = (const float*)d_in[4];
    const float* ln2b = (const float*)d_in[5];
    const float* wq = (const float*)d_in[6];
    const float* wk = (const float*)d_in[7];
    const float* wv = (const float*)d_in[8];
    const float* wo = (const float*)d_in[9];
    const float* lora_down = (const float*)d_in[10];
    const float* lora_up = (const float*)d_in[11];
    const float* mlp_down = (const float*)d_in[12];
    const float* mlp_up = (const float*)d_in[13];
    float* out = (float*)d_out;

    char* ws = (char*)d_ws;
    size_t off = 0;
    auto alloc = [&](size_t bytes) -> char* {
        char* p = ws + off;
        off = (off + bytes + 255) & ~(size_t)255;
        return p;
    };
    u16* wtq = (u16*)alloc(768 * 768 * 2);
    u16* wtk = (u16*)alloc(768 * 768 * 2);
    u16* wtv = (u16*)alloc(768 * 768 * 2);
    u16* wto = (u16*)alloc(768 * 768 * 2);
    u16* dT  = (u16*)alloc(768 * 64 * 2);
    u16* uT  = (u16*)alloc(768 * 64 * 2);
    u16* mdT = (u16*)alloc(768 * 64 * 2);
    u16* muT = (u16*)alloc(768 * 64 * 2);
    u16* lnZ = (u16*)alloc((size_t)2 * 4096 * 768 * 2);    // region B start
    u16* lnX = (u16*)alloc((size_t)2 * 16384 * 768 * 2);   // contiguous with lnZ
    u16* qb  = (u16*)alloc((size_t)2 * 4096 * 768 * 2);    // region C (h2 aliases)
    u16* kb  = (u16*)alloc((size_t)2 * 16384 * 768 * 2);   // region D (fz aliases)
    u16* vb  = (u16*)alloc((size_t)2 * 16384 * 768 * 2);
    u16* ao  = (u16*)alloc((size_t)2 * 4096 * 768 * 2);
    float* aff = (float*)alloc((size_t)2 * 64 * 256 * 64 * 4);
    float* den = (float*)alloc((size_t)2 * 64 * 256 * 4);
    u16* h01 = (u16*)alloc((size_t)2 * 4096 * 64 * 2);
    // aliases (lifetimes disjoint by stream order):
    u16* ln2y = lnZ;               // 40960*768*2 == lnZ+lnX exactly
    u16* h2 = qb;                  // 40960*64*2  <= q region
    float* fz = (float*)kb;        // 2*4096*768*4 <= k region
    u16* paff = lnX;               // 2*768*64*256*2 == lnX region exactly (lnX dead after k/v proj)
    if (ws_size < off) return;     // ws too small -> leave poison (diagnosable)

    // 1. weight prep (batched)
    TPack big = {wq, wk, wv, wo, wtq, wtk, wtv, wto};
    transpose_big<<<dim3(2304, 4), 256, 0, stream>>>(big);
    TPack small = {lora_down, lora_up, mlp_down, mlp_up, dT, uT, mdT, muT};
    transpose_small<<<dim3(192, 4), 256, 0, stream>>>(small);
    hipMemsetAsync(den, 0, (size_t)2 * 64 * 256 * 4, stream);
    // 2. LN1
    ln1_kernel<<<40960, 256, 0, stream>>>(x0, x1, ln1w, ln1b, lnZ, lnX);
    // 3. projections; kv cross-stream via row^16384 on output
    gemm_bt<128, 128, 2, 2, EPI_BF16, 0><<<dim3(6, 64), 256, 0, stream>>>(
        lnZ, wtq, 8192, 768, 768, nullptr, qb, nullptr, nullptr);
    gemm_bt<128, 128, 2, 2, EPI_BF16, 16384><<<dim3(6, 256), 256, 0, stream>>>(
        lnX, wtk, 32768, 768, 768, nullptr, kb, nullptr, nullptr);
    gemm_bt<128, 128, 2, 2, EPI_BF16, 16384><<<dim3(6, 256), 256, 0, stream>>>(
        lnX, wtv, 32768, 768, 768, nullptr, vb, nullptr, nullptr);
    // 4. attention (MFMA, no atomics); paff overwrites dead lnX region
    attn_mfma<<<1536, 256, 0, stream>>>(qb, kb, vb, ao, paff);
    // 5. fusion prep (h-sum reduce + colmax + nu/den)
    fusion_prep2<<<dim3(128, 4), 256, 0, stream>>>(paff, aff, den);
    // 6. lora-z down -> h = [gelu(lnZ0@dT); gelu(lnZ1@dT)]; wo+resid; up with row^4096
    gemm_bt<128, 64, 2, 1, EPI_GELU, 0><<<dim3(1, 64), 128, 0, stream>>>(
        lnZ, dT, 8192, 64, 768, nullptr, h01, nullptr, nullptr);
    gemm_bt<128, 128, 2, 2, EPI_RESID, 0><<<dim3(6, 64), 256, 0, stream>>>(
        ao, wto, 8192, 768, 768, fz, nullptr, x0, x1);
    gemm_bt<128, 128, 2, 2, EPI_ACCUM, 4096><<<dim3(6, 64), 256, 0, stream>>>(
        h01, uT, 8192, 768, 64, fz, nullptr, nullptr, nullptr);
    // 7. fusion apply
    fusion_apply<<<40960, 256, 0, stream>>>(x0, x1, fz, aff, den, out);
    // 8. LN2 + mlp lora
    ln2_kernel<<<40960, 256, 0, stream>>>(out, ln2w, ln2b, ln2y);
    gemm_bt<128, 64, 2, 1, EPI_GELU, 0><<<dim3(1, 320), 128, 0, stream>>>(
        ln2y, mdT, 40960, 64, 768, nullptr, h2, nullptr, nullptr);
    gemm_bt<128, 128, 2, 2, EPI_ACCUM, 0><<<dim3(6, 320), 256, 0, stream>>>(
        h2, muT, 40960, 768, 64, out, nullptr, nullptr, nullptr);
}

// Round 4
// 513.471 us; speedup vs baseline: 1.9350x; 1.1274x over previous
//
#include <hip/hip_runtime.h>

// TMMixer: B=64, T=64, S=256, DIM=768, H=12, HD=64, RANK=64
// Pipeline (all bf16 MFMA GEMMs, f32 accumulation):
//  1. transpose weights -> bf16 (Bt layout: [n][k]) [2 batched kernels]
//  2. LN1 -> bf16
//  3. q/k/v projections (3 combined GEMMs; cross-stream via row^XORBIT)
//  4. attention per (s,b,h): MFMA QK^T -> wave-local softmax -> MFMA PV;
//     P dumped as bf16 to paff[sbh][q][k] (NO global atomics)
//  5. fusion_prep2: h-sum reduce -> colmax -> nu, den partials + winner bitmask
//  6. lora-z down (gelu); wo GEMM + resid -> out z-rows; lora-z up accum -> out z-rows
//  7. fusion_apply_x: x rows only; bitmask-gathered weighted z adds
//  8. LN2 + mlp lora into d_out

typedef __bf16 bf8_t __attribute__((ext_vector_type(8)));
typedef float f4_t __attribute__((ext_vector_type(4)));
typedef unsigned short u16;
typedef unsigned int u32;
typedef unsigned long long u64;
typedef unsigned short us8_t __attribute__((ext_vector_type(8)));

__device__ __forceinline__ float bf2f(u16 h) {
    return __uint_as_float(((unsigned int)h) << 16);
}
__device__ __forceinline__ u16 f2bf(float f) {
    unsigned int u = __float_as_uint(f);
    u += 0x7fffu + ((u >> 16) & 1u);
    return (u16)(u >> 16);
}
__device__ __forceinline__ float gelu_tanh(float x) {
    float t = tanhf(0.7978845608028654f * (x + 0.044715f * x * x * x));
    return 0.5f * x * (1.0f + t);
}

// ---------------- weight prep: dst[C][R] = bf16(src[R][C]) ----------------
struct TPack {
    const float* s0; const float* s1; const float* s2; const float* s3;
    u16* d0; u16* d1; u16* d2; u16* d3;
};
__global__ __launch_bounds__(256) void transpose_big(TPack p) {
    int which = blockIdx.y;
    const float* src = which == 0 ? p.s0 : which == 1 ? p.s1 : which == 2 ? p.s2 : p.s3;
    u16* dst = which == 0 ? p.d0 : which == 1 ? p.d1 : which == 2 ? p.d2 : p.d3;
    int idx = blockIdx.x * 256 + threadIdx.x;  // 768*768
    int c = idx / 768, r = idx - c * 768;
    dst[idx] = f2bf(src[(size_t)r * 768 + c]);
}
__global__ __launch_bounds__(256) void transpose_small(TPack p) {
    int which = blockIdx.y;
    const float* src = which == 0 ? p.s0 : which == 1 ? p.s1 : which == 2 ? p.s2 : p.s3;
    u16* dst = which == 0 ? p.d0 : which == 1 ? p.d1 : which == 2 ? p.d2 : p.d3;
    int R = (which & 1) ? 64 : 768;
    int C = (which & 1) ? 768 : 64;
    int idx = blockIdx.x * 256 + threadIdx.x;  // 49152
    int c = idx / R, r = idx - c * R;
    dst[idx] = f2bf(src[(size_t)r * C + c]);
}

// ---------------- LN1: 40960 rows; z rows then x rows per stream ----------
__global__ __launch_bounds__(256) void ln1_kernel(
    const float* __restrict__ x0, const float* __restrict__ x1,
    const float* __restrict__ w, const float* __restrict__ b,
    u16* __restrict__ lnZ, u16* __restrict__ lnX) {
    int rid = blockIdx.x;
    int s = rid / 20480;
    int r2 = rid - s * 20480;
    const float* srcBase = (s == 0) ? x0 : x1;
    const float* src; u16* dst;
    if (r2 < 4096) {
        int bb = r2 >> 6, t = r2 & 63;
        src = srcBase + ((size_t)(bb * 320 + t)) * 768;
        dst = lnZ + ((size_t)(s * 4096 + r2)) * 768;
    } else {
        int rx = r2 - 4096;
        int bb = rx >> 8, sx = rx & 255;
        src = srcBase + ((size_t)(bb * 320 + 64 + sx)) * 768;
        dst = lnX + ((size_t)(s * 16384 + rx)) * 768;
    }
    int tid = threadIdx.x;
    float xv0 = src[tid], xv1 = src[tid + 256], xv2 = src[tid + 512];
    float s1 = xv0 + xv1 + xv2;
    float s2 = xv0 * xv0 + xv1 * xv1 + xv2 * xv2;
    #pragma unroll
    for (int o = 1; o < 64; o <<= 1) { s1 += __shfl_xor(s1, o); s2 += __shfl_xor(s2, o); }
    __shared__ float red[2][4];
    int wv = tid >> 6;
    if ((tid & 63) == 0) { red[0][wv] = s1; red[1][wv] = s2; }
    __syncthreads();
    s1 = red[0][0] + red[0][1] + red[0][2] + red[0][3];
    s2 = red[1][0] + red[1][1] + red[1][2] + red[1][3];
    float mean = s1 * (1.0f / 768.0f);
    float var = s2 * (1.0f / 768.0f) - mean * mean;
    float rstd = rsqrtf(var + 1e-5f);
    dst[tid]       = f2bf((xv0 - mean) * rstd * w[tid]       + b[tid]);
    dst[tid + 256] = f2bf((xv1 - mean) * rstd * w[tid + 256] + b[tid + 256]);
    dst[tid + 512] = f2bf((xv2 - mean) * rstd * w[tid + 512] + b[tid + 512]);
}

// ---------------- LN2: contiguous rows from d_out ----------
__global__ __launch_bounds__(256) void ln2_kernel(
    const float* __restrict__ src0, const float* __restrict__ w,
    const float* __restrict__ b, u16* __restrict__ dst0) {
    int rid = blockIdx.x;
    const float* src = src0 + (size_t)rid * 768;
    u16* dst = dst0 + (size_t)rid * 768;
    int tid = threadIdx.x;
    float xv0 = src[tid], xv1 = src[tid + 256], xv2 = src[tid + 512];
    float s1 = xv0 + xv1 + xv2;
    float s2 = xv0 * xv0 + xv1 * xv1 + xv2 * xv2;
    #pragma unroll
    for (int o = 1; o < 64; o <<= 1) { s1 += __shfl_xor(s1, o); s2 += __shfl_xor(s2, o); }
    __shared__ float red[2][4];
    int wv = tid >> 6;
    if ((tid & 63) == 0) { red[0][wv] = s1; red[1][wv] = s2; }
    __syncthreads();
    s1 = red[0][0] + red[0][1] + red[0][2] + red[0][3];
    s2 = red[1][0] + red[1][1] + red[1][2] + red[1][3];
    float mean = s1 * (1.0f / 768.0f);
    float var = s2 * (1.0f / 768.0f) - mean * mean;
    float rstd = rsqrtf(var + 1e-5f);
    dst[tid]       = f2bf((xv0 - mean) * rstd * w[tid]       + b[tid]);
    dst[tid + 256] = f2bf((xv1 - mean) * rstd * w[tid + 256] + b[tid + 256]);
    dst[tid + 512] = f2bf((xv2 - mean) * rstd * w[tid + 512] + b[tid + 512]);
}

// ---------------- MFMA GEMM: C = A(MxK) * Bt(NxK)^T, epilogues -----------
// EPI_*_Z map row (s<<12 | b<<6 | t) to out row s*20480 + b*320 + t.
enum { EPI_BF16 = 0, EPI_RESID_Z = 1, EPI_GELU = 2, EPI_ACCUM = 3, EPI_ACCUM_Z = 4 };

template <int BM, int BN, int WR, int WC, int EPI, int XB>
__global__ __launch_bounds__(WR * WC * 64, 1) void gemm_bt(
    const u16* __restrict__ A, const u16* __restrict__ Bt,
    int M, int N, int K,
    float* __restrict__ Cf, u16* __restrict__ Cbf,
    const float* __restrict__ resid0, const float* __restrict__ resid1) {
    constexpr int THREADS = WR * WC * 64;
    constexpr int BK = 64;
    __shared__ alignas(16) u16 As[BM][BK + 8];
    __shared__ alignas(16) u16 Bs[BN][BK + 8];

    const int tid = threadIdx.x;
    const int lane = tid & 63;
    const int w = tid >> 6;
    const int wr = w / WC, wc = w % WC;
    const int r = lane & 15, g = lane >> 4;
    const int brow = blockIdx.y * BM;
    const int bcol = blockIdx.x * BN;

    f4_t acc[4][4];
    f4_t zero = {0.f, 0.f, 0.f, 0.f};
    #pragma unroll
    for (int m = 0; m < 4; m++)
        #pragma unroll
        for (int n = 0; n < 4; n++) acc[m][n] = zero;

    for (int k0 = 0; k0 < K; k0 += BK) {
        constexpr int CA = BM * BK / 8;
        #pragma unroll
        for (int i = 0; i < CA / THREADS; i++) {
            int c = tid + THREADS * i;
            int row = c >> 3, kc = (c & 7) * 8;
            bf8_t val = *reinterpret_cast<const bf8_t*>(A + (size_t)(brow + row) * K + k0 + kc);
            *reinterpret_cast<bf8_t*>(&As[row][kc]) = val;
        }
        constexpr int CB = BN * BK / 8;
        #pragma unroll
        for (int i = 0; i < CB / THREADS; i++) {
            int c = tid + THREADS * i;
            int row = c >> 3, kc = (c & 7) * 8;
            bf8_t val = *reinterpret_cast<const bf8_t*>(Bt + (size_t)(bcol + row) * K + k0 + kc);
            *reinterpret_cast<bf8_t*>(&Bs[row][kc]) = val;
        }
        __syncthreads();
        #pragma unroll
        for (int ks = 0; ks < BK; ks += 32) {
            bf8_t af[4], bfr[4];
            #pragma unroll
            for (int m = 0; m < 4; m++)
                af[m] = *reinterpret_cast<const bf8_t*>(&As[wr * 64 + m * 16 + r][ks + g * 8]);
            #pragma unroll
            for (int n = 0; n < 4; n++)
                bfr[n] = *reinterpret_cast<const bf8_t*>(&Bs[wc * 64 + n * 16 + r][ks + g * 8]);
            #pragma unroll
            for (int m = 0; m < 4; m++)
                #pragma unroll
                for (int n = 0; n < 4; n++)
                    acc[m][n] = __builtin_amdgcn_mfma_f32_16x16x32_bf16(af[m], bfr[n], acc[m][n], 0, 0, 0);
        }
        __syncthreads();
    }

    #pragma unroll
    for (int m = 0; m < 4; m++) {
        #pragma unroll
        for (int n = 0; n < 4; n++) {
            int col = bcol + wc * 64 + n * 16 + r;
            #pragma unroll
            for (int i = 0; i < 4; i++) {
                int row = brow + wr * 64 + m * 16 + g * 4 + i;
                int orow = row ^ XB;
                float val = acc[m][n][i];
                if constexpr (EPI == EPI_BF16) {
                    Cbf[(size_t)orow * N + col] = f2bf(val);
                } else if constexpr (EPI == EPI_RESID_Z) {
                    int s = orow >> 12, bb = (orow >> 6) & 63, t = orow & 63;
                    const float* rp = (s != 0) ? resid1 : resid0;
                    float rs = rp[((size_t)bb * 320 + t) * 768 + col];
                    Cf[((size_t)s * 20480 + bb * 320 + t) * 768 + col] = val + rs;
                } else if constexpr (EPI == EPI_GELU) {
                    Cbf[(size_t)orow * N + col] = f2bf(gelu_tanh(val));
                } else if constexpr (EPI == EPI_ACCUM_Z) {
                    int s = orow >> 12, bb = (orow >> 6) & 63, t = orow & 63;
                    Cf[((size_t)s * 20480 + bb * 320 + t) * 768 + col] += val;
                } else {
                    Cf[(size_t)orow * N + col] += val;
                }
            }
        }
    }
}

// ---------------- MFMA attention per (s,b,h) ------------------------------
__global__ __launch_bounds__(256, 2) void attn_mfma(
    const u16* __restrict__ q, const u16* __restrict__ k,
    const u16* __restrict__ v, u16* __restrict__ attnout,
    u16* __restrict__ paff) {
    __shared__ alignas(16) u16 Ks[256][72];   // 36,864 B (P tiles alias after sync)
    __shared__ alignas(16) u16 Vt[64][264];   // 33,792 B
    int bid = blockIdx.x;
    int s = bid / 768;
    int rem = bid - s * 768;
    int b = rem / 12, h = rem - (rem / 12) * 12;
    int tid = threadIdx.x, lane = tid & 63, w = tid >> 6;
    int r = lane & 15, g = lane >> 4;

    size_t kvbase = ((size_t)(s * 16384 + b * 256)) * 768 + h * 64;

    const u16* qrow = q + ((size_t)(s * 4096 + b * 64 + w * 16 + r)) * 768 + h * 64 + g * 8;
    bf8_t qf0 = *reinterpret_cast<const bf8_t*>(qrow);
    bf8_t qf1 = *reinterpret_cast<const bf8_t*>(qrow + 32);

    #pragma unroll
    for (int i = 0; i < 8; i++) {
        int c = tid + 256 * i;
        int row = c >> 3, kc = (c & 7) * 8;
        *reinterpret_cast<bf8_t*>(&Ks[row][kc]) =
            *reinterpret_cast<const bf8_t*>(k + kvbase + (size_t)row * 768 + kc);
    }
    u32* vt32 = reinterpret_cast<u32*>(&Vt[0][0]);  // row stride 132 u32
    #pragma unroll
    for (int i = 0; i < 4; i++) {
        int c = tid + 256 * i;
        int kp = c >> 3, d0 = (c & 7) * 8;
        const u16* vr = v + kvbase + (size_t)(2 * kp) * 768 + d0;
        us8_t va = *reinterpret_cast<const us8_t*>(vr);
        us8_t vb = *reinterpret_cast<const us8_t*>(vr + 768);
        #pragma unroll
        for (int j = 0; j < 8; j++)
            vt32[(d0 + j) * 132 + kp] = (u32)va[j] | ((u32)vb[j] << 16);
    }
    __syncthreads();

    f4_t acc[16];
    f4_t zero = {0.f, 0.f, 0.f, 0.f};
    #pragma unroll
    for (int n = 0; n < 16; n++) acc[n] = zero;
    #pragma unroll
    for (int n = 0; n < 16; n++) {
        bf8_t b0 = *reinterpret_cast<const bf8_t*>(&Ks[n * 16 + r][g * 8]);
        acc[n] = __builtin_amdgcn_mfma_f32_16x16x32_bf16(qf0, b0, acc[n], 0, 0, 0);
        bf8_t b1 = *reinterpret_cast<const bf8_t*>(&Ks[n * 16 + r][32 + g * 8]);
        acc[n] = __builtin_amdgcn_mfma_f32_16x16x32_bf16(qf1, b1, acc[n], 0, 0, 0);
    }

    float mx[4] = {-1e30f, -1e30f, -1e30f, -1e30f};
    #pragma unroll
    for (int n = 0; n < 16; n++)
        #pragma unroll
        for (int i = 0; i < 4; i++) {
            acc[n][i] *= 0.125f;
            mx[i] = fmaxf(mx[i], acc[n][i]);
        }
    #pragma unroll
    for (int i = 0; i < 4; i++) {
        mx[i] = fmaxf(mx[i], __shfl_xor(mx[i], 1));
        mx[i] = fmaxf(mx[i], __shfl_xor(mx[i], 2));
        mx[i] = fmaxf(mx[i], __shfl_xor(mx[i], 4));
        mx[i] = fmaxf(mx[i], __shfl_xor(mx[i], 8));
    }
    float sm[4] = {0.f, 0.f, 0.f, 0.f};
    #pragma unroll
    for (int n = 0; n < 16; n++)
        #pragma unroll
        for (int i = 0; i < 4; i++) {
            float e = __expf(acc[n][i] - mx[i]);
            acc[n][i] = e;
            sm[i] += e;
        }
    #pragma unroll
    for (int i = 0; i < 4; i++) {
        sm[i] += __shfl_xor(sm[i], 1);
        sm[i] += __shfl_xor(sm[i], 2);
        sm[i] += __shfl_xor(sm[i], 4);
        sm[i] += __shfl_xor(sm[i], 8);
    }
    float inv[4];
    #pragma unroll
    for (int i = 0; i < 4; i++) inv[i] = 1.0f / sm[i];

    __syncthreads();  // all waves done reading Ks; safe to overwrite with P

    u16* Pw = &Ks[w * 64][0];
    u16* pout = paff + ((size_t)bid * 64 + w * 16) * 256;
    #pragma unroll
    for (int n = 0; n < 16; n++) {
        int kcol = n * 16 + r;
        #pragma unroll
        for (int i = 0; i < 4; i++) {
            u16 pb = f2bf(acc[n][i] * inv[i]);
            Pw[(g * 4 + i) * 264 + kcol] = pb;
            pout[(g * 4 + i) * 256 + kcol] = pb;
        }
    }

    f4_t acc2[4];
    #pragma unroll
    for (int n = 0; n < 4; n++) acc2[n] = zero;
    #pragma unroll
    for (int k2 = 0; k2 < 8; k2++) {
        bf8_t pa = *reinterpret_cast<const bf8_t*>(&Pw[r * 264 + k2 * 32 + g * 8]);
        #pragma unroll
        for (int n2 = 0; n2 < 4; n2++) {
            bf8_t vbf = *reinterpret_cast<const bf8_t*>(&Vt[n2 * 16 + r][k2 * 32 + g * 8]);
            acc2[n2] = __builtin_amdgcn_mfma_f32_16x16x32_bf16(pa, vbf, acc2[n2], 0, 0, 0);
        }
    }
    u16* op = attnout + ((size_t)(s * 4096 + b * 64 + w * 16 + g * 4)) * 768 + h * 64;
    #pragma unroll
    for (int n2 = 0; n2 < 4; n2++)
        #pragma unroll
        for (int i = 0; i < 4; i++)
            op[(size_t)i * 768 + n2 * 16 + r] = f2bf(acc2[n2][i]);
}

// ---------------- fusion_prep2: h-sum -> colmax -> nu/den + winner bitmask -
// grid (128 sb, 4 qc) x 256 threads; thread t owns s-row=t, 16 q-columns.
__global__ __launch_bounds__(256) void fusion_prep2(
    const u16* __restrict__ paff, float* __restrict__ aff, float* __restrict__ den,
    u64* __restrict__ winners) {
    int sb = blockIdx.x, qc = blockIdx.y;
    int t = threadIdx.x, lane = t & 63, w = t >> 6;
    int q0 = qc * 16;
    float a[16];
    #pragma unroll
    for (int j = 0; j < 16; j++) a[j] = 0.f;
    size_t base = ((size_t)sb * 12 * 64 + q0) * 256 + t;
    for (int h = 0; h < 12; h++) {
        size_t hb = base + (size_t)h * 64 * 256;
        #pragma unroll
        for (int j = 0; j < 16; j++) a[j] += bf2f(paff[hb + j * 256]);
    }
    float m[16];
    #pragma unroll
    for (int j = 0; j < 16; j++) {
        float v = a[j];
        #pragma unroll
        for (int o = 1; o < 64; o <<= 1) v = fmaxf(v, __shfl_xor(v, o));
        m[j] = v;
    }
    __shared__ float red[16][4];
    if (lane == 0) {
        #pragma unroll
        for (int j = 0; j < 16; j++) red[j][w] = m[j];
    }
    __syncthreads();
    float dsum = 0.f;
    u64 wmask = 0;
    float nu[16];
    #pragma unroll
    for (int j = 0; j < 16; j++) {
        float cm = fmaxf(fmaxf(red[j][0], red[j][1]), fmaxf(red[j][2], red[j][3]));
        nu[j] = (a[j] == cm) ? __expf(a[j] - 12.0f) : 0.f;
        if (nu[j] != 0.f) wmask |= (u64)1 << (q0 + j);
        dsum += nu[j];
    }
    if (dsum != 0.f) atomicAdd(&den[sb * 256 + t], dsum);
    if (wmask) atomicOr(&winners[(size_t)sb * 256 + t], wmask);
    float* ap = aff + ((size_t)sb * 256 + t) * 64 + q0;
    #pragma unroll
    for (int j = 0; j < 16; j++) ap[j] = nu[j];
}

// ---------------- fusion_apply_x: x rows only, bitmask gather -------------
__global__ __launch_bounds__(192) void fusion_apply_x(
    const float* __restrict__ x0, const float* __restrict__ x1,
    const float* __restrict__ aff, const float* __restrict__ den,
    const u64* __restrict__ winners, float* out) {
    int bid = blockIdx.x;          // 0..32767
    int s = bid >> 14;
    int rx = bid & 16383;
    int b = rx >> 8, sx = rx & 255;
    int sb = s * 64 + b;
    int tid = threadIdx.x;
    const float* xrow = ((s == 0) ? x0 : x1) + ((size_t)(b * 320 + 64 + sx)) * 768;
    float* orow = out + ((size_t)(s * 20480 + b * 320 + 64 + sx)) * 768;
    u64 mask = winners[(size_t)sb * 256 + sx];
    float invd = 1.0f / (1.0f + den[sb * 256 + sx]);
    f4_t a = *reinterpret_cast<const f4_t*>(xrow + tid * 4) * invd;
    while (mask) {
        int t = (int)__builtin_ctzll(mask);
        mask &= mask - 1;
        float nu = aff[((size_t)sb * 256 + sx) * 64 + t];
        float wgt = nu * invd;
        const float* zr = out + ((size_t)(s * 20480 + b * 320 + t)) * 768;
        f4_t z = *reinterpret_cast<const f4_t*>(zr + tid * 4);
        a += z * wgt;
    }
    *reinterpret_cast<f4_t*>(orow + tid * 4) = a;
}

extern "C" void kernel_launch(void* const* d_in, const int* in_sizes, int n_in,
                              void* d_out, int out_size, void* d_ws, size_t ws_size,
                              hipStream_t stream) {
    (void)in_sizes; (void)n_in; (void)out_size;
    const float* x0 = (const float*)d_in[0];
    const float* x1 = (const float*)d_in[1];
    const float* ln1w = (const float*)d_in[2];
    const float* ln1b = (const float*)d_in[3];
    const float* ln2w = (const float*)d_in[4];
    const float* ln2b = (const float*)d_in[5];
    const float* wq = (const float*)d_in[6];
    const float* wk = (const float*)d_in[7];
    const float* wv = (const float*)d_in[8];
    const float* wo = (const float*)d_in[9];
    const float* lora_down = (const float*)d_in[10];
    const float* lora_up = (const float*)d_in[11];
    const float* mlp_down = (const float*)d_in[12];
    const float* mlp_up = (const float*)d_in[13];
    float* out = (float*)d_out;

    char* ws = (char*)d_ws;
    size_t off = 0;
    auto alloc = [&](size_t bytes) -> char* {
        char* p = ws + off;
        off = (off + bytes + 255) & ~(size_t)255;
        return p;
    };
    u16* wtq = (u16*)alloc(768 * 768 * 2);
    u16* wtk = (u16*)alloc(768 * 768 * 2);
    u16* wtv = (u16*)alloc(768 * 768 * 2);
    u16* wto = (u16*)alloc(768 * 768 * 2);
    u16* dT  = (u16*)alloc(768 * 64 * 2);
    u16* uT  = (u16*)alloc(768 * 64 * 2);
    u16* mdT = (u16*)alloc(768 * 64 * 2);
    u16* muT = (u16*)alloc(768 * 64 * 2);
    u16* lnZ = (u16*)alloc((size_t)2 * 4096 * 768 * 2);    // region B start
    u16* lnX = (u16*)alloc((size_t)2 * 16384 * 768 * 2);   // contiguous with lnZ
    u16* qb  = (u16*)alloc((size_t)2 * 4096 * 768 * 2);    // region C (h2 aliases)
    u16* kb  = (u16*)alloc((size_t)2 * 16384 * 768 * 2);
    u16* vb  = (u16*)alloc((size_t)2 * 16384 * 768 * 2);
    u16* ao  = (u16*)alloc((size_t)2 * 4096 * 768 * 2);
    float* aff = (float*)alloc((size_t)2 * 64 * 256 * 64 * 4);
    float* den = (float*)alloc((size_t)2 * 64 * 256 * 4);
    u64* winners = (u64*)alloc((size_t)2 * 64 * 256 * 8);
    u16* h01 = (u16*)alloc((size_t)2 * 4096 * 64 * 2);
    // aliases (lifetimes disjoint by stream order):
    u16* ln2y = lnZ;               // 40960*768*2 == lnZ+lnX exactly
    u16* h2 = qb;                  // 40960*64*2  <= q region
    u16* paff = lnX;               // 2*768*64*256*2 == lnX region exactly (lnX dead after k/v proj)
    if (ws_size < off) return;     // ws too small -> leave poison (diagnosable)

    // 1. weight prep (batched)
    TPack big = {wq, wk, wv, wo, wtq, wtk, wtv, wto};
    transpose_big<<<dim3(2304, 4), 256, 0, stream>>>(big);
    TPack small = {lora_down, lora_up, mlp_down, mlp_up, dT, uT, mdT, muT};
    transpose_small<<<dim3(192, 4), 256, 0, stream>>>(small);
    hipMemsetAsync(den, 0, (size_t)2 * 64 * 256 * 4, stream);
    hipMemsetAsync(winners, 0, (size_t)2 * 64 * 256 * 8, stream);
    // 2. LN1
    ln1_kernel<<<40960, 256, 0, stream>>>(x0, x1, ln1w, ln1b, lnZ, lnX);
    // 3. projections; kv cross-stream via row^16384 on output
    gemm_bt<128, 128, 2, 2, EPI_BF16, 0><<<dim3(6, 64), 256, 0, stream>>>(
        lnZ, wtq, 8192, 768, 768, nullptr, qb, nullptr, nullptr);
    gemm_bt<128, 128, 2, 2, EPI_BF16, 16384><<<dim3(6, 256), 256, 0, stream>>>(
        lnX, wtk, 32768, 768, 768, nullptr, kb, nullptr, nullptr);
    gemm_bt<128, 128, 2, 2, EPI_BF16, 16384><<<dim3(6, 256), 256, 0, stream>>>(
        lnX, wtv, 32768, 768, 768, nullptr, vb, nullptr, nullptr);
    // 4. attention (MFMA, no atomics); paff overwrites dead lnX region
    attn_mfma<<<1536, 256, 0, stream>>>(qb, kb, vb, ao, paff);
    // 5. fusion prep (h-sum reduce + colmax + nu/den/winners)
    fusion_prep2<<<dim3(128, 4), 256, 0, stream>>>(paff, aff, den, winners);
    // 6. lora-z down; wo GEMM + resid -> out z rows; lora-z up accum -> out z rows
    gemm_bt<128, 64, 2, 1, EPI_GELU, 0><<<dim3(1, 64), 128, 0, stream>>>(
        lnZ, dT, 8192, 64, 768, nullptr, h01, nullptr, nullptr);
    gemm_bt<128, 128, 2, 2, EPI_RESID_Z, 0><<<dim3(6, 64), 256, 0, stream>>>(
        ao, wto, 8192, 768, 768, out, nullptr, x0, x1);
    gemm_bt<128, 128, 2, 2, EPI_ACCUM_Z, 4096><<<dim3(6, 64), 256, 0, stream>>>(
        h01, uT, 8192, 768, 64, out, nullptr, nullptr, nullptr);
    // 7. fusion apply (x rows only; z rows already final in out)
    fusion_apply_x<<<32768, 192, 0, stream>>>(x0, x1, aff, den, winners, out);
    // 8. LN2 + mlp lora
    ln2_kernel<<<40960, 256, 0, stream>>>(out, ln2w, ln2b, ln2y);
    gemm_bt<128, 64, 2, 1, EPI_GELU, 0><<<dim3(1, 320), 128, 0, stream>>>(
        ln2y, mdT, 40960, 64, 768, nullptr, h2, nullptr, nullptr);
    gemm_bt<128, 128, 2, 2, EPI_ACCUM, 0><<<dim3(6, 320), 256, 0, stream>>>(
        h2, muT, 40960, 768, 64, out, nullptr, nullptr, nullptr);
}

// Round 5
// 445.866 us; speedup vs baseline: 2.2284x; 1.1516x over previous
//
#include <hip/hip_runtime.h>

// TMMixer: B=64, T=64, S=256, DIM=768, H=12, HD=64, RANK=64
// Pipeline (all bf16 MFMA GEMMs, f32 accumulation):
//  1. transpose weights -> bf16 (Bt layout: [n][k]) [2 batched kernels]
//  2. LN1 -> bf16 (f4 vectorized, wave-per-row)
//  3. q/k/v projections (3 combined GEMMs; cross-stream via row^XORBIT)
//  4. attention per (s,b,h): MFMA QK^T -> wave-local softmax -> MFMA PV;
//     P dumped as bf16 to paff[sbh][q][k] (NO global atomics)
//  5. fusion_prep2: h-sum reduce -> colmax -> nu, den partials + winner bitmask
//  6. lora-z down (gelu); wo GEMM + resid -> out z-rows; lora-z up accum -> out z-rows
//  7. fusion_apply_x: x rows only; bitmask-gathered weighted z adds
//  8. ln2_mlp: fused LN2 + mlp-down(gelu) + mlp-up accumulate, in-place on out

typedef __bf16 bf8_t __attribute__((ext_vector_type(8)));
typedef float f4_t __attribute__((ext_vector_type(4)));
typedef unsigned short u16;
typedef unsigned int u32;
typedef unsigned long long u64;
typedef unsigned short us4_t __attribute__((ext_vector_type(4)));
typedef unsigned short us8_t __attribute__((ext_vector_type(8)));

__device__ __forceinline__ float bf2f(u16 h) {
    return __uint_as_float(((unsigned int)h) << 16);
}
__device__ __forceinline__ u16 f2bf(float f) {
    unsigned int u = __float_as_uint(f);
    u += 0x7fffu + ((u >> 16) & 1u);
    return (u16)(u >> 16);
}
__device__ __forceinline__ float gelu_tanh(float x) {
    float t = tanhf(0.7978845608028654f * (x + 0.044715f * x * x * x));
    return 0.5f * x * (1.0f + t);
}

// ---------------- weight prep: dst[C][R] = bf16(src[R][C]) ----------------
struct TPack {
    const float* s0; const float* s1; const float* s2; const float* s3;
    u16* d0; u16* d1; u16* d2; u16* d3;
};
__global__ __launch_bounds__(256) void transpose_big(TPack p) {
    int which = blockIdx.y;
    const float* src = which == 0 ? p.s0 : which == 1 ? p.s1 : which == 2 ? p.s2 : p.s3;
    u16* dst = which == 0 ? p.d0 : which == 1 ? p.d1 : which == 2 ? p.d2 : p.d3;
    int idx = blockIdx.x * 256 + threadIdx.x;  // 768*768
    int c = idx / 768, r = idx - c * 768;
    dst[idx] = f2bf(src[(size_t)r * 768 + c]);
}
__global__ __launch_bounds__(256) void transpose_small(TPack p) {
    int which = blockIdx.y;
    const float* src = which == 0 ? p.s0 : which == 1 ? p.s1 : which == 2 ? p.s2 : p.s3;
    u16* dst = which == 0 ? p.d0 : which == 1 ? p.d1 : which == 2 ? p.d2 : p.d3;
    int R = (which & 1) ? 64 : 768;
    int C = (which & 1) ? 768 : 64;
    int idx = blockIdx.x * 256 + threadIdx.x;  // 49152
    int c = idx / R, r = idx - c * R;
    dst[idx] = f2bf(src[(size_t)r * C + c]);
}

// ---------------- LN1: wave-per-row, f4 loads ----------
__global__ __launch_bounds__(256) void ln1_kernel(
    const float* __restrict__ x0, const float* __restrict__ x1,
    const float* __restrict__ w, const float* __restrict__ b,
    u16* __restrict__ lnZ, u16* __restrict__ lnX) {
    int rid = blockIdx.x * 4 + (threadIdx.x >> 6);
    int lane = threadIdx.x & 63;
    int s = rid / 20480;
    int r2 = rid - s * 20480;
    const float* srcBase = (s == 0) ? x0 : x1;
    const float* src; u16* dst;
    if (r2 < 4096) {
        int bb = r2 >> 6, t = r2 & 63;
        src = srcBase + ((size_t)(bb * 320 + t)) * 768;
        dst = lnZ + ((size_t)(s * 4096 + r2)) * 768;
    } else {
        int rx = r2 - 4096;
        int bb = rx >> 8, sx = rx & 255;
        src = srcBase + ((size_t)(bb * 320 + 64 + sx)) * 768;
        dst = lnX + ((size_t)(s * 16384 + rx)) * 768;
    }
    f4_t v[3];
    float s1 = 0.f, s2 = 0.f;
    #pragma unroll
    for (int jj = 0; jj < 3; jj++) {
        v[jj] = *reinterpret_cast<const f4_t*>(src + (lane + 64 * jj) * 4);
        #pragma unroll
        for (int e = 0; e < 4; e++) { s1 += v[jj][e]; s2 += v[jj][e] * v[jj][e]; }
    }
    #pragma unroll
    for (int o = 1; o < 64; o <<= 1) { s1 += __shfl_xor(s1, o); s2 += __shfl_xor(s2, o); }
    float mean = s1 * (1.0f / 768.0f);
    float var = s2 * (1.0f / 768.0f) - mean * mean;
    float rstd = rsqrtf(var + 1e-5f);
    #pragma unroll
    for (int jj = 0; jj < 3; jj++) {
        int c0 = (lane + 64 * jj) * 4;
        f4_t wv = *reinterpret_cast<const f4_t*>(w + c0);
        f4_t bv = *reinterpret_cast<const f4_t*>(b + c0);
        us4_t o4;
        #pragma unroll
        for (int e = 0; e < 4; e++)
            o4[e] = f2bf((v[jj][e] - mean) * rstd * wv[e] + bv[e]);
        *reinterpret_cast<us4_t*>(dst + c0) = o4;
    }
}

// ---------------- MFMA GEMM: C = A(MxK) * Bt(NxK)^T, epilogues -----------
// EPI_*_Z map row (s<<12 | b<<6 | t) to out row s*20480 + b*320 + t.
enum { EPI_BF16 = 0, EPI_RESID_Z = 1, EPI_GELU = 2, EPI_ACCUM = 3, EPI_ACCUM_Z = 4 };

template <int BM, int BN, int WR, int WC, int EPI, int XB>
__global__ __launch_bounds__(WR * WC * 64, 1) void gemm_bt(
    const u16* __restrict__ A, const u16* __restrict__ Bt,
    int M, int N, int K,
    float* __restrict__ Cf, u16* __restrict__ Cbf,
    const float* __restrict__ resid0, const float* __restrict__ resid1) {
    constexpr int THREADS = WR * WC * 64;
    constexpr int BK = 64;
    __shared__ alignas(16) u16 As[BM][BK + 8];
    __shared__ alignas(16) u16 Bs[BN][BK + 8];

    const int tid = threadIdx.x;
    const int lane = tid & 63;
    const int w = tid >> 6;
    const int wr = w / WC, wc = w % WC;
    const int r = lane & 15, g = lane >> 4;
    const int brow = blockIdx.y * BM;
    const int bcol = blockIdx.x * BN;

    f4_t acc[4][4];
    f4_t zero = {0.f, 0.f, 0.f, 0.f};
    #pragma unroll
    for (int m = 0; m < 4; m++)
        #pragma unroll
        for (int n = 0; n < 4; n++) acc[m][n] = zero;

    for (int k0 = 0; k0 < K; k0 += BK) {
        constexpr int CA = BM * BK / 8;
        #pragma unroll
        for (int i = 0; i < CA / THREADS; i++) {
            int c = tid + THREADS * i;
            int row = c >> 3, kc = (c & 7) * 8;
            bf8_t val = *reinterpret_cast<const bf8_t*>(A + (size_t)(brow + row) * K + k0 + kc);
            *reinterpret_cast<bf8_t*>(&As[row][kc]) = val;
        }
        constexpr int CB = BN * BK / 8;
        #pragma unroll
        for (int i = 0; i < CB / THREADS; i++) {
            int c = tid + THREADS * i;
            int row = c >> 3, kc = (c & 7) * 8;
            bf8_t val = *reinterpret_cast<const bf8_t*>(Bt + (size_t)(bcol + row) * K + k0 + kc);
            *reinterpret_cast<bf8_t*>(&Bs[row][kc]) = val;
        }
        __syncthreads();
        #pragma unroll
        for (int ks = 0; ks < BK; ks += 32) {
            bf8_t af[4], bfr[4];
            #pragma unroll
            for (int m = 0; m < 4; m++)
                af[m] = *reinterpret_cast<const bf8_t*>(&As[wr * 64 + m * 16 + r][ks + g * 8]);
            #pragma unroll
            for (int n = 0; n < 4; n++)
                bfr[n] = *reinterpret_cast<const bf8_t*>(&Bs[wc * 64 + n * 16 + r][ks + g * 8]);
            #pragma unroll
            for (int m = 0; m < 4; m++)
                #pragma unroll
                for (int n = 0; n < 4; n++)
                    acc[m][n] = __builtin_amdgcn_mfma_f32_16x16x32_bf16(af[m], bfr[n], acc[m][n], 0, 0, 0);
        }
        __syncthreads();
    }

    #pragma unroll
    for (int m = 0; m < 4; m++) {
        #pragma unroll
        for (int n = 0; n < 4; n++) {
            int col = bcol + wc * 64 + n * 16 + r;
            #pragma unroll
            for (int i = 0; i < 4; i++) {
                int row = brow + wr * 64 + m * 16 + g * 4 + i;
                int orow = row ^ XB;
                float val = acc[m][n][i];
                if constexpr (EPI == EPI_BF16) {
                    Cbf[(size_t)orow * N + col] = f2bf(val);
                } else if constexpr (EPI == EPI_RESID_Z) {
                    int s = orow >> 12, bb = (orow >> 6) & 63, t = orow & 63;
                    const float* rp = (s != 0) ? resid1 : resid0;
                    float rs = rp[((size_t)bb * 320 + t) * 768 + col];
                    Cf[((size_t)s * 20480 + bb * 320 + t) * 768 + col] = val + rs;
                } else if constexpr (EPI == EPI_GELU) {
                    Cbf[(size_t)orow * N + col] = f2bf(gelu_tanh(val));
                } else if constexpr (EPI == EPI_ACCUM_Z) {
                    int s = orow >> 12, bb = (orow >> 6) & 63, t = orow & 63;
                    Cf[((size_t)s * 20480 + bb * 320 + t) * 768 + col] += val;
                } else {
                    Cf[(size_t)orow * N + col] += val;
                }
            }
        }
    }
}

// ---------------- MFMA attention per (s,b,h) ------------------------------
__global__ __launch_bounds__(256, 2) void attn_mfma(
    const u16* __restrict__ q, const u16* __restrict__ k,
    const u16* __restrict__ v, u16* __restrict__ attnout,
    u16* __restrict__ paff) {
    __shared__ alignas(16) u16 Ks[256][72];   // 36,864 B (P tiles alias after sync)
    __shared__ alignas(16) u16 Vt[64][264];   // 33,792 B
    int bid = blockIdx.x;
    int s = bid / 768;
    int rem = bid - s * 768;
    int b = rem / 12, h = rem - (rem / 12) * 12;
    int tid = threadIdx.x, lane = tid & 63, w = tid >> 6;
    int r = lane & 15, g = lane >> 4;

    size_t kvbase = ((size_t)(s * 16384 + b * 256)) * 768 + h * 64;

    const u16* qrow = q + ((size_t)(s * 4096 + b * 64 + w * 16 + r)) * 768 + h * 64 + g * 8;
    bf8_t qf0 = *reinterpret_cast<const bf8_t*>(qrow);
    bf8_t qf1 = *reinterpret_cast<const bf8_t*>(qrow + 32);

    #pragma unroll
    for (int i = 0; i < 8; i++) {
        int c = tid + 256 * i;
        int row = c >> 3, kc = (c & 7) * 8;
        *reinterpret_cast<bf8_t*>(&Ks[row][kc]) =
            *reinterpret_cast<const bf8_t*>(k + kvbase + (size_t)row * 768 + kc);
    }
    u32* vt32 = reinterpret_cast<u32*>(&Vt[0][0]);  // row stride 132 u32
    #pragma unroll
    for (int i = 0; i < 4; i++) {
        int c = tid + 256 * i;
        int kp = c >> 3, d0 = (c & 7) * 8;
        const u16* vr = v + kvbase + (size_t)(2 * kp) * 768 + d0;
        us8_t va = *reinterpret_cast<const us8_t*>(vr);
        us8_t vb = *reinterpret_cast<const us8_t*>(vr + 768);
        #pragma unroll
        for (int j = 0; j < 8; j++)
            vt32[(d0 + j) * 132 + kp] = (u32)va[j] | ((u32)vb[j] << 16);
    }
    __syncthreads();

    f4_t acc[16];
    f4_t zero = {0.f, 0.f, 0.f, 0.f};
    #pragma unroll
    for (int n = 0; n < 16; n++) acc[n] = zero;
    #pragma unroll
    for (int n = 0; n < 16; n++) {
        bf8_t b0 = *reinterpret_cast<const bf8_t*>(&Ks[n * 16 + r][g * 8]);
        acc[n] = __builtin_amdgcn_mfma_f32_16x16x32_bf16(qf0, b0, acc[n], 0, 0, 0);
        bf8_t b1 = *reinterpret_cast<const bf8_t*>(&Ks[n * 16 + r][32 + g * 8]);
        acc[n] = __builtin_amdgcn_mfma_f32_16x16x32_bf16(qf1, b1, acc[n], 0, 0, 0);
    }

    float mx[4] = {-1e30f, -1e30f, -1e30f, -1e30f};
    #pragma unroll
    for (int n = 0; n < 16; n++)
        #pragma unroll
        for (int i = 0; i < 4; i++) {
            acc[n][i] *= 0.125f;
            mx[i] = fmaxf(mx[i], acc[n][i]);
        }
    #pragma unroll
    for (int i = 0; i < 4; i++) {
        mx[i] = fmaxf(mx[i], __shfl_xor(mx[i], 1));
        mx[i] = fmaxf(mx[i], __shfl_xor(mx[i], 2));
        mx[i] = fmaxf(mx[i], __shfl_xor(mx[i], 4));
        mx[i] = fmaxf(mx[i], __shfl_xor(mx[i], 8));
    }
    float sm[4] = {0.f, 0.f, 0.f, 0.f};
    #pragma unroll
    for (int n = 0; n < 16; n++)
        #pragma unroll
        for (int i = 0; i < 4; i++) {
            float e = __expf(acc[n][i] - mx[i]);
            acc[n][i] = e;
            sm[i] += e;
        }
    #pragma unroll
    for (int i = 0; i < 4; i++) {
        sm[i] += __shfl_xor(sm[i], 1);
        sm[i] += __shfl_xor(sm[i], 2);
        sm[i] += __shfl_xor(sm[i], 4);
        sm[i] += __shfl_xor(sm[i], 8);
    }
    float inv[4];
    #pragma unroll
    for (int i = 0; i < 4; i++) inv[i] = 1.0f / sm[i];

    __syncthreads();  // all waves done reading Ks; safe to overwrite with P

    u16* Pw = &Ks[w * 64][0];
    u16* pout = paff + ((size_t)bid * 64 + w * 16) * 256;
    #pragma unroll
    for (int n = 0; n < 16; n++) {
        int kcol = n * 16 + r;
        #pragma unroll
        for (int i = 0; i < 4; i++) {
            u16 pb = f2bf(acc[n][i] * inv[i]);
            Pw[(g * 4 + i) * 264 + kcol] = pb;
            pout[(g * 4 + i) * 256 + kcol] = pb;
        }
    }

    f4_t acc2[4];
    #pragma unroll
    for (int n = 0; n < 4; n++) acc2[n] = zero;
    #pragma unroll
    for (int k2 = 0; k2 < 8; k2++) {
        bf8_t pa = *reinterpret_cast<const bf8_t*>(&Pw[r * 264 + k2 * 32 + g * 8]);
        #pragma unroll
        for (int n2 = 0; n2 < 4; n2++) {
            bf8_t vbf = *reinterpret_cast<const bf8_t*>(&Vt[n2 * 16 + r][k2 * 32 + g * 8]);
            acc2[n2] = __builtin_amdgcn_mfma_f32_16x16x32_bf16(pa, vbf, acc2[n2], 0, 0, 0);
        }
    }
    u16* op = attnout + ((size_t)(s * 4096 + b * 64 + w * 16 + g * 4)) * 768 + h * 64;
    #pragma unroll
    for (int n2 = 0; n2 < 4; n2++)
        #pragma unroll
        for (int i = 0; i < 4; i++)
            op[(size_t)i * 768 + n2 * 16 + r] = f2bf(acc2[n2][i]);
}

// ---------------- fusion_prep2: h-sum -> colmax -> nu/den + winner bitmask -
__global__ __launch_bounds__(256) void fusion_prep2(
    const u16* __restrict__ paff, float* __restrict__ aff, float* __restrict__ den,
    u64* __restrict__ winners) {
    int sb = blockIdx.x, qc = blockIdx.y;
    int t = threadIdx.x, lane = t & 63, w = t >> 6;
    int q0 = qc * 16;
    float a[16];
    #pragma unroll
    for (int j = 0; j < 16; j++) a[j] = 0.f;
    size_t base = ((size_t)sb * 12 * 64 + q0) * 256 + t;
    for (int h = 0; h < 12; h++) {
        size_t hb = base + (size_t)h * 64 * 256;
        #pragma unroll
        for (int j = 0; j < 16; j++) a[j] += bf2f(paff[hb + j * 256]);
    }
    float m[16];
    #pragma unroll
    for (int j = 0; j < 16; j++) {
        float v = a[j];
        #pragma unroll
        for (int o = 1; o < 64; o <<= 1) v = fmaxf(v, __shfl_xor(v, o));
        m[j] = v;
    }
    __shared__ float red[16][4];
    if (lane == 0) {
        #pragma unroll
        for (int j = 0; j < 16; j++) red[j][w] = m[j];
    }
    __syncthreads();
    float dsum = 0.f;
    u64 wmask = 0;
    float nu[16];
    #pragma unroll
    for (int j = 0; j < 16; j++) {
        float cm = fmaxf(fmaxf(red[j][0], red[j][1]), fmaxf(red[j][2], red[j][3]));
        nu[j] = (a[j] == cm) ? __expf(a[j] - 12.0f) : 0.f;
        if (nu[j] != 0.f) wmask |= (u64)1 << (q0 + j);
        dsum += nu[j];
    }
    if (dsum != 0.f) atomicAdd(&den[sb * 256 + t], dsum);
    if (wmask) atomicOr(&winners[(size_t)sb * 256 + t], wmask);
    float* ap = aff + ((size_t)sb * 256 + t) * 64 + q0;
    #pragma unroll
    for (int j = 0; j < 16; j++) ap[j] = nu[j];
}

// ---------------- fusion_apply_x: x rows only, bitmask gather -------------
__global__ __launch_bounds__(192) void fusion_apply_x(
    const float* __restrict__ x0, const float* __restrict__ x1,
    const float* __restrict__ aff, const float* __restrict__ den,
    const u64* __restrict__ winners, float* out) {
    int bid = blockIdx.x;          // 0..32767
    int s = bid >> 14;
    int rx = bid & 16383;
    int b = rx >> 8, sx = rx & 255;
    int sb = s * 64 + b;
    int tid = threadIdx.x;
    const float* xrow = ((s == 0) ? x0 : x1) + ((size_t)(b * 320 + 64 + sx)) * 768;
    float* orow = out + ((size_t)(s * 20480 + b * 320 + 64 + sx)) * 768;
    u64 mask = winners[(size_t)sb * 256 + sx];
    float invd = 1.0f / (1.0f + den[sb * 256 + sx]);
    f4_t a = *reinterpret_cast<const f4_t*>(xrow + tid * 4) * invd;
    while (mask) {
        int t = (int)__builtin_ctzll(mask);
        mask &= mask - 1;
        float nu = aff[((size_t)sb * 256 + sx) * 64 + t];
        float wgt = nu * invd;
        const float* zr = out + ((size_t)(s * 20480 + b * 320 + t)) * 768;
        f4_t z = *reinterpret_cast<const f4_t*>(zr + tid * 4);
        a += z * wgt;
    }
    *reinterpret_cast<f4_t*>(orow + tid * 4) = a;
}

// ---------------- ln2_mlp: fused LN2 + mlp-down(gelu) + mlp-up accum ------
// 32 rows/block, 256 threads (4 waves: wm=w&1 M-half, wh=w>>1 N-half).
// Thread holds out values in MFMA C-layout; in-place update of out.
__global__ __launch_bounds__(256, 2) void ln2_mlp(
    float* __restrict__ out, const float* __restrict__ w2,
    const float* __restrict__ b2, const u16* __restrict__ mdT,
    const u16* __restrict__ muT) {
    __shared__ alignas(16) u16 A[32][776];   // LN2 output tile, bf16
    __shared__ alignas(16) u16 Hs[32][72];   // gelu(down) tile, bf16
    __shared__ float red[2][4][16];
    int tid = threadIdx.x, lane = tid & 63, w = tid >> 6;
    int r = lane & 15, g = lane >> 4;
    int wm = w & 1, wh = w >> 1;
    size_t base_row = (size_t)blockIdx.x * 32;

    // phase 0: load 96 out values in C-layout, accumulate LN stats
    float p[24][4];
    float rs1[4] = {0.f, 0.f, 0.f, 0.f}, rs2[4] = {0.f, 0.f, 0.f, 0.f};
    #pragma unroll
    for (int nn = 0; nn < 24; nn++) {
        int col = (wh * 24 + nn) * 16 + r;
        #pragma unroll
        for (int i = 0; i < 4; i++) {
            float v = out[(base_row + wm * 16 + g * 4 + i) * 768 + col];
            p[nn][i] = v;
            rs1[i] += v;
            rs2[i] += v * v;
        }
    }
    #pragma unroll
    for (int i = 0; i < 4; i++) {
        #pragma unroll
        for (int o = 1; o < 16; o <<= 1) {
            rs1[i] += __shfl_xor(rs1[i], o);
            rs2[i] += __shfl_xor(rs2[i], o);
        }
    }
    if (r == 0) {
        #pragma unroll
        for (int i = 0; i < 4; i++) {
            red[0][w][g * 4 + i] = rs1[i];
            red[1][w][g * 4 + i] = rs2[i];
        }
    }
    __syncthreads();
    float mean[4], rstd[4];
    #pragma unroll
    for (int i = 0; i < 4; i++) {
        int li = g * 4 + i;
        float t1 = red[0][wm][li] + red[0][wm + 2][li];
        float t2 = red[1][wm][li] + red[1][wm + 2][li];
        mean[i] = t1 * (1.0f / 768.0f);
        float var = t2 * (1.0f / 768.0f) - mean[i] * mean[i];
        rstd[i] = rsqrtf(var + 1e-5f);
    }
    // normalize -> A (bf16)
    #pragma unroll
    for (int nn = 0; nn < 24; nn++) {
        int col = (wh * 24 + nn) * 16 + r;
        float ww = w2[col], bb = b2[col];
        #pragma unroll
        for (int i = 0; i < 4; i++)
            A[wm * 16 + g * 4 + i][col] = f2bf((p[nn][i] - mean[i]) * rstd[i] * ww + bb);
    }
    __syncthreads();

    // phase 1: down GEMM (M=32,N=64,K=768); wave computes tiles (wm, wh*2+{0,1})
    f4_t zero = {0.f, 0.f, 0.f, 0.f};
    f4_t hacc[2] = {zero, zero};
    for (int k0 = 0; k0 < 768; k0 += 32) {
        bf8_t af = *reinterpret_cast<const bf8_t*>(&A[wm * 16 + r][k0 + g * 8]);
        #pragma unroll
        for (int t = 0; t < 2; t++) {
            bf8_t bf = *reinterpret_cast<const bf8_t*>(
                mdT + (size_t)((wh * 2 + t) * 16 + r) * 768 + k0 + g * 8);
            hacc[t] = __builtin_amdgcn_mfma_f32_16x16x32_bf16(af, bf, hacc[t], 0, 0, 0);
        }
    }
    #pragma unroll
    for (int t = 0; t < 2; t++)
        #pragma unroll
        for (int i = 0; i < 4; i++)
            Hs[wm * 16 + g * 4 + i][(wh * 2 + t) * 16 + r] = f2bf(gelu_tanh(hacc[t][i]));
    __syncthreads();

    // phase 2: up GEMM (M=32,N=768,K=64) + accumulate into p, store
    bf8_t a0 = *reinterpret_cast<const bf8_t*>(&Hs[wm * 16 + r][g * 8]);
    bf8_t a1 = *reinterpret_cast<const bf8_t*>(&Hs[wm * 16 + r][32 + g * 8]);
    #pragma unroll
    for (int nn = 0; nn < 24; nn++) {
        int col = (wh * 24 + nn) * 16 + r;
        bf8_t b0 = *reinterpret_cast<const bf8_t*>(muT + (size_t)col * 64 + g * 8);
        bf8_t b1 = *reinterpret_cast<const bf8_t*>(muT + (size_t)col * 64 + 32 + g * 8);
        f4_t c = __builtin_amdgcn_mfma_f32_16x16x32_bf16(a1, b1, zero, 0, 0, 0);
        c = __builtin_amdgcn_mfma_f32_16x16x32_bf16(a0, b0, c, 0, 0, 0);
        #pragma unroll
        for (int i = 0; i < 4; i++)
            out[(base_row + wm * 16 + g * 4 + i) * 768 + col] = p[nn][i] + c[i];
    }
}

extern "C" void kernel_launch(void* const* d_in, const int* in_sizes, int n_in,
                              void* d_out, int out_size, void* d_ws, size_t ws_size,
                              hipStream_t stream) {
    (void)in_sizes; (void)n_in; (void)out_size;
    const float* x0 = (const float*)d_in[0];
    const float* x1 = (const float*)d_in[1];
    const float* ln1w = (const float*)d_in[2];
    const float* ln1b = (const float*)d_in[3];
    const float* ln2w = (const float*)d_in[4];
    const float* ln2b = (const float*)d_in[5];
    const float* wq = (const float*)d_in[6];
    const float* wk = (const float*)d_in[7];
    const float* wv = (const float*)d_in[8];
    const float* wo = (const float*)d_in[9];
    const float* lora_down = (const float*)d_in[10];
    const float* lora_up = (const float*)d_in[11];
    const float* mlp_down = (const float*)d_in[12];
    const float* mlp_up = (const float*)d_in[13];
    float* out = (float*)d_out;

    char* ws = (char*)d_ws;
    size_t off = 0;
    auto alloc = [&](size_t bytes) -> char* {
        char* p = ws + off;
        off = (off + bytes + 255) & ~(size_t)255;
        return p;
    };
    u16* wtq = (u16*)alloc(768 * 768 * 2);
    u16* wtk = (u16*)alloc(768 * 768 * 2);
    u16* wtv = (u16*)alloc(768 * 768 * 2);
    u16* wto = (u16*)alloc(768 * 768 * 2);
    u16* dT  = (u16*)alloc(768 * 64 * 2);
    u16* uT  = (u16*)alloc(768 * 64 * 2);
    u16* mdT = (u16*)alloc(768 * 64 * 2);
    u16* muT = (u16*)alloc(768 * 64 * 2);
    u16* lnZ = (u16*)alloc((size_t)2 * 4096 * 768 * 2);    // region B start
    u16* lnX = (u16*)alloc((size_t)2 * 16384 * 768 * 2);   // contiguous with lnZ
    u16* qb  = (u16*)alloc((size_t)2 * 4096 * 768 * 2);
    u16* kb  = (u16*)alloc((size_t)2 * 16384 * 768 * 2);
    u16* vb  = (u16*)alloc((size_t)2 * 16384 * 768 * 2);
    u16* ao  = (u16*)alloc((size_t)2 * 4096 * 768 * 2);
    float* aff = (float*)alloc((size_t)2 * 64 * 256 * 64 * 4);
    float* den = (float*)alloc((size_t)2 * 64 * 256 * 4);
    u64* winners = (u64*)alloc((size_t)2 * 64 * 256 * 8);
    u16* h01 = (u16*)alloc((size_t)2 * 4096 * 64 * 2);
    // aliases (lifetimes disjoint by stream order):
    u16* paff = lnX;               // 2*768*64*256*2 == lnX region exactly (lnX dead after k/v proj)
    if (ws_size < off) return;     // ws too small -> leave poison (diagnosable)

    // 1. weight prep (batched)
    TPack big = {wq, wk, wv, wo, wtq, wtk, wtv, wto};
    transpose_big<<<dim3(2304, 4), 256, 0, stream>>>(big);
    TPack small = {lora_down, lora_up, mlp_down, mlp_up, dT, uT, mdT, muT};
    transpose_small<<<dim3(192, 4), 256, 0, stream>>>(small);
    hipMemsetAsync(den, 0, (size_t)2 * 64 * 256 * 4, stream);
    hipMemsetAsync(winners, 0, (size_t)2 * 64 * 256 * 8, stream);
    // 2. LN1 (wave-per-row, f4)
    ln1_kernel<<<10240, 256, 0, stream>>>(x0, x1, ln1w, ln1b, lnZ, lnX);
    // 3. projections; kv cross-stream via row^16384 on output
    gemm_bt<128, 128, 2, 2, EPI_BF16, 0><<<dim3(6, 64), 256, 0, stream>>>(
        lnZ, wtq, 8192, 768, 768, nullptr, qb, nullptr, nullptr);
    gemm_bt<128, 128, 2, 2, EPI_BF16, 16384><<<dim3(6, 256), 256, 0, stream>>>(
        lnX, wtk, 32768, 768, 768, nullptr, kb, nullptr, nullptr);
    gemm_bt<128, 128, 2, 2, EPI_BF16, 16384><<<dim3(6, 256), 256, 0, stream>>>(
        lnX, wtv, 32768, 768, 768, nullptr, vb, nullptr, nullptr);
    // 4. attention (MFMA, no atomics); paff overwrites dead lnX region
    attn_mfma<<<1536, 256, 0, stream>>>(qb, kb, vb, ao, paff);
    // 5. fusion prep (h-sum reduce + colmax + nu/den/winners)
    fusion_prep2<<<dim3(128, 4), 256, 0, stream>>>(paff, aff, den, winners);
    // 6. lora-z down; wo GEMM + resid -> out z rows; lora-z up accum -> out z rows
    gemm_bt<128, 64, 2, 1, EPI_GELU, 0><<<dim3(1, 64), 128, 0, stream>>>(
        lnZ, dT, 8192, 64, 768, nullptr, h01, nullptr, nullptr);
    gemm_bt<128, 128, 2, 2, EPI_RESID_Z, 0><<<dim3(6, 64), 256, 0, stream>>>(
        ao, wto, 8192, 768, 768, out, nullptr, x0, x1);
    gemm_bt<128, 128, 2, 2, EPI_ACCUM_Z, 4096><<<dim3(6, 64), 256, 0, stream>>>(
        h01, uT, 8192, 768, 64, out, nullptr, nullptr, nullptr);
    // 7. fusion apply (x rows only; z rows already final in out)
    fusion_apply_x<<<32768, 192, 0, stream>>>(x0, x1, aff, den, winners, out);
    // 8. fused LN2 + mlp lora (in-place on out)
    ln2_mlp<<<1280, 256, 0, stream>>>(out, ln2w, ln2b, mdT, muT);
}

// Round 6
// 443.836 us; speedup vs baseline: 2.2386x; 1.0046x over previous
//
#include <hip/hip_runtime.h>

// TMMixer: B=64, T=64, S=256, DIM=768, H=12, HD=64, RANK=64
// Pipeline (all bf16 MFMA GEMMs, f32 accumulation):
//  1. transpose weights -> bf16 (Bt layout: [n][k]); k+v stacked into wtkv
//  2. LN1 -> bf16 (f4 vectorized, wave-per-row)
//  3. q projection; fused k+v projection (N=1536, row stride 1536)
//  4. attention per (s,b,h): MFMA QK^T -> wave-local softmax -> MFMA PV;
//     P dumped as bf16 to paff[sbh][q][k] (NO global atomics)
//  5. fusion_prep2: h-sum reduce -> colmax -> nu, den partials + winner bitmask
//  6. lora-z down (gelu); wo GEMM + resid -> out z-rows; lora-z up accum -> out z-rows
//  7. fusion_apply_x: x rows only; bitmask-gathered weighted z adds
//  8. ln2_mlp v2: coalesced f4 in/out, wave-owns-8-rows LN, 3 blocks/CU

typedef __bf16 bf8_t __attribute__((ext_vector_type(8)));
typedef float f4_t __attribute__((ext_vector_type(4)));
typedef unsigned short u16;
typedef unsigned int u32;
typedef unsigned long long u64;
typedef unsigned short us4_t __attribute__((ext_vector_type(4)));
typedef unsigned short us8_t __attribute__((ext_vector_type(8)));

__device__ __forceinline__ float bf2f(u16 h) {
    return __uint_as_float(((unsigned int)h) << 16);
}
__device__ __forceinline__ u16 f2bf(float f) {
    unsigned int u = __float_as_uint(f);
    u += 0x7fffu + ((u >> 16) & 1u);
    return (u16)(u >> 16);
}
__device__ __forceinline__ float gelu_tanh(float x) {
    float t = tanhf(0.7978845608028654f * (x + 0.044715f * x * x * x));
    return 0.5f * x * (1.0f + t);
}

// ---------------- weight prep: dst[C][R] = bf16(src[R][C]) ----------------
struct TPack {
    const float* s0; const float* s1; const float* s2; const float* s3;
    u16* d0; u16* d1; u16* d2; u16* d3;
};
__global__ __launch_bounds__(256) void transpose_big(TPack p) {
    int which = blockIdx.y;
    const float* src = which == 0 ? p.s0 : which == 1 ? p.s1 : which == 2 ? p.s2 : p.s3;
    u16* dst = which == 0 ? p.d0 : which == 1 ? p.d1 : which == 2 ? p.d2 : p.d3;
    int idx = blockIdx.x * 256 + threadIdx.x;  // 768*768
    int c = idx / 768, r = idx - c * 768;
    dst[idx] = f2bf(src[(size_t)r * 768 + c]);
}
__global__ __launch_bounds__(256) void transpose_small(TPack p) {
    int which = blockIdx.y;
    const float* src = which == 0 ? p.s0 : which == 1 ? p.s1 : which == 2 ? p.s2 : p.s3;
    u16* dst = which == 0 ? p.d0 : which == 1 ? p.d1 : which == 2 ? p.d2 : p.d3;
    int R = (which & 1) ? 64 : 768;
    int C = (which & 1) ? 768 : 64;
    int idx = blockIdx.x * 256 + threadIdx.x;  // 49152
    int c = idx / R, r = idx - c * R;
    dst[idx] = f2bf(src[(size_t)r * C + c]);
}

// ---------------- LN1: wave-per-row, f4 loads ----------
__global__ __launch_bounds__(256) void ln1_kernel(
    const float* __restrict__ x0, const float* __restrict__ x1,
    const float* __restrict__ w, const float* __restrict__ b,
    u16* __restrict__ lnZ, u16* __restrict__ lnX) {
    int rid = blockIdx.x * 4 + (threadIdx.x >> 6);
    int lane = threadIdx.x & 63;
    int s = rid / 20480;
    int r2 = rid - s * 20480;
    const float* srcBase = (s == 0) ? x0 : x1;
    const float* src; u16* dst;
    if (r2 < 4096) {
        int bb = r2 >> 6, t = r2 & 63;
        src = srcBase + ((size_t)(bb * 320 + t)) * 768;
        dst = lnZ + ((size_t)(s * 4096 + r2)) * 768;
    } else {
        int rx = r2 - 4096;
        int bb = rx >> 8, sx = rx & 255;
        src = srcBase + ((size_t)(bb * 320 + 64 + sx)) * 768;
        dst = lnX + ((size_t)(s * 16384 + rx)) * 768;
    }
    f4_t v[3];
    float s1 = 0.f, s2 = 0.f;
    #pragma unroll
    for (int jj = 0; jj < 3; jj++) {
        v[jj] = *reinterpret_cast<const f4_t*>(src + (lane + 64 * jj) * 4);
        #pragma unroll
        for (int e = 0; e < 4; e++) { s1 += v[jj][e]; s2 += v[jj][e] * v[jj][e]; }
    }
    #pragma unroll
    for (int o = 1; o < 64; o <<= 1) { s1 += __shfl_xor(s1, o); s2 += __shfl_xor(s2, o); }
    float mean = s1 * (1.0f / 768.0f);
    float var = s2 * (1.0f / 768.0f) - mean * mean;
    float rstd = rsqrtf(var + 1e-5f);
    #pragma unroll
    for (int jj = 0; jj < 3; jj++) {
        int c0 = (lane + 64 * jj) * 4;
        f4_t wv = *reinterpret_cast<const f4_t*>(w + c0);
        f4_t bv = *reinterpret_cast<const f4_t*>(b + c0);
        us4_t o4;
        #pragma unroll
        for (int e = 0; e < 4; e++)
            o4[e] = f2bf((v[jj][e] - mean) * rstd * wv[e] + bv[e]);
        *reinterpret_cast<us4_t*>(dst + c0) = o4;
    }
}

// ---------------- MFMA GEMM: C = A(MxK) * Bt(NxK)^T, epilogues -----------
// EPI_*_Z map row (s<<12 | b<<6 | t) to out row s*20480 + b*320 + t.
enum { EPI_BF16 = 0, EPI_RESID_Z = 1, EPI_GELU = 2, EPI_ACCUM = 3, EPI_ACCUM_Z = 4 };

template <int BM, int BN, int WR, int WC, int EPI, int XB>
__global__ __launch_bounds__(WR * WC * 64, 1) void gemm_bt(
    const u16* __restrict__ A, const u16* __restrict__ Bt,
    int M, int N, int K,
    float* __restrict__ Cf, u16* __restrict__ Cbf,
    const float* __restrict__ resid0, const float* __restrict__ resid1) {
    constexpr int THREADS = WR * WC * 64;
    constexpr int BK = 64;
    __shared__ alignas(16) u16 As[BM][BK + 8];
    __shared__ alignas(16) u16 Bs[BN][BK + 8];

    const int tid = threadIdx.x;
    const int lane = tid & 63;
    const int w = tid >> 6;
    const int wr = w / WC, wc = w % WC;
    const int r = lane & 15, g = lane >> 4;
    const int brow = blockIdx.y * BM;
    const int bcol = blockIdx.x * BN;

    f4_t acc[4][4];
    f4_t zero = {0.f, 0.f, 0.f, 0.f};
    #pragma unroll
    for (int m = 0; m < 4; m++)
        #pragma unroll
        for (int n = 0; n < 4; n++) acc[m][n] = zero;

    for (int k0 = 0; k0 < K; k0 += BK) {
        constexpr int CA = BM * BK / 8;
        #pragma unroll
        for (int i = 0; i < CA / THREADS; i++) {
            int c = tid + THREADS * i;
            int row = c >> 3, kc = (c & 7) * 8;
            bf8_t val = *reinterpret_cast<const bf8_t*>(A + (size_t)(brow + row) * K + k0 + kc);
            *reinterpret_cast<bf8_t*>(&As[row][kc]) = val;
        }
        constexpr int CB = BN * BK / 8;
        #pragma unroll
        for (int i = 0; i < CB / THREADS; i++) {
            int c = tid + THREADS * i;
            int row = c >> 3, kc = (c & 7) * 8;
            bf8_t val = *reinterpret_cast<const bf8_t*>(Bt + (size_t)(bcol + row) * K + k0 + kc);
            *reinterpret_cast<bf8_t*>(&Bs[row][kc]) = val;
        }
        __syncthreads();
        #pragma unroll
        for (int ks = 0; ks < BK; ks += 32) {
            bf8_t af[4], bfr[4];
            #pragma unroll
            for (int m = 0; m < 4; m++)
                af[m] = *reinterpret_cast<const bf8_t*>(&As[wr * 64 + m * 16 + r][ks + g * 8]);
            #pragma unroll
            for (int n = 0; n < 4; n++)
                bfr[n] = *reinterpret_cast<const bf8_t*>(&Bs[wc * 64 + n * 16 + r][ks + g * 8]);
            #pragma unroll
            for (int m = 0; m < 4; m++)
                #pragma unroll
                for (int n = 0; n < 4; n++)
                    acc[m][n] = __builtin_amdgcn_mfma_f32_16x16x32_bf16(af[m], bfr[n], acc[m][n], 0, 0, 0);
        }
        __syncthreads();
    }

    #pragma unroll
    for (int m = 0; m < 4; m++) {
        #pragma unroll
        for (int n = 0; n < 4; n++) {
            int col = bcol + wc * 64 + n * 16 + r;
            #pragma unroll
            for (int i = 0; i < 4; i++) {
                int row = brow + wr * 64 + m * 16 + g * 4 + i;
                int orow = row ^ XB;
                float val = acc[m][n][i];
                if constexpr (EPI == EPI_BF16) {
                    Cbf[(size_t)orow * N + col] = f2bf(val);
                } else if constexpr (EPI == EPI_RESID_Z) {
                    int s = orow >> 12, bb = (orow >> 6) & 63, t = orow & 63;
                    const float* rp = (s != 0) ? resid1 : resid0;
                    float rs = rp[((size_t)bb * 320 + t) * 768 + col];
                    Cf[((size_t)s * 20480 + bb * 320 + t) * 768 + col] = val + rs;
                } else if constexpr (EPI == EPI_GELU) {
                    Cbf[(size_t)orow * N + col] = f2bf(gelu_tanh(val));
                } else if constexpr (EPI == EPI_ACCUM_Z) {
                    int s = orow >> 12, bb = (orow >> 6) & 63, t = orow & 63;
                    Cf[((size_t)s * 20480 + bb * 320 + t) * 768 + col] += val;
                } else {
                    Cf[(size_t)orow * N + col] += val;
                }
            }
        }
    }
}

// ---------------- MFMA attention per (s,b,h); kv combined stride 1536 -----
__global__ __launch_bounds__(256, 2) void attn_mfma(
    const u16* __restrict__ q, const u16* __restrict__ kv,
    u16* __restrict__ attnout, u16* __restrict__ paff) {
    __shared__ alignas(16) u16 Ks[256][72];   // 36,864 B (P tiles alias after sync)
    __shared__ alignas(16) u16 Vt[64][264];   // 33,792 B
    int bid = blockIdx.x;
    int s = bid / 768;
    int rem = bid - s * 768;
    int b = rem / 12, h = rem - (rem / 12) * 12;
    int tid = threadIdx.x, lane = tid & 63, w = tid >> 6;
    int r = lane & 15, g = lane >> 4;

    size_t kvbase = ((size_t)(s * 16384 + b * 256)) * 1536 + h * 64;

    const u16* qrow = q + ((size_t)(s * 4096 + b * 64 + w * 16 + r)) * 768 + h * 64 + g * 8;
    bf8_t qf0 = *reinterpret_cast<const bf8_t*>(qrow);
    bf8_t qf1 = *reinterpret_cast<const bf8_t*>(qrow + 32);

    // stage K [256][64] -> Ks (k at col offset 0 of kv row)
    #pragma unroll
    for (int i = 0; i < 8; i++) {
        int c = tid + 256 * i;
        int row = c >> 3, kc = (c & 7) * 8;
        *reinterpret_cast<bf8_t*>(&Ks[row][kc]) =
            *reinterpret_cast<const bf8_t*>(kv + kvbase + (size_t)row * 1536 + kc);
    }
    // stage V transposed (v at col offset 768 of kv row)
    u32* vt32 = reinterpret_cast<u32*>(&Vt[0][0]);  // row stride 132 u32
    #pragma unroll
    for (int i = 0; i < 4; i++) {
        int c = tid + 256 * i;
        int kp = c >> 3, d0 = (c & 7) * 8;
        const u16* vr = kv + kvbase + 768 + (size_t)(2 * kp) * 1536 + d0;
        us8_t va = *reinterpret_cast<const us8_t*>(vr);
        us8_t vb = *reinterpret_cast<const us8_t*>(vr + 1536);
        #pragma unroll
        for (int j = 0; j < 8; j++)
            vt32[(d0 + j) * 132 + kp] = (u32)va[j] | ((u32)vb[j] << 16);
    }
    __syncthreads();

    f4_t acc[16];
    f4_t zero = {0.f, 0.f, 0.f, 0.f};
    #pragma unroll
    for (int n = 0; n < 16; n++) acc[n] = zero;
    #pragma unroll
    for (int n = 0; n < 16; n++) {
        bf8_t b0 = *reinterpret_cast<const bf8_t*>(&Ks[n * 16 + r][g * 8]);
        acc[n] = __builtin_amdgcn_mfma_f32_16x16x32_bf16(qf0, b0, acc[n], 0, 0, 0);
        bf8_t b1 = *reinterpret_cast<const bf8_t*>(&Ks[n * 16 + r][32 + g * 8]);
        acc[n] = __builtin_amdgcn_mfma_f32_16x16x32_bf16(qf1, b1, acc[n], 0, 0, 0);
    }

    float mx[4] = {-1e30f, -1e30f, -1e30f, -1e30f};
    #pragma unroll
    for (int n = 0; n < 16; n++)
        #pragma unroll
        for (int i = 0; i < 4; i++) {
            acc[n][i] *= 0.125f;
            mx[i] = fmaxf(mx[i], acc[n][i]);
        }
    #pragma unroll
    for (int i = 0; i < 4; i++) {
        mx[i] = fmaxf(mx[i], __shfl_xor(mx[i], 1));
        mx[i] = fmaxf(mx[i], __shfl_xor(mx[i], 2));
        mx[i] = fmaxf(mx[i], __shfl_xor(mx[i], 4));
        mx[i] = fmaxf(mx[i], __shfl_xor(mx[i], 8));
    }
    float sm[4] = {0.f, 0.f, 0.f, 0.f};
    #pragma unroll
    for (int n = 0; n < 16; n++)
        #pragma unroll
        for (int i = 0; i < 4; i++) {
            float e = __expf(acc[n][i] - mx[i]);
            acc[n][i] = e;
            sm[i] += e;
        }
    #pragma unroll
    for (int i = 0; i < 4; i++) {
        sm[i] += __shfl_xor(sm[i], 1);
        sm[i] += __shfl_xor(sm[i], 2);
        sm[i] += __shfl_xor(sm[i], 4);
        sm[i] += __shfl_xor(sm[i], 8);
    }
    float inv[4];
    #pragma unroll
    for (int i = 0; i < 4; i++) inv[i] = 1.0f / sm[i];

    __syncthreads();  // all waves done reading Ks; safe to overwrite with P

    u16* Pw = &Ks[w * 64][0];
    u16* pout = paff + ((size_t)bid * 64 + w * 16) * 256;
    #pragma unroll
    for (int n = 0; n < 16; n++) {
        int kcol = n * 16 + r;
        #pragma unroll
        for (int i = 0; i < 4; i++) {
            u16 pb = f2bf(acc[n][i] * inv[i]);
            Pw[(g * 4 + i) * 264 + kcol] = pb;
            pout[(g * 4 + i) * 256 + kcol] = pb;
        }
    }

    f4_t acc2[4];
    #pragma unroll
    for (int n = 0; n < 4; n++) acc2[n] = zero;
    #pragma unroll
    for (int k2 = 0; k2 < 8; k2++) {
        bf8_t pa = *reinterpret_cast<const bf8_t*>(&Pw[r * 264 + k2 * 32 + g * 8]);
        #pragma unroll
        for (int n2 = 0; n2 < 4; n2++) {
            bf8_t vbf = *reinterpret_cast<const bf8_t*>(&Vt[n2 * 16 + r][k2 * 32 + g * 8]);
            acc2[n2] = __builtin_amdgcn_mfma_f32_16x16x32_bf16(pa, vbf, acc2[n2], 0, 0, 0);
        }
    }
    u16* op = attnout + ((size_t)(s * 4096 + b * 64 + w * 16 + g * 4)) * 768 + h * 64;
    #pragma unroll
    for (int n2 = 0; n2 < 4; n2++)
        #pragma unroll
        for (int i = 0; i < 4; i++)
            op[(size_t)i * 768 + n2 * 16 + r] = f2bf(acc2[n2][i]);
}

// ---------------- fusion_prep2: h-sum -> colmax -> nu/den + winner bitmask -
__global__ __launch_bounds__(256) void fusion_prep2(
    const u16* __restrict__ paff, float* __restrict__ aff, float* __restrict__ den,
    u64* __restrict__ winners) {
    int sb = blockIdx.x, qc = blockIdx.y;
    int t = threadIdx.x, lane = t & 63, w = t >> 6;
    int q0 = qc * 16;
    float a[16];
    #pragma unroll
    for (int j = 0; j < 16; j++) a[j] = 0.f;
    size_t base = ((size_t)sb * 12 * 64 + q0) * 256 + t;
    for (int h = 0; h < 12; h++) {
        size_t hb = base + (size_t)h * 64 * 256;
        #pragma unroll
        for (int j = 0; j < 16; j++) a[j] += bf2f(paff[hb + j * 256]);
    }
    float m[16];
    #pragma unroll
    for (int j = 0; j < 16; j++) {
        float v = a[j];
        #pragma unroll
        for (int o = 1; o < 64; o <<= 1) v = fmaxf(v, __shfl_xor(v, o));
        m[j] = v;
    }
    __shared__ float red[16][4];
    if (lane == 0) {
        #pragma unroll
        for (int j = 0; j < 16; j++) red[j][w] = m[j];
    }
    __syncthreads();
    float dsum = 0.f;
    u64 wmask = 0;
    float nu[16];
    #pragma unroll
    for (int j = 0; j < 16; j++) {
        float cm = fmaxf(fmaxf(red[j][0], red[j][1]), fmaxf(red[j][2], red[j][3]));
        nu[j] = (a[j] == cm) ? __expf(a[j] - 12.0f) : 0.f;
        if (nu[j] != 0.f) wmask |= (u64)1 << (q0 + j);
        dsum += nu[j];
    }
    if (dsum != 0.f) atomicAdd(&den[sb * 256 + t], dsum);
    if (wmask) atomicOr(&winners[(size_t)sb * 256 + t], wmask);
    float* ap = aff + ((size_t)sb * 256 + t) * 64 + q0;
    #pragma unroll
    for (int j = 0; j < 16; j++) ap[j] = nu[j];
}

// ---------------- fusion_apply_x: x rows only, bitmask gather -------------
__global__ __launch_bounds__(192) void fusion_apply_x(
    const float* __restrict__ x0, const float* __restrict__ x1,
    const float* __restrict__ aff, const float* __restrict__ den,
    const u64* __restrict__ winners, float* out) {
    int bid = blockIdx.x;          // 0..32767
    int s = bid >> 14;
    int rx = bid & 16383;
    int b = rx >> 8, sx = rx & 255;
    int sb = s * 64 + b;
    int tid = threadIdx.x;
    const float* xrow = ((s == 0) ? x0 : x1) + ((size_t)(b * 320 + 64 + sx)) * 768;
    float* orow = out + ((size_t)(s * 20480 + b * 320 + 64 + sx)) * 768;
    u64 mask = winners[(size_t)sb * 256 + sx];
    float invd = 1.0f / (1.0f + den[sb * 256 + sx]);
    f4_t a = *reinterpret_cast<const f4_t*>(xrow + tid * 4) * invd;
    while (mask) {
        int t = (int)__builtin_ctzll(mask);
        mask &= mask - 1;
        float nu = aff[((size_t)sb * 256 + sx) * 64 + t];
        float wgt = nu * invd;
        const float* zr = out + ((size_t)(s * 20480 + b * 320 + t)) * 768;
        f4_t z = *reinterpret_cast<const f4_t*>(zr + tid * 4);
        a += z * wgt;
    }
    *reinterpret_cast<f4_t*>(orow + tid * 4) = a;
}

// ---------------- ln2_mlp v2: coalesced f4, wave-owns-8-rows --------------
// 32 rows/block, 256 threads. Phase 0: f4 loads + per-wave LN -> A (bf16 LDS).
// Phase 1: down GEMM (C-layout waves). Phase 2: up GEMM -> bf16 into A region.
// Phase 3: f4 re-read A-region contribution + add + f4 store.
__global__ __launch_bounds__(256, 3) void ln2_mlp(
    float* __restrict__ out, const float* __restrict__ w2,
    const float* __restrict__ b2, const u16* __restrict__ mdT,
    const u16* __restrict__ muT) {
    __shared__ alignas(16) u16 A[32][776];   // 49,664 B; reused for up-contribution
    __shared__ alignas(16) u16 Hs[32][72];   //  4,608 B
    int tid = threadIdx.x, lane = tid & 63, w = tid >> 6;
    int r = lane & 15, g = lane >> 4;
    int wm = w & 1, wh = w >> 1;
    size_t base = (size_t)blockIdx.x * 32 * 768;

    // phase 0: coalesced loads, per-row LN stats (row fully within one wave)
    f4_t p[8][3];
    float mu[8], rs[8];
    #pragma unroll
    for (int rr = 0; rr < 8; rr++) {
        int row = w * 8 + rr;
        float a1 = 0.f, a2 = 0.f;
        #pragma unroll
        for (int cc = 0; cc < 3; cc++) {
            f4_t v = *reinterpret_cast<const f4_t*>(out + base + (size_t)row * 768 + cc * 256 + lane * 4);
            p[rr][cc] = v;
            #pragma unroll
            for (int e = 0; e < 4; e++) { a1 += v[e]; a2 += v[e] * v[e]; }
        }
        #pragma unroll
        for (int o = 1; o < 64; o <<= 1) { a1 += __shfl_xor(a1, o); a2 += __shfl_xor(a2, o); }
        float mean = a1 * (1.0f / 768.0f);
        float var = a2 * (1.0f / 768.0f) - mean * mean;
        mu[rr] = mean;
        rs[rr] = rsqrtf(var + 1e-5f);
    }
    #pragma unroll
    for (int rr = 0; rr < 8; rr++) {
        int row = w * 8 + rr;
        #pragma unroll
        for (int cc = 0; cc < 3; cc++) {
            int c0 = cc * 256 + lane * 4;
            f4_t wv = *reinterpret_cast<const f4_t*>(w2 + c0);
            f4_t bv = *reinterpret_cast<const f4_t*>(b2 + c0);
            us4_t o4;
            #pragma unroll
            for (int e = 0; e < 4; e++)
                o4[e] = f2bf((p[rr][cc][e] - mu[rr]) * rs[rr] * wv[e] + bv[e]);
            *reinterpret_cast<us4_t*>(&A[row][c0]) = o4;
        }
    }
    __syncthreads();

    // phase 1: down GEMM (M=32,N=64,K=768); wave (wm, wh*2+{0,1})
    f4_t zero = {0.f, 0.f, 0.f, 0.f};
    f4_t hacc[2] = {zero, zero};
    for (int k0 = 0; k0 < 768; k0 += 32) {
        bf8_t af = *reinterpret_cast<const bf8_t*>(&A[wm * 16 + r][k0 + g * 8]);
        #pragma unroll
        for (int t = 0; t < 2; t++) {
            bf8_t bf = *reinterpret_cast<const bf8_t*>(
                mdT + (size_t)((wh * 2 + t) * 16 + r) * 768 + k0 + g * 8);
            hacc[t] = __builtin_amdgcn_mfma_f32_16x16x32_bf16(af, bf, hacc[t], 0, 0, 0);
        }
    }
    #pragma unroll
    for (int t = 0; t < 2; t++)
        #pragma unroll
        for (int i = 0; i < 4; i++)
            Hs[wm * 16 + g * 4 + i][(wh * 2 + t) * 16 + r] = f2bf(gelu_tanh(hacc[t][i]));
    __syncthreads();   // Hs ready; all A reads done

    // phase 2: up GEMM (M=32,N=768,K=64); write bf16 contribution into A region
    bf8_t a0 = *reinterpret_cast<const bf8_t*>(&Hs[wm * 16 + r][g * 8]);
    bf8_t a1 = *reinterpret_cast<const bf8_t*>(&Hs[wm * 16 + r][32 + g * 8]);
    #pragma unroll
    for (int nn = 0; nn < 24; nn++) {
        int col = (wh * 24 + nn) * 16 + r;
        bf8_t b0 = *reinterpret_cast<const bf8_t*>(muT + (size_t)col * 64 + g * 8);
        bf8_t b1 = *reinterpret_cast<const bf8_t*>(muT + (size_t)col * 64 + 32 + g * 8);
        f4_t c = __builtin_amdgcn_mfma_f32_16x16x32_bf16(a1, b1, zero, 0, 0, 0);
        c = __builtin_amdgcn_mfma_f32_16x16x32_bf16(a0, b0, c, 0, 0, 0);
        #pragma unroll
        for (int i = 0; i < 4; i++)
            A[wm * 16 + g * 4 + i][col] = f2bf(c[i]);
    }
    __syncthreads();

    // phase 3: coalesced add + store
    #pragma unroll
    for (int rr = 0; rr < 8; rr++) {
        int row = w * 8 + rr;
        #pragma unroll
        for (int cc = 0; cc < 3; cc++) {
            int c0 = cc * 256 + lane * 4;
            us4_t c4 = *reinterpret_cast<const us4_t*>(&A[row][c0]);
            f4_t o = p[rr][cc];
            #pragma unroll
            for (int e = 0; e < 4; e++) o[e] += bf2f(c4[e]);
            *reinterpret_cast<f4_t*>(out + base + (size_t)row * 768 + c0) = o;
        }
    }
}

extern "C" void kernel_launch(void* const* d_in, const int* in_sizes, int n_in,
                              void* d_out, int out_size, void* d_ws, size_t ws_size,
                              hipStream_t stream) {
    (void)in_sizes; (void)n_in; (void)out_size;
    const float* x0 = (const float*)d_in[0];
    const float* x1 = (const float*)d_in[1];
    const float* ln1w = (const float*)d_in[2];
    const float* ln1b = (const float*)d_in[3];
    const float* ln2w = (const float*)d_in[4];
    const float* ln2b = (const float*)d_in[5];
    const float* wq = (const float*)d_in[6];
    const float* wk = (const float*)d_in[7];
    const float* wv = (const float*)d_in[8];
    const float* wo = (const float*)d_in[9];
    const float* lora_down = (const float*)d_in[10];
    const float* lora_up = (const float*)d_in[11];
    const float* mlp_down = (const float*)d_in[12];
    const float* mlp_up = (const float*)d_in[13];
    float* out = (float*)d_out;

    char* ws = (char*)d_ws;
    size_t off = 0;
    auto alloc = [&](size_t bytes) -> char* {
        char* p = ws + off;
        off = (off + bytes + 255) & ~(size_t)255;
        return p;
    };
    u16* wtq  = (u16*)alloc(768 * 768 * 2);
    u16* wtkv = (u16*)alloc((size_t)1536 * 768 * 2);
    u16* wto  = (u16*)alloc(768 * 768 * 2);
    u16* dT  = (u16*)alloc(768 * 64 * 2);
    u16* uT  = (u16*)alloc(768 * 64 * 2);
    u16* mdT = (u16*)alloc(768 * 64 * 2);
    u16* muT = (u16*)alloc(768 * 64 * 2);
    u16* lnZ = (u16*)alloc((size_t)2 * 4096 * 768 * 2);
    u16* lnX = (u16*)alloc((size_t)2 * 16384 * 768 * 2);
    u16* qb  = (u16*)alloc((size_t)2 * 4096 * 768 * 2);
    u16* kvb = (u16*)alloc((size_t)2 * 16384 * 1536 * 2);
    u16* ao  = (u16*)alloc((size_t)2 * 4096 * 768 * 2);
    float* aff = (float*)alloc((size_t)2 * 64 * 256 * 64 * 4);
    float* den = (float*)alloc((size_t)2 * 64 * 256 * 4);
    u64* winners = (u64*)alloc((size_t)2 * 64 * 256 * 8);
    u16* h01 = (u16*)alloc((size_t)2 * 4096 * 64 * 2);
    // aliases (lifetimes disjoint by stream order):
    u16* paff = lnX;               // 2*768*64*256*2 == lnX region exactly (lnX dead after kv proj)
    if (ws_size < off) return;     // ws too small -> leave poison (diagnosable)

    // 1. weight prep (batched); k,v stacked into wtkv
    TPack big = {wq, wk, wv, wo, wtq, wtkv, wtkv + (size_t)768 * 768, wto};
    transpose_big<<<dim3(2304, 4), 256, 0, stream>>>(big);
    TPack small = {lora_down, lora_up, mlp_down, mlp_up, dT, uT, mdT, muT};
    transpose_small<<<dim3(192, 4), 256, 0, stream>>>(small);
    hipMemsetAsync(den, 0, (size_t)2 * 64 * 256 * 4, stream);
    hipMemsetAsync(winners, 0, (size_t)2 * 64 * 256 * 8, stream);
    // 2. LN1 (wave-per-row, f4)
    ln1_kernel<<<10240, 256, 0, stream>>>(x0, x1, ln1w, ln1b, lnZ, lnX);
    // 3. q projection; fused kv projection (cross-stream via row^16384)
    gemm_bt<128, 128, 2, 2, EPI_BF16, 0><<<dim3(6, 64), 256, 0, stream>>>(
        lnZ, wtq, 8192, 768, 768, nullptr, qb, nullptr, nullptr);
    gemm_bt<128, 128, 2, 2, EPI_BF16, 16384><<<dim3(12, 256), 256, 0, stream>>>(
        lnX, wtkv, 32768, 1536, 768, nullptr, kvb, nullptr, nullptr);
    // 4. attention (MFMA, no atomics); paff overwrites dead lnX region
    attn_mfma<<<1536, 256, 0, stream>>>(qb, kvb, ao, paff);
    // 5. fusion prep (h-sum reduce + colmax + nu/den/winners)
    fusion_prep2<<<dim3(128, 4), 256, 0, stream>>>(paff, aff, den, winners);
    // 6. lora-z down; wo GEMM + resid -> out z rows; lora-z up accum -> out z rows
    gemm_bt<128, 64, 2, 1, EPI_GELU, 0><<<dim3(1, 64), 128, 0, stream>>>(
        lnZ, dT, 8192, 64, 768, nullptr, h01, nullptr, nullptr);
    gemm_bt<128, 128, 2, 2, EPI_RESID_Z, 0><<<dim3(6, 64), 256, 0, stream>>>(
        ao, wto, 8192, 768, 768, out, nullptr, x0, x1);
    gemm_bt<128, 128, 2, 2, EPI_ACCUM_Z, 4096><<<dim3(6, 64), 256, 0, stream>>>(
        h01, uT, 8192, 768, 64, out, nullptr, nullptr, nullptr);
    // 7. fusion apply (x rows only; z rows already final in out)
    fusion_apply_x<<<32768, 192, 0, stream>>>(x0, x1, aff, den, winners, out);
    // 8. fused LN2 + mlp lora (in-place on out, v2)
    ln2_mlp<<<1280, 256, 0, stream>>>(out, ln2w, ln2b, mdT, muT);
}

// Round 7
// 438.379 us; speedup vs baseline: 2.2665x; 1.0124x over previous
//
#include <hip/hip_runtime.h>

// TMMixer: B=64, T=64, S=256, DIM=768, H=12, HD=64, RANK=64
// Pipeline (all bf16 MFMA GEMMs, f32 accumulation):
//  1. transpose weights -> bf16; k+v stacked into wtkv; wo+lora_up stacked into wtoU[768][832]
//  2. LN1 -> bf16 (f4 vectorized, wave-per-row)
//  3. q projection; fused k+v projection (N=1536); all GEMMs XCD-swizzled 1D grid
//  4. attention: MFMA QK^T -> wave-local softmax -> MFMA PV; out -> aoh[.][0:768] (stride 832)
//     P dumped as bf16 to paff[sbh][q][k] (NO global atomics)
//  5. fusion_prep2: h-sum reduce -> colmax -> nu, den partials + winner bitmask
//  6. lora-z down (gelu) -> aoh[.][768:832] (row^4096); merged (wo|up) GEMM K=832 + resid -> out z-rows
//  7. fusion_apply_x: x rows only; bitmask-gathered weighted z adds
//  8. ln2_mlp: coalesced f4 in/out, wave-owns-8-rows LN, 3 blocks/CU

typedef __bf16 bf8_t __attribute__((ext_vector_type(8)));
typedef float f4_t __attribute__((ext_vector_type(4)));
typedef unsigned short u16;
typedef unsigned int u32;
typedef unsigned long long u64;
typedef unsigned short us4_t __attribute__((ext_vector_type(4)));
typedef unsigned short us8_t __attribute__((ext_vector_type(8)));

__device__ __forceinline__ float bf2f(u16 h) {
    return __uint_as_float(((unsigned int)h) << 16);
}
__device__ __forceinline__ u16 f2bf(float f) {
    unsigned int u = __float_as_uint(f);
    u += 0x7fffu + ((u >> 16) & 1u);
    return (u16)(u >> 16);
}
__device__ __forceinline__ float gelu_tanh(float x) {
    float t = tanhf(0.7978845608028654f * (x + 0.044715f * x * x * x));
    return 0.5f * x * (1.0f + t);
}

// ---------------- weight prep ----------------
// big: wq->wtq[768], wk->wtkv[0:768], wv->wtkv[768:1536], wo->wtoU (stride 832)
struct TPack {
    const float* s0; const float* s1; const float* s2; const float* s3;
    u16* d0; u16* d1; u16* d2; u16* d3;
};
__global__ __launch_bounds__(256) void transpose_big(TPack p) {
    int which = blockIdx.y;
    const float* src = which == 0 ? p.s0 : which == 1 ? p.s1 : which == 2 ? p.s2 : p.s3;
    u16* dst = which == 0 ? p.d0 : which == 1 ? p.d1 : which == 2 ? p.d2 : p.d3;
    int idx = blockIdx.x * 256 + threadIdx.x;  // 768*768
    int c = idx / 768, r = idx - c * 768;
    u16 v = f2bf(src[(size_t)r * 768 + c]);
    if (which == 3) dst[(size_t)c * 832 + r] = v;   // wtoU k-cols 0..767
    else dst[idx] = v;
}
// small: lora_down->dT[64][768]; lora_up->wtoU[n][768+j]; mlp_down->mdT; mlp_up->muT
__global__ __launch_bounds__(256) void transpose_small(TPack p) {
    int which = blockIdx.y;
    const float* src = which == 0 ? p.s0 : which == 1 ? p.s1 : which == 2 ? p.s2 : p.s3;
    u16* dst = which == 0 ? p.d0 : which == 1 ? p.d1 : which == 2 ? p.d2 : p.d3;
    int R = (which & 1) ? 64 : 768;
    int C = (which & 1) ? 768 : 64;
    int idx = blockIdx.x * 256 + threadIdx.x;  // 49152
    int c = idx / R, r = idx - c * R;
    u16 v = f2bf(src[(size_t)r * C + c]);
    if (which == 1) dst[(size_t)c * 832 + r] = v;   // wtoU+768: k-cols 768..831
    else dst[idx] = v;
}

// ---------------- LN1: wave-per-row, f4 loads ----------
__global__ __launch_bounds__(256) void ln1_kernel(
    const float* __restrict__ x0, const float* __restrict__ x1,
    const float* __restrict__ w, const float* __restrict__ b,
    u16* __restrict__ lnZ, u16* __restrict__ lnX) {
    int rid = blockIdx.x * 4 + (threadIdx.x >> 6);
    int lane = threadIdx.x & 63;
    int s = rid / 20480;
    int r2 = rid - s * 20480;
    const float* srcBase = (s == 0) ? x0 : x1;
    const float* src; u16* dst;
    if (r2 < 4096) {
        int bb = r2 >> 6, t = r2 & 63;
        src = srcBase + ((size_t)(bb * 320 + t)) * 768;
        dst = lnZ + ((size_t)(s * 4096 + r2)) * 768;
    } else {
        int rx = r2 - 4096;
        int bb = rx >> 8, sx = rx & 255;
        src = srcBase + ((size_t)(bb * 320 + 64 + sx)) * 768;
        dst = lnX + ((size_t)(s * 16384 + rx)) * 768;
    }
    f4_t v[3];
    float s1 = 0.f, s2 = 0.f;
    #pragma unroll
    for (int jj = 0; jj < 3; jj++) {
        v[jj] = *reinterpret_cast<const f4_t*>(src + (lane + 64 * jj) * 4);
        #pragma unroll
        for (int e = 0; e < 4; e++) { s1 += v[jj][e]; s2 += v[jj][e] * v[jj][e]; }
    }
    #pragma unroll
    for (int o = 1; o < 64; o <<= 1) { s1 += __shfl_xor(s1, o); s2 += __shfl_xor(s2, o); }
    float mean = s1 * (1.0f / 768.0f);
    float var = s2 * (1.0f / 768.0f) - mean * mean;
    float rstd = rsqrtf(var + 1e-5f);
    #pragma unroll
    for (int jj = 0; jj < 3; jj++) {
        int c0 = (lane + 64 * jj) * 4;
        f4_t wv = *reinterpret_cast<const f4_t*>(w + c0);
        f4_t bv = *reinterpret_cast<const f4_t*>(b + c0);
        us4_t o4;
        #pragma unroll
        for (int e = 0; e < 4; e++)
            o4[e] = f2bf((v[jj][e] - mean) * rstd * wv[e] + bv[e]);
        *reinterpret_cast<us4_t*>(dst + c0) = o4;
    }
}

// ---------------- MFMA GEMM: C = A(MxK) * Bt(NxK)^T, epilogues -----------
// 1D grid, XCD-aware mapping: xcd owns contiguous row panels; cols inner.
// EPI_*_Z map row (s<<12 | b<<6 | t) to out row s*20480 + b*320 + t.
enum { EPI_BF16 = 0, EPI_RESID_Z = 1, EPI_GELU = 2 };

template <int BM, int BN, int WR, int WC, int EPI, int XB>
__global__ __launch_bounds__(WR * WC * 64, 1) void gemm_bt(
    const u16* __restrict__ A, const u16* __restrict__ Bt,
    int M, int N, int K, int ldc,
    float* __restrict__ Cf, u16* __restrict__ Cbf,
    const float* __restrict__ resid0, const float* __restrict__ resid1) {
    constexpr int THREADS = WR * WC * 64;
    constexpr int BK = 64;
    __shared__ alignas(16) u16 As[BM][BK + 8];
    __shared__ alignas(16) u16 Bs[BN][BK + 8];

    const int tid = threadIdx.x;
    const int lane = tid & 63;
    const int w = tid >> 6;
    const int wr = w / WC, wc = w % WC;
    const int r = lane & 15, g = lane >> 4;
    // XCD-aware block mapping (requires (M/BM)%8==0)
    const int gx = N / BN;
    const int panels = (M / BM) >> 3;
    int bid = blockIdx.x;
    int xcd = bid & 7, local = bid >> 3;
    const int bcol = (local % gx) * BN;
    const int brow = (xcd * panels + local / gx) * BM;

    f4_t acc[4][4];
    f4_t zero = {0.f, 0.f, 0.f, 0.f};
    #pragma unroll
    for (int m = 0; m < 4; m++)
        #pragma unroll
        for (int n = 0; n < 4; n++) acc[m][n] = zero;

    for (int k0 = 0; k0 < K; k0 += BK) {
        constexpr int CA = BM * BK / 8;
        #pragma unroll
        for (int i = 0; i < CA / THREADS; i++) {
            int c = tid + THREADS * i;
            int row = c >> 3, kc = (c & 7) * 8;
            bf8_t val = *reinterpret_cast<const bf8_t*>(A + (size_t)(brow + row) * K + k0 + kc);
            *reinterpret_cast<bf8_t*>(&As[row][kc]) = val;
        }
        constexpr int CB = BN * BK / 8;
        #pragma unroll
        for (int i = 0; i < CB / THREADS; i++) {
            int c = tid + THREADS * i;
            int row = c >> 3, kc = (c & 7) * 8;
            bf8_t val = *reinterpret_cast<const bf8_t*>(Bt + (size_t)(bcol + row) * K + k0 + kc);
            *reinterpret_cast<bf8_t*>(&Bs[row][kc]) = val;
        }
        __syncthreads();
        #pragma unroll
        for (int ks = 0; ks < BK; ks += 32) {
            bf8_t af[4], bfr[4];
            #pragma unroll
            for (int m = 0; m < 4; m++)
                af[m] = *reinterpret_cast<const bf8_t*>(&As[wr * 64 + m * 16 + r][ks + g * 8]);
            #pragma unroll
            for (int n = 0; n < 4; n++)
                bfr[n] = *reinterpret_cast<const bf8_t*>(&Bs[wc * 64 + n * 16 + r][ks + g * 8]);
            #pragma unroll
            for (int m = 0; m < 4; m++)
                #pragma unroll
                for (int n = 0; n < 4; n++)
                    acc[m][n] = __builtin_amdgcn_mfma_f32_16x16x32_bf16(af[m], bfr[n], acc[m][n], 0, 0, 0);
        }
        __syncthreads();
    }

    #pragma unroll
    for (int m = 0; m < 4; m++) {
        #pragma unroll
        for (int n = 0; n < 4; n++) {
            int col = bcol + wc * 64 + n * 16 + r;
            #pragma unroll
            for (int i = 0; i < 4; i++) {
                int row = brow + wr * 64 + m * 16 + g * 4 + i;
                int orow = row ^ XB;
                float val = acc[m][n][i];
                if constexpr (EPI == EPI_BF16) {
                    Cbf[(size_t)orow * ldc + col] = f2bf(val);
                } else if constexpr (EPI == EPI_RESID_Z) {
                    int s = orow >> 12, bb = (orow >> 6) & 63, t = orow & 63;
                    const float* rp = (s != 0) ? resid1 : resid0;
                    float rs = rp[((size_t)bb * 320 + t) * 768 + col];
                    Cf[((size_t)s * 20480 + bb * 320 + t) * 768 + col] = val + rs;
                } else if constexpr (EPI == EPI_GELU) {
                    Cbf[(size_t)orow * ldc + col] = f2bf(gelu_tanh(val));
                }
            }
        }
    }
}

// ---------------- MFMA attention per (s,b,h); kv stride 1536; out stride 832
__global__ __launch_bounds__(256, 2) void attn_mfma(
    const u16* __restrict__ q, const u16* __restrict__ kv,
    u16* __restrict__ aoh, u16* __restrict__ paff) {
    __shared__ alignas(16) u16 Ks[256][72];   // 36,864 B (P tiles alias after sync)
    __shared__ alignas(16) u16 Vt[64][264];   // 33,792 B
    int bid = blockIdx.x;
    int s = bid / 768;
    int rem = bid - s * 768;
    int b = rem / 12, h = rem - (rem / 12) * 12;
    int tid = threadIdx.x, lane = tid & 63, w = tid >> 6;
    int r = lane & 15, g = lane >> 4;

    size_t kvbase = ((size_t)(s * 16384 + b * 256)) * 1536 + h * 64;

    const u16* qrow = q + ((size_t)(s * 4096 + b * 64 + w * 16 + r)) * 768 + h * 64 + g * 8;
    bf8_t qf0 = *reinterpret_cast<const bf8_t*>(qrow);
    bf8_t qf1 = *reinterpret_cast<const bf8_t*>(qrow + 32);

    #pragma unroll
    for (int i = 0; i < 8; i++) {
        int c = tid + 256 * i;
        int row = c >> 3, kc = (c & 7) * 8;
        *reinterpret_cast<bf8_t*>(&Ks[row][kc]) =
            *reinterpret_cast<const bf8_t*>(kv + kvbase + (size_t)row * 1536 + kc);
    }
    u32* vt32 = reinterpret_cast<u32*>(&Vt[0][0]);  // row stride 132 u32
    #pragma unroll
    for (int i = 0; i < 4; i++) {
        int c = tid + 256 * i;
        int kp = c >> 3, d0 = (c & 7) * 8;
        const u16* vr = kv + kvbase + 768 + (size_t)(2 * kp) * 1536 + d0;
        us8_t va = *reinterpret_cast<const us8_t*>(vr);
        us8_t vb = *reinterpret_cast<const us8_t*>(vr + 1536);
        #pragma unroll
        for (int j = 0; j < 8; j++)
            vt32[(d0 + j) * 132 + kp] = (u32)va[j] | ((u32)vb[j] << 16);
    }
    __syncthreads();

    f4_t acc[16];
    f4_t zero = {0.f, 0.f, 0.f, 0.f};
    #pragma unroll
    for (int n = 0; n < 16; n++) acc[n] = zero;
    #pragma unroll
    for (int n = 0; n < 16; n++) {
        bf8_t b0 = *reinterpret_cast<const bf8_t*>(&Ks[n * 16 + r][g * 8]);
        acc[n] = __builtin_amdgcn_mfma_f32_16x16x32_bf16(qf0, b0, acc[n], 0, 0, 0);
        bf8_t b1 = *reinterpret_cast<const bf8_t*>(&Ks[n * 16 + r][32 + g * 8]);
        acc[n] = __builtin_amdgcn_mfma_f32_16x16x32_bf16(qf1, b1, acc[n], 0, 0, 0);
    }

    float mx[4] = {-1e30f, -1e30f, -1e30f, -1e30f};
    #pragma unroll
    for (int n = 0; n < 16; n++)
        #pragma unroll
        for (int i = 0; i < 4; i++) {
            acc[n][i] *= 0.125f;
            mx[i] = fmaxf(mx[i], acc[n][i]);
        }
    #pragma unroll
    for (int i = 0; i < 4; i++) {
        mx[i] = fmaxf(mx[i], __shfl_xor(mx[i], 1));
        mx[i] = fmaxf(mx[i], __shfl_xor(mx[i], 2));
        mx[i] = fmaxf(mx[i], __shfl_xor(mx[i], 4));
        mx[i] = fmaxf(mx[i], __shfl_xor(mx[i], 8));
    }
    float sm[4] = {0.f, 0.f, 0.f, 0.f};
    #pragma unroll
    for (int n = 0; n < 16; n++)
        #pragma unroll
        for (int i = 0; i < 4; i++) {
            float e = __expf(acc[n][i] - mx[i]);
            acc[n][i] = e;
            sm[i] += e;
        }
    #pragma unroll
    for (int i = 0; i < 4; i++) {
        sm[i] += __shfl_xor(sm[i], 1);
        sm[i] += __shfl_xor(sm[i], 2);
        sm[i] += __shfl_xor(sm[i], 4);
        sm[i] += __shfl_xor(sm[i], 8);
    }
    float inv[4];
    #pragma unroll
    for (int i = 0; i < 4; i++) inv[i] = 1.0f / sm[i];

    __syncthreads();  // all waves done reading Ks; safe to overwrite with P

    u16* Pw = &Ks[w * 64][0];
    u16* pout = paff + ((size_t)bid * 64 + w * 16) * 256;
    #pragma unroll
    for (int n = 0; n < 16; n++) {
        int kcol = n * 16 + r;
        #pragma unroll
        for (int i = 0; i < 4; i++) {
            u16 pb = f2bf(acc[n][i] * inv[i]);
            Pw[(g * 4 + i) * 264 + kcol] = pb;
            pout[(g * 4 + i) * 256 + kcol] = pb;
        }
    }

    f4_t acc2[4];
    #pragma unroll
    for (int n = 0; n < 4; n++) acc2[n] = zero;
    #pragma unroll
    for (int k2 = 0; k2 < 8; k2++) {
        bf8_t pa = *reinterpret_cast<const bf8_t*>(&Pw[r * 264 + k2 * 32 + g * 8]);
        #pragma unroll
        for (int n2 = 0; n2 < 4; n2++) {
            bf8_t vbf = *reinterpret_cast<const bf8_t*>(&Vt[n2 * 16 + r][k2 * 32 + g * 8]);
            acc2[n2] = __builtin_amdgcn_mfma_f32_16x16x32_bf16(pa, vbf, acc2[n2], 0, 0, 0);
        }
    }
    u16* op = aoh + ((size_t)(s * 4096 + b * 64 + w * 16 + g * 4)) * 832 + h * 64;
    #pragma unroll
    for (int n2 = 0; n2 < 4; n2++)
        #pragma unroll
        for (int i = 0; i < 4; i++)
            op[(size_t)i * 832 + n2 * 16 + r] = f2bf(acc2[n2][i]);
}

// ---------------- fusion_prep2: h-sum -> colmax -> nu/den + winner bitmask -
__global__ __launch_bounds__(256) void fusion_prep2(
    const u16* __restrict__ paff, float* __restrict__ aff, float* __restrict__ den,
    u64* __restrict__ winners) {
    int sb = blockIdx.x, qc = blockIdx.y;
    int t = threadIdx.x, lane = t & 63, w = t >> 6;
    int q0 = qc * 16;
    float a[16];
    #pragma unroll
    for (int j = 0; j < 16; j++) a[j] = 0.f;
    size_t base = ((size_t)sb * 12 * 64 + q0) * 256 + t;
    for (int h = 0; h < 12; h++) {
        size_t hb = base + (size_t)h * 64 * 256;
        #pragma unroll
        for (int j = 0; j < 16; j++) a[j] += bf2f(paff[hb + j * 256]);
    }
    float m[16];
    #pragma unroll
    for (int j = 0; j < 16; j++) {
        float v = a[j];
        #pragma unroll
        for (int o = 1; o < 64; o <<= 1) v = fmaxf(v, __shfl_xor(v, o));
        m[j] = v;
    }
    __shared__ float red[16][4];
    if (lane == 0) {
        #pragma unroll
        for (int j = 0; j < 16; j++) red[j][w] = m[j];
    }
    __syncthreads();
    float dsum = 0.f;
    u64 wmask = 0;
    float nu[16];
    #pragma unroll
    for (int j = 0; j < 16; j++) {
        float cm = fmaxf(fmaxf(red[j][0], red[j][1]), fmaxf(red[j][2], red[j][3]));
        nu[j] = (a[j] == cm) ? __expf(a[j] - 12.0f) : 0.f;
        if (nu[j] != 0.f) wmask |= (u64)1 << (q0 + j);
        dsum += nu[j];
    }
    if (dsum != 0.f) atomicAdd(&den[sb * 256 + t], dsum);
    if (wmask) atomicOr(&winners[(size_t)sb * 256 + t], wmask);
    float* ap = aff + ((size_t)sb * 256 + t) * 64 + q0;
    #pragma unroll
    for (int j = 0; j < 16; j++) ap[j] = nu[j];
}

// ---------------- fusion_apply_x: x rows only, bitmask gather -------------
__global__ __launch_bounds__(192) void fusion_apply_x(
    const float* __restrict__ x0, const float* __restrict__ x1,
    const float* __restrict__ aff, const float* __restrict__ den,
    const u64* __restrict__ winners, float* out) {
    int bid = blockIdx.x;          // 0..32767
    int s = bid >> 14;
    int rx = bid & 16383;
    int b = rx >> 8, sx = rx & 255;
    int sb = s * 64 + b;
    int tid = threadIdx.x;
    const float* xrow = ((s == 0) ? x0 : x1) + ((size_t)(b * 320 + 64 + sx)) * 768;
    float* orow = out + ((size_t)(s * 20480 + b * 320 + 64 + sx)) * 768;
    u64 mask = winners[(size_t)sb * 256 + sx];
    float invd = 1.0f / (1.0f + den[sb * 256 + sx]);
    f4_t a = *reinterpret_cast<const f4_t*>(xrow + tid * 4) * invd;
    while (mask) {
        int t = (int)__builtin_ctzll(mask);
        mask &= mask - 1;
        float nu = aff[((size_t)sb * 256 + sx) * 64 + t];
        float wgt = nu * invd;
        const float* zr = out + ((size_t)(s * 20480 + b * 320 + t)) * 768;
        f4_t z = *reinterpret_cast<const f4_t*>(zr + tid * 4);
        a += z * wgt;
    }
    *reinterpret_cast<f4_t*>(orow + tid * 4) = a;
}

// ---------------- ln2_mlp: coalesced f4, wave-owns-8-rows -----------------
__global__ __launch_bounds__(256, 3) void ln2_mlp(
    float* __restrict__ out, const float* __restrict__ w2,
    const float* __restrict__ b2, const u16* __restrict__ mdT,
    const u16* __restrict__ muT) {
    __shared__ alignas(16) u16 A[32][776];   // 49,664 B; reused for up-contribution
    __shared__ alignas(16) u16 Hs[32][72];   //  4,608 B
    int tid = threadIdx.x, lane = tid & 63, w = tid >> 6;
    int r = lane & 15, g = lane >> 4;
    int wm = w & 1, wh = w >> 1;
    size_t base = (size_t)blockIdx.x * 32 * 768;

    f4_t p[8][3];
    float mu[8], rs[8];
    #pragma unroll
    for (int rr = 0; rr < 8; rr++) {
        int row = w * 8 + rr;
        float a1 = 0.f, a2 = 0.f;
        #pragma unroll
        for (int cc = 0; cc < 3; cc++) {
            f4_t v = *reinterpret_cast<const f4_t*>(out + base + (size_t)row * 768 + cc * 256 + lane * 4);
            p[rr][cc] = v;
            #pragma unroll
            for (int e = 0; e < 4; e++) { a1 += v[e]; a2 += v[e] * v[e]; }
        }
        #pragma unroll
        for (int o = 1; o < 64; o <<= 1) { a1 += __shfl_xor(a1, o); a2 += __shfl_xor(a2, o); }
        float mean = a1 * (1.0f / 768.0f);
        float var = a2 * (1.0f / 768.0f) - mean * mean;
        mu[rr] = mean;
        rs[rr] = rsqrtf(var + 1e-5f);
    }
    #pragma unroll
    for (int rr = 0; rr < 8; rr++) {
        int row = w * 8 + rr;
        #pragma unroll
        for (int cc = 0; cc < 3; cc++) {
            int c0 = cc * 256 + lane * 4;
            f4_t wv = *reinterpret_cast<const f4_t*>(w2 + c0);
            f4_t bv = *reinterpret_cast<const f4_t*>(b2 + c0);
            us4_t o4;
            #pragma unroll
            for (int e = 0; e < 4; e++)
                o4[e] = f2bf((p[rr][cc][e] - mu[rr]) * rs[rr] * wv[e] + bv[e]);
            *reinterpret_cast<us4_t*>(&A[row][c0]) = o4;
        }
    }
    __syncthreads();

    f4_t zero = {0.f, 0.f, 0.f, 0.f};
    f4_t hacc[2] = {zero, zero};
    for (int k0 = 0; k0 < 768; k0 += 32) {
        bf8_t af = *reinterpret_cast<const bf8_t*>(&A[wm * 16 + r][k0 + g * 8]);
        #pragma unroll
        for (int t = 0; t < 2; t++) {
            bf8_t bf = *reinterpret_cast<const bf8_t*>(
                mdT + (size_t)((wh * 2 + t) * 16 + r) * 768 + k0 + g * 8);
            hacc[t] = __builtin_amdgcn_mfma_f32_16x16x32_bf16(af, bf, hacc[t], 0, 0, 0);
        }
    }
    #pragma unroll
    for (int t = 0; t < 2; t++)
        #pragma unroll
        for (int i = 0; i < 4; i++)
            Hs[wm * 16 + g * 4 + i][(wh * 2 + t) * 16 + r] = f2bf(gelu_tanh(hacc[t][i]));
    __syncthreads();

    bf8_t a0 = *reinterpret_cast<const bf8_t*>(&Hs[wm * 16 + r][g * 8]);
    bf8_t a1 = *reinterpret_cast<const bf8_t*>(&Hs[wm * 16 + r][32 + g * 8]);
    #pragma unroll
    for (int nn = 0; nn < 24; nn++) {
        int col = (wh * 24 + nn) * 16 + r;
        bf8_t b0 = *reinterpret_cast<const bf8_t*>(muT + (size_t)col * 64 + g * 8);
        bf8_t b1 = *reinterpret_cast<const bf8_t*>(muT + (size_t)col * 64 + 32 + g * 8);
        f4_t c = __builtin_amdgcn_mfma_f32_16x16x32_bf16(a1, b1, zero, 0, 0, 0);
        c = __builtin_amdgcn_mfma_f32_16x16x32_bf16(a0, b0, c, 0, 0, 0);
        #pragma unroll
        for (int i = 0; i < 4; i++)
            A[wm * 16 + g * 4 + i][col] = f2bf(c[i]);
    }
    __syncthreads();

    #pragma unroll
    for (int rr = 0; rr < 8; rr++) {
        int row = w * 8 + rr;
        #pragma unroll
        for (int cc = 0; cc < 3; cc++) {
            int c0 = cc * 256 + lane * 4;
            us4_t c4 = *reinterpret_cast<const us4_t*>(&A[row][c0]);
            f4_t o = p[rr][cc];
            #pragma unroll
            for (int e = 0; e < 4; e++) o[e] += bf2f(c4[e]);
            *reinterpret_cast<f4_t*>(out + base + (size_t)row * 768 + c0) = o;
        }
    }
}

extern "C" void kernel_launch(void* const* d_in, const int* in_sizes, int n_in,
                              void* d_out, int out_size, void* d_ws, size_t ws_size,
                              hipStream_t stream) {
    (void)in_sizes; (void)n_in; (void)out_size;
    const float* x0 = (const float*)d_in[0];
    const float* x1 = (const float*)d_in[1];
    const float* ln1w = (const float*)d_in[2];
    const float* ln1b = (const float*)d_in[3];
    const float* ln2w = (const float*)d_in[4];
    const float* ln2b = (const float*)d_in[5];
    const float* wq = (const float*)d_in[6];
    const float* wk = (const float*)d_in[7];
    const float* wv = (const float*)d_in[8];
    const float* wo = (const float*)d_in[9];
    const float* lora_down = (const float*)d_in[10];
    const float* lora_up = (const float*)d_in[11];
    const float* mlp_down = (const float*)d_in[12];
    const float* mlp_up = (const float*)d_in[13];
    float* out = (float*)d_out;

    char* ws = (char*)d_ws;
    size_t off = 0;
    auto alloc = [&](size_t bytes) -> char* {
        char* p = ws + off;
        off = (off + bytes + 255) & ~(size_t)255;
        return p;
    };
    u16* wtq  = (u16*)alloc(768 * 768 * 2);
    u16* wtkv = (u16*)alloc((size_t)1536 * 768 * 2);
    u16* wtoU = (u16*)alloc((size_t)768 * 832 * 2);
    u16* dT  = (u16*)alloc(768 * 64 * 2);
    u16* mdT = (u16*)alloc(768 * 64 * 2);
    u16* muT = (u16*)alloc(768 * 64 * 2);
    u16* lnZ = (u16*)alloc((size_t)2 * 4096 * 768 * 2);
    u16* lnX = (u16*)alloc((size_t)2 * 16384 * 768 * 2);
    u16* qb  = (u16*)alloc((size_t)2 * 4096 * 768 * 2);
    u16* kvb = (u16*)alloc((size_t)2 * 16384 * 1536 * 2);
    u16* aoh = (u16*)alloc((size_t)2 * 4096 * 832 * 2);
    float* aff = (float*)alloc((size_t)2 * 64 * 256 * 64 * 4);
    float* den = (float*)alloc((size_t)2 * 64 * 256 * 4);
    u64* winners = (u64*)alloc((size_t)2 * 64 * 256 * 8);
    // aliases (lifetimes disjoint by stream order):
    u16* paff = lnX;               // 2*768*64*256*2 == lnX region exactly (lnX dead after kv proj)
    if (ws_size < off) return;     // ws too small -> leave poison (diagnosable)

    // 1. weight prep; k,v stacked into wtkv; wo + lora_up stacked into wtoU (k=832)
    TPack big = {wq, wk, wv, wo, wtq, wtkv, wtkv + (size_t)768 * 768, wtoU};
    transpose_big<<<dim3(2304, 4), 256, 0, stream>>>(big);
    TPack small = {lora_down, lora_up, mlp_down, mlp_up, dT, wtoU + 768, mdT, muT};
    transpose_small<<<dim3(192, 4), 256, 0, stream>>>(small);
    hipMemsetAsync(den, 0, (size_t)2 * 64 * 256 * 4, stream);
    hipMemsetAsync(winners, 0, (size_t)2 * 64 * 256 * 8, stream);
    // 2. LN1 (wave-per-row, f4)
    ln1_kernel<<<10240, 256, 0, stream>>>(x0, x1, ln1w, ln1b, lnZ, lnX);
    // 3. q projection; fused kv projection (cross-stream via row^16384); XCD-swizzled
    gemm_bt<128, 128, 2, 2, EPI_BF16, 0><<<384, 256, 0, stream>>>(
        lnZ, wtq, 8192, 768, 768, 768, nullptr, qb, nullptr, nullptr);
    gemm_bt<128, 128, 2, 2, EPI_BF16, 16384><<<3072, 256, 0, stream>>>(
        lnX, wtkv, 32768, 1536, 768, 1536, nullptr, kvb, nullptr, nullptr);
    // 4. attention (MFMA); out -> aoh cols 0..767 (stride 832); paff over dead lnX
    attn_mfma<<<1536, 256, 0, stream>>>(qb, kvb, aoh, paff);
    // 5. fusion prep (h-sum reduce + colmax + nu/den/winners)
    fusion_prep2<<<dim3(128, 4), 256, 0, stream>>>(paff, aff, den, winners);
    // 6. lora-z down (gelu, row^4096) -> aoh cols 768..831; merged (wo|up) GEMM + resid
    gemm_bt<128, 64, 2, 1, EPI_GELU, 4096><<<64, 128, 0, stream>>>(
        lnZ, dT, 8192, 64, 768, 832, nullptr, aoh + 768, nullptr, nullptr);
    gemm_bt<128, 128, 2, 2, EPI_RESID_Z, 0><<<384, 256, 0, stream>>>(
        aoh, wtoU, 8192, 768, 832, 768, out, nullptr, x0, x1);
    // 7. fusion apply (x rows only; z rows already final in out)
    fusion_apply_x<<<32768, 192, 0, stream>>>(x0, x1, aff, den, winners, out);
    // 8. fused LN2 + mlp lora (in-place on out)
    ln2_mlp<<<1280, 256, 0, stream>>>(out, ln2w, ln2b, mdT, muT);
}

// Round 8
// 418.884 us; speedup vs baseline: 2.3719x; 1.0465x over previous
//
#include <hip/hip_runtime.h>

// TMMixer: B=64, T=64, S=256, DIM=768, H=12, HD=64, RANK=64
// Pipeline (all bf16 MFMA GEMMs, f32 accumulation):
//  1. transpose weights -> bf16; k+v stacked into wtkv; wo+lora_up stacked into wtoU[768][832]
//  2. LN1 -> bf16 (f4 vectorized, wave-per-row)
//  3. q projection; fused k+v projection (N=1536); XCD-swizzled 1D grid
//     GEMM staging via global_load_lds(16B) + XOR-swizzled LDS (linear dest, pre-swizzled src)
//  4. attention: MFMA QK^T -> wave-local softmax -> MFMA PV; out -> aoh[.][0:768] (stride 832)
//  5. fusion_prep2: h-sum reduce -> colmax -> nu, den partials + winner bitmask
//  6. lora-z down (gelu) -> aoh[.][768:832] (row^4096); merged (wo|up) GEMM K=832 + resid
//  7. fusion_apply_x: x rows only; bitmask-gathered weighted z adds
//  8. ln2_mlp: coalesced f4 in/out, wave-owns-8-rows LN, 3 blocks/CU

typedef __bf16 bf8_t __attribute__((ext_vector_type(8)));
typedef float f4_t __attribute__((ext_vector_type(4)));
typedef unsigned short u16;
typedef unsigned int u32;
typedef unsigned long long u64;
typedef unsigned short us4_t __attribute__((ext_vector_type(4)));
typedef unsigned short us8_t __attribute__((ext_vector_type(8)));

__device__ __forceinline__ float bf2f(u16 h) {
    return __uint_as_float(((unsigned int)h) << 16);
}
__device__ __forceinline__ u16 f2bf(float f) {
    unsigned int u = __float_as_uint(f);
    u += 0x7fffu + ((u >> 16) & 1u);
    return (u16)(u >> 16);
}
__device__ __forceinline__ float gelu_tanh(float x) {
    float t = tanhf(0.7978845608028654f * (x + 0.044715f * x * x * x));
    return 0.5f * x * (1.0f + t);
}
__device__ __forceinline__ void load_lds16(const void* g, void* l) {
    __builtin_amdgcn_global_load_lds(
        (const __attribute__((address_space(1))) unsigned int*)g,
        (__attribute__((address_space(3))) unsigned int*)l, 16, 0, 0);
}

// ---------------- weight prep ----------------
struct TPack {
    const float* s0; const float* s1; const float* s2; const float* s3;
    u16* d0; u16* d1; u16* d2; u16* d3;
};
__global__ __launch_bounds__(256) void transpose_big(TPack p) {
    int which = blockIdx.y;
    const float* src = which == 0 ? p.s0 : which == 1 ? p.s1 : which == 2 ? p.s2 : p.s3;
    u16* dst = which == 0 ? p.d0 : which == 1 ? p.d1 : which == 2 ? p.d2 : p.d3;
    int idx = blockIdx.x * 256 + threadIdx.x;  // 768*768
    int c = idx / 768, r = idx - c * 768;
    u16 v = f2bf(src[(size_t)r * 768 + c]);
    if (which == 3) dst[(size_t)c * 832 + r] = v;   // wtoU k-cols 0..767
    else dst[idx] = v;
}
__global__ __launch_bounds__(256) void transpose_small(TPack p) {
    int which = blockIdx.y;
    const float* src = which == 0 ? p.s0 : which == 1 ? p.s1 : which == 2 ? p.s2 : p.s3;
    u16* dst = which == 0 ? p.d0 : which == 1 ? p.d1 : which == 2 ? p.d2 : p.d3;
    int R = (which & 1) ? 64 : 768;
    int C = (which & 1) ? 768 : 64;
    int idx = blockIdx.x * 256 + threadIdx.x;  // 49152
    int c = idx / R, r = idx - c * R;
    u16 v = f2bf(src[(size_t)r * C + c]);
    if (which == 1) dst[(size_t)c * 832 + r] = v;   // wtoU+768: k-cols 768..831
    else dst[idx] = v;
}

// ---------------- LN1: wave-per-row, f4 loads ----------
__global__ __launch_bounds__(256) void ln1_kernel(
    const float* __restrict__ x0, const float* __restrict__ x1,
    const float* __restrict__ w, const float* __restrict__ b,
    u16* __restrict__ lnZ, u16* __restrict__ lnX) {
    int rid = blockIdx.x * 4 + (threadIdx.x >> 6);
    int lane = threadIdx.x & 63;
    int s = rid / 20480;
    int r2 = rid - s * 20480;
    const float* srcBase = (s == 0) ? x0 : x1;
    const float* src; u16* dst;
    if (r2 < 4096) {
        int bb = r2 >> 6, t = r2 & 63;
        src = srcBase + ((size_t)(bb * 320 + t)) * 768;
        dst = lnZ + ((size_t)(s * 4096 + r2)) * 768;
    } else {
        int rx = r2 - 4096;
        int bb = rx >> 8, sx = rx & 255;
        src = srcBase + ((size_t)(bb * 320 + 64 + sx)) * 768;
        dst = lnX + ((size_t)(s * 16384 + rx)) * 768;
    }
    f4_t v[3];
    float s1 = 0.f, s2 = 0.f;
    #pragma unroll
    for (int jj = 0; jj < 3; jj++) {
        v[jj] = *reinterpret_cast<const f4_t*>(src + (lane + 64 * jj) * 4);
        #pragma unroll
        for (int e = 0; e < 4; e++) { s1 += v[jj][e]; s2 += v[jj][e] * v[jj][e]; }
    }
    #pragma unroll
    for (int o = 1; o < 64; o <<= 1) { s1 += __shfl_xor(s1, o); s2 += __shfl_xor(s2, o); }
    float mean = s1 * (1.0f / 768.0f);
    float var = s2 * (1.0f / 768.0f) - mean * mean;
    float rstd = rsqrtf(var + 1e-5f);
    #pragma unroll
    for (int jj = 0; jj < 3; jj++) {
        int c0 = (lane + 64 * jj) * 4;
        f4_t wv = *reinterpret_cast<const f4_t*>(w + c0);
        f4_t bv = *reinterpret_cast<const f4_t*>(b + c0);
        us4_t o4;
        #pragma unroll
        for (int e = 0; e < 4; e++)
            o4[e] = f2bf((v[jj][e] - mean) * rstd * wv[e] + bv[e]);
        *reinterpret_cast<us4_t*>(dst + c0) = o4;
    }
}

// ---------------- MFMA GEMM: C = A(MxK) * Bt(NxK)^T, epilogues -----------
// global_load_lds staging: LDS linear [R][64], source chunk pre-swizzled by
// (lane&7)^(lane>>3); ds_read applies col16 ^= (row&7). 1D XCD-aware grid.
enum { EPI_BF16 = 0, EPI_RESID_Z = 1, EPI_GELU = 2 };

template <int BM, int BN, int WR, int WC, int EPI, int XB>
__global__ __launch_bounds__(WR * WC * 64, 1) void gemm_bt(
    const u16* __restrict__ A, const u16* __restrict__ Bt,
    int M, int N, int K, int ldc,
    float* __restrict__ Cf, u16* __restrict__ Cbf,
    const float* __restrict__ resid0, const float* __restrict__ resid1) {
    constexpr int THREADS = WR * WC * 64;
    constexpr int NW = THREADS / 64;
    constexpr int BK = 64;
    __shared__ alignas(16) u16 As[BM * BK];
    __shared__ alignas(16) u16 Bs[BN * BK];

    const int tid = threadIdx.x;
    const int lane = tid & 63;
    const int w = tid >> 6;
    const int wr = w / WC, wc = w % WC;
    const int r = lane & 15, g = lane >> 4;
    // XCD-aware block mapping (requires (M/BM)%8==0)
    const int gx = N / BN;
    const int panels = (M / BM) >> 3;
    int bid = blockIdx.x;
    int xcd = bid & 7, local = bid >> 3;
    const int bcol = (local % gx) * BN;
    const int brow = (xcd * panels + local / gx) * BM;

    // staging geometry: 1 KB per wave-instruction = 8 rows x 64 cols bf16
    const int srow = lane >> 3;            // row within 8-row chunk
    const int scol = (lane & 7) ^ srow;    // pre-swizzled 16B-chunk index
    const int rsw = r & 7;                 // read-side swizzle key

    f4_t acc[4][4];
    f4_t zero = {0.f, 0.f, 0.f, 0.f};
    #pragma unroll
    for (int m = 0; m < 4; m++)
        #pragma unroll
        for (int n = 0; n < 4; n++) acc[m][n] = zero;

    for (int k0 = 0; k0 < K; k0 += BK) {
        #pragma unroll
        for (int c = 0; c < BM / 8 / NW; c++) {
            int chunk = w + c * NW;
            int row = chunk * 8 + srow;
            load_lds16(A + (size_t)(brow + row) * K + k0 + scol * 8, As + chunk * 512);
        }
        #pragma unroll
        for (int c = 0; c < BN / 8 / NW; c++) {
            int chunk = w + c * NW;
            int row = chunk * 8 + srow;
            load_lds16(Bt + (size_t)(bcol + row) * K + k0 + scol * 8, Bs + chunk * 512);
        }
        __syncthreads();
        #pragma unroll
        for (int ks = 0; ks < BK; ks += 32) {
            const int c16 = (ks >> 3) + g;         // 16B-chunk col (0..7)
            const int csw = (c16 ^ rsw) * 8;       // swizzled element offset
            bf8_t af[4], bfr[4];
            #pragma unroll
            for (int m = 0; m < 4; m++)
                af[m] = *reinterpret_cast<const bf8_t*>(&As[(wr * 64 + m * 16 + r) * 64 + csw]);
            #pragma unroll
            for (int n = 0; n < 4; n++)
                bfr[n] = *reinterpret_cast<const bf8_t*>(&Bs[(wc * 64 + n * 16 + r) * 64 + csw]);
            #pragma unroll
            for (int m = 0; m < 4; m++)
                #pragma unroll
                for (int n = 0; n < 4; n++)
                    acc[m][n] = __builtin_amdgcn_mfma_f32_16x16x32_bf16(af[m], bfr[n], acc[m][n], 0, 0, 0);
        }
        __syncthreads();
    }

    #pragma unroll
    for (int m = 0; m < 4; m++) {
        #pragma unroll
        for (int n = 0; n < 4; n++) {
            int col = bcol + wc * 64 + n * 16 + r;
            #pragma unroll
            for (int i = 0; i < 4; i++) {
                int row = brow + wr * 64 + m * 16 + g * 4 + i;
                int orow = row ^ XB;
                float val = acc[m][n][i];
                if constexpr (EPI == EPI_BF16) {
                    Cbf[(size_t)orow * ldc + col] = f2bf(val);
                } else if constexpr (EPI == EPI_RESID_Z) {
                    int s = orow >> 12, bb = (orow >> 6) & 63, t = orow & 63;
                    const float* rp = (s != 0) ? resid1 : resid0;
                    float rs = rp[((size_t)bb * 320 + t) * 768 + col];
                    Cf[((size_t)s * 20480 + bb * 320 + t) * 768 + col] = val + rs;
                } else if constexpr (EPI == EPI_GELU) {
                    Cbf[(size_t)orow * ldc + col] = f2bf(gelu_tanh(val));
                }
            }
        }
    }
}

// ---------------- MFMA attention per (s,b,h); kv stride 1536; out stride 832
__global__ __launch_bounds__(256, 2) void attn_mfma(
    const u16* __restrict__ q, const u16* __restrict__ kv,
    u16* __restrict__ aoh, u16* __restrict__ paff) {
    __shared__ alignas(16) u16 Ks[256][72];   // 36,864 B (P tiles alias after sync)
    __shared__ alignas(16) u16 Vt[64][264];   // 33,792 B
    int bid = blockIdx.x;
    int s = bid / 768;
    int rem = bid - s * 768;
    int b = rem / 12, h = rem - (rem / 12) * 12;
    int tid = threadIdx.x, lane = tid & 63, w = tid >> 6;
    int r = lane & 15, g = lane >> 4;

    size_t kvbase = ((size_t)(s * 16384 + b * 256)) * 1536 + h * 64;

    const u16* qrow = q + ((size_t)(s * 4096 + b * 64 + w * 16 + r)) * 768 + h * 64 + g * 8;
    bf8_t qf0 = *reinterpret_cast<const bf8_t*>(qrow);
    bf8_t qf1 = *reinterpret_cast<const bf8_t*>(qrow + 32);

    #pragma unroll
    for (int i = 0; i < 8; i++) {
        int c = tid + 256 * i;
        int row = c >> 3, kc = (c & 7) * 8;
        *reinterpret_cast<bf8_t*>(&Ks[row][kc]) =
            *reinterpret_cast<const bf8_t*>(kv + kvbase + (size_t)row * 1536 + kc);
    }
    u32* vt32 = reinterpret_cast<u32*>(&Vt[0][0]);  // row stride 132 u32
    #pragma unroll
    for (int i = 0; i < 4; i++) {
        int c = tid + 256 * i;
        int kp = c >> 3, d0 = (c & 7) * 8;
        const u16* vr = kv + kvbase + 768 + (size_t)(2 * kp) * 1536 + d0;
        us8_t va = *reinterpret_cast<const us8_t*>(vr);
        us8_t vb = *reinterpret_cast<const us8_t*>(vr + 1536);
        #pragma unroll
        for (int j = 0; j < 8; j++)
            vt32[(d0 + j) * 132 + kp] = (u32)va[j] | ((u32)vb[j] << 16);
    }
    __syncthreads();

    f4_t acc[16];
    f4_t zero = {0.f, 0.f, 0.f, 0.f};
    #pragma unroll
    for (int n = 0; n < 16; n++) acc[n] = zero;
    #pragma unroll
    for (int n = 0; n < 16; n++) {
        bf8_t b0 = *reinterpret_cast<const bf8_t*>(&Ks[n * 16 + r][g * 8]);
        acc[n] = __builtin_amdgcn_mfma_f32_16x16x32_bf16(qf0, b0, acc[n], 0, 0, 0);
        bf8_t b1 = *reinterpret_cast<const bf8_t*>(&Ks[n * 16 + r][32 + g * 8]);
        acc[n] = __builtin_amdgcn_mfma_f32_16x16x32_bf16(qf1, b1, acc[n], 0, 0, 0);
    }

    float mx[4] = {-1e30f, -1e30f, -1e30f, -1e30f};
    #pragma unroll
    for (int n = 0; n < 16; n++)
        #pragma unroll
        for (int i = 0; i < 4; i++) {
            acc[n][i] *= 0.125f;
            mx[i] = fmaxf(mx[i], acc[n][i]);
        }
    #pragma unroll
    for (int i = 0; i < 4; i++) {
        mx[i] = fmaxf(mx[i], __shfl_xor(mx[i], 1));
        mx[i] = fmaxf(mx[i], __shfl_xor(mx[i], 2));
        mx[i] = fmaxf(mx[i], __shfl_xor(mx[i], 4));
        mx[i] = fmaxf(mx[i], __shfl_xor(mx[i], 8));
    }
    float sm[4] = {0.f, 0.f, 0.f, 0.f};
    #pragma unroll
    for (int n = 0; n < 16; n++)
        #pragma unroll
        for (int i = 0; i < 4; i++) {
            float e = __expf(acc[n][i] - mx[i]);
            acc[n][i] = e;
            sm[i] += e;
        }
    #pragma unroll
    for (int i = 0; i < 4; i++) {
        sm[i] += __shfl_xor(sm[i], 1);
        sm[i] += __shfl_xor(sm[i], 2);
        sm[i] += __shfl_xor(sm[i], 4);
        sm[i] += __shfl_xor(sm[i], 8);
    }
    float inv[4];
    #pragma unroll
    for (int i = 0; i < 4; i++) inv[i] = 1.0f / sm[i];

    __syncthreads();  // all waves done reading Ks; safe to overwrite with P

    u16* Pw = &Ks[w * 64][0];
    u16* pout = paff + ((size_t)bid * 64 + w * 16) * 256;
    #pragma unroll
    for (int n = 0; n < 16; n++) {
        int kcol = n * 16 + r;
        #pragma unroll
        for (int i = 0; i < 4; i++) {
            u16 pb = f2bf(acc[n][i] * inv[i]);
            Pw[(g * 4 + i) * 264 + kcol] = pb;
            pout[(g * 4 + i) * 256 + kcol] = pb;
        }
    }

    f4_t acc2[4];
    #pragma unroll
    for (int n = 0; n < 4; n++) acc2[n] = zero;
    #pragma unroll
    for (int k2 = 0; k2 < 8; k2++) {
        bf8_t pa = *reinterpret_cast<const bf8_t*>(&Pw[r * 264 + k2 * 32 + g * 8]);
        #pragma unroll
        for (int n2 = 0; n2 < 4; n2++) {
            bf8_t vbf = *reinterpret_cast<const bf8_t*>(&Vt[n2 * 16 + r][k2 * 32 + g * 8]);
            acc2[n2] = __builtin_amdgcn_mfma_f32_16x16x32_bf16(pa, vbf, acc2[n2], 0, 0, 0);
        }
    }
    u16* op = aoh + ((size_t)(s * 4096 + b * 64 + w * 16 + g * 4)) * 832 + h * 64;
    #pragma unroll
    for (int n2 = 0; n2 < 4; n2++)
        #pragma unroll
        for (int i = 0; i < 4; i++)
            op[(size_t)i * 832 + n2 * 16 + r] = f2bf(acc2[n2][i]);
}

// ---------------- fusion_prep2: h-sum -> colmax -> nu/den + winner bitmask -
__global__ __launch_bounds__(256) void fusion_prep2(
    const u16* __restrict__ paff, float* __restrict__ aff, float* __restrict__ den,
    u64* __restrict__ winners) {
    int sb = blockIdx.x, qc = blockIdx.y;
    int t = threadIdx.x, lane = t & 63, w = t >> 6;
    int q0 = qc * 16;
    float a[16];
    #pragma unroll
    for (int j = 0; j < 16; j++) a[j] = 0.f;
    size_t base = ((size_t)sb * 12 * 64 + q0) * 256 + t;
    for (int h = 0; h < 12; h++) {
        size_t hb = base + (size_t)h * 64 * 256;
        #pragma unroll
        for (int j = 0; j < 16; j++) a[j] += bf2f(paff[hb + j * 256]);
    }
    float m[16];
    #pragma unroll
    for (int j = 0; j < 16; j++) {
        float v = a[j];
        #pragma unroll
        for (int o = 1; o < 64; o <<= 1) v = fmaxf(v, __shfl_xor(v, o));
        m[j] = v;
    }
    __shared__ float red[16][4];
    if (lane == 0) {
        #pragma unroll
        for (int j = 0; j < 16; j++) red[j][w] = m[j];
    }
    __syncthreads();
    float dsum = 0.f;
    u64 wmask = 0;
    float nu[16];
    #pragma unroll
    for (int j = 0; j < 16; j++) {
        float cm = fmaxf(fmaxf(red[j][0], red[j][1]), fmaxf(red[j][2], red[j][3]));
        nu[j] = (a[j] == cm) ? __expf(a[j] - 12.0f) : 0.f;
        if (nu[j] != 0.f) wmask |= (u64)1 << (q0 + j);
        dsum += nu[j];
    }
    if (dsum != 0.f) atomicAdd(&den[sb * 256 + t], dsum);
    if (wmask) atomicOr(&winners[(size_t)sb * 256 + t], wmask);
    float* ap = aff + ((size_t)sb * 256 + t) * 64 + q0;
    #pragma unroll
    for (int j = 0; j < 16; j++) ap[j] = nu[j];
}

// ---------------- fusion_apply_x: x rows only, bitmask gather -------------
__global__ __launch_bounds__(192) void fusion_apply_x(
    const float* __restrict__ x0, const float* __restrict__ x1,
    const float* __restrict__ aff, const float* __restrict__ den,
    const u64* __restrict__ winners, float* out) {
    int bid = blockIdx.x;          // 0..32767
    int s = bid >> 14;
    int rx = bid & 16383;
    int b = rx >> 8, sx = rx & 255;
    int sb = s * 64 + b;
    int tid = threadIdx.x;
    const float* xrow = ((s == 0) ? x0 : x1) + ((size_t)(b * 320 + 64 + sx)) * 768;
    float* orow = out + ((size_t)(s * 20480 + b * 320 + 64 + sx)) * 768;
    u64 mask = winners[(size_t)sb * 256 + sx];
    float invd = 1.0f / (1.0f + den[sb * 256 + sx]);
    f4_t a = *reinterpret_cast<const f4_t*>(xrow + tid * 4) * invd;
    while (mask) {
        int t = (int)__builtin_ctzll(mask);
        mask &= mask - 1;
        float nu = aff[((size_t)sb * 256 + sx) * 64 + t];
        float wgt = nu * invd;
        const float* zr = out + ((size_t)(s * 20480 + b * 320 + t)) * 768;
        f4_t z = *reinterpret_cast<const f4_t*>(zr + tid * 4);
        a += z * wgt;
    }
    *reinterpret_cast<f4_t*>(orow + tid * 4) = a;
}

// ---------------- ln2_mlp: coalesced f4, wave-owns-8-rows -----------------
__global__ __launch_bounds__(256, 3) void ln2_mlp(
    float* __restrict__ out, const float* __restrict__ w2,
    const float* __restrict__ b2, const u16* __restrict__ mdT,
    const u16* __restrict__ muT) {
    __shared__ alignas(16) u16 A[32][776];   // 49,664 B; reused for up-contribution
    __shared__ alignas(16) u16 Hs[32][72];   //  4,608 B
    int tid = threadIdx.x, lane = tid & 63, w = tid >> 6;
    int r = lane & 15, g = lane >> 4;
    int wm = w & 1, wh = w >> 1;
    size_t base = (size_t)blockIdx.x * 32 * 768;

    f4_t p[8][3];
    float mu[8], rs[8];
    #pragma unroll
    for (int rr = 0; rr < 8; rr++) {
        int row = w * 8 + rr;
        float a1 = 0.f, a2 = 0.f;
        #pragma unroll
        for (int cc = 0; cc < 3; cc++) {
            f4_t v = *reinterpret_cast<const f4_t*>(out + base + (size_t)row * 768 + cc * 256 + lane * 4);
            p[rr][cc] = v;
            #pragma unroll
            for (int e = 0; e < 4; e++) { a1 += v[e]; a2 += v[e] * v[e]; }
        }
        #pragma unroll
        for (int o = 1; o < 64; o <<= 1) { a1 += __shfl_xor(a1, o); a2 += __shfl_xor(a2, o); }
        float mean = a1 * (1.0f / 768.0f);
        float var = a2 * (1.0f / 768.0f) - mean * mean;
        mu[rr] = mean;
        rs[rr] = rsqrtf(var + 1e-5f);
    }
    #pragma unroll
    for (int rr = 0; rr < 8; rr++) {
        int row = w * 8 + rr;
        #pragma unroll
        for (int cc = 0; cc < 3; cc++) {
            int c0 = cc * 256 + lane * 4;
            f4_t wv = *reinterpret_cast<const f4_t*>(w2 + c0);
            f4_t bv = *reinterpret_cast<const f4_t*>(b2 + c0);
            us4_t o4;
            #pragma unroll
            for (int e = 0; e < 4; e++)
                o4[e] = f2bf((p[rr][cc][e] - mu[rr]) * rs[rr] * wv[e] + bv[e]);
            *reinterpret_cast<us4_t*>(&A[row][c0]) = o4;
        }
    }
    __syncthreads();

    f4_t zero = {0.f, 0.f, 0.f, 0.f};
    f4_t hacc[2] = {zero, zero};
    for (int k0 = 0; k0 < 768; k0 += 32) {
        bf8_t af = *reinterpret_cast<const bf8_t*>(&A[wm * 16 + r][k0 + g * 8]);
        #pragma unroll
        for (int t = 0; t < 2; t++) {
            bf8_t bf = *reinterpret_cast<const bf8_t*>(
                mdT + (size_t)((wh * 2 + t) * 16 + r) * 768 + k0 + g * 8);
            hacc[t] = __builtin_amdgcn_mfma_f32_16x16x32_bf16(af, bf, hacc[t], 0, 0, 0);
        }
    }
    #pragma unroll
    for (int t = 0; t < 2; t++)
        #pragma unroll
        for (int i = 0; i < 4; i++)
            Hs[wm * 16 + g * 4 + i][(wh * 2 + t) * 16 + r] = f2bf(gelu_tanh(hacc[t][i]));
    __syncthreads();

    bf8_t a0 = *reinterpret_cast<const bf8_t*>(&Hs[wm * 16 + r][g * 8]);
    bf8_t a1 = *reinterpret_cast<const bf8_t*>(&Hs[wm * 16 + r][32 + g * 8]);
    #pragma unroll
    for (int nn = 0; nn < 24; nn++) {
        int col = (wh * 24 + nn) * 16 + r;
        bf8_t b0 = *reinterpret_cast<const bf8_t*>(muT + (size_t)col * 64 + g * 8);
        bf8_t b1 = *reinterpret_cast<const bf8_t*>(muT + (size_t)col * 64 + 32 + g * 8);
        f4_t c = __builtin_amdgcn_mfma_f32_16x16x32_bf16(a1, b1, zero, 0, 0, 0);
        c = __builtin_amdgcn_mfma_f32_16x16x32_bf16(a0, b0, c, 0, 0, 0);
        #pragma unroll
        for (int i = 0; i < 4; i++)
            A[wm * 16 + g * 4 + i][col] = f2bf(c[i]);
    }
    __syncthreads();

    #pragma unroll
    for (int rr = 0; rr < 8; rr++) {
        int row = w * 8 + rr;
        #pragma unroll
        for (int cc = 0; cc < 3; cc++) {
            int c0 = cc * 256 + lane * 4;
            us4_t c4 = *reinterpret_cast<const us4_t*>(&A[row][c0]);
            f4_t o = p[rr][cc];
            #pragma unroll
            for (int e = 0; e < 4; e++) o[e] += bf2f(c4[e]);
            *reinterpret_cast<f4_t*>(out + base + (size_t)row * 768 + c0) = o;
        }
    }
}

extern "C" void kernel_launch(void* const* d_in, const int* in_sizes, int n_in,
                              void* d_out, int out_size, void* d_ws, size_t ws_size,
                              hipStream_t stream) {
    (void)in_sizes; (void)n_in; (void)out_size;
    const float* x0 = (const float*)d_in[0];
    const float* x1 = (const float*)d_in[1];
    const float* ln1w = (const float*)d_in[2];
    const float* ln1b = (const float*)d_in[3];
    const float* ln2w = (const float*)d_in[4];
    const float* ln2b = (const float*)d_in[5];
    const float* wq = (const float*)d_in[6];
    const float* wk = (const float*)d_in[7];
    const float* wv = (const float*)d_in[8];
    const float* wo = (const float*)d_in[9];
    const float* lora_down = (const float*)d_in[10];
    const float* lora_up = (const float*)d_in[11];
    const float* mlp_down = (const float*)d_in[12];
    const float* mlp_up = (const float*)d_in[13];
    float* out = (float*)d_out;

    char* ws = (char*)d_ws;
    size_t off = 0;
    auto alloc = [&](size_t bytes) -> char* {
        char* p = ws + off;
        off = (off + bytes + 255) & ~(size_t)255;
        return p;
    };
    u16* wtq  = (u16*)alloc(768 * 768 * 2);
    u16* wtkv = (u16*)alloc((size_t)1536 * 768 * 2);
    u16* wtoU = (u16*)alloc((size_t)768 * 832 * 2);
    u16* dT  = (u16*)alloc(768 * 64 * 2);
    u16* mdT = (u16*)alloc(768 * 64 * 2);
    u16* muT = (u16*)alloc(768 * 64 * 2);
    u16* lnZ = (u16*)alloc((size_t)2 * 4096 * 768 * 2);
    u16* lnX = (u16*)alloc((size_t)2 * 16384 * 768 * 2);
    u16* qb  = (u16*)alloc((size_t)2 * 4096 * 768 * 2);
    u16* kvb = (u16*)alloc((size_t)2 * 16384 * 1536 * 2);
    u16* aoh = (u16*)alloc((size_t)2 * 4096 * 832 * 2);
    float* aff = (float*)alloc((size_t)2 * 64 * 256 * 64 * 4);
    float* den = (float*)alloc((size_t)2 * 64 * 256 * 4);
    u64* winners = (u64*)alloc((size_t)2 * 64 * 256 * 8);
    // aliases (lifetimes disjoint by stream order):
    u16* paff = lnX;               // 2*768*64*256*2 == lnX region exactly (lnX dead after kv proj)
    if (ws_size < off) return;     // ws too small -> leave poison (diagnosable)

    // 1. weight prep; k,v stacked into wtkv; wo + lora_up stacked into wtoU (k=832)
    TPack big = {wq, wk, wv, wo, wtq, wtkv, wtkv + (size_t)768 * 768, wtoU};
    transpose_big<<<dim3(2304, 4), 256, 0, stream>>>(big);
    TPack small = {lora_down, lora_up, mlp_down, mlp_up, dT, wtoU + 768, mdT, muT};
    transpose_small<<<dim3(192, 4), 256, 0, stream>>>(small);
    hipMemsetAsync(den, 0, (size_t)2 * 64 * 256 * 4, stream);
    hipMemsetAsync(winners, 0, (size_t)2 * 64 * 256 * 8, stream);
    // 2. LN1 (wave-per-row, f4)
    ln1_kernel<<<10240, 256, 0, stream>>>(x0, x1, ln1w, ln1b, lnZ, lnX);
    // 3. q projection; fused kv projection (cross-stream via row^16384); XCD-swizzled
    gemm_bt<128, 128, 2, 2, EPI_BF16, 0><<<384, 256, 0, stream>>>(
        lnZ, wtq, 8192, 768, 768, 768, nullptr, qb, nullptr, nullptr);
    gemm_bt<128, 128, 2, 2, EPI_BF16, 16384><<<3072, 256, 0, stream>>>(
        lnX, wtkv, 32768, 1536, 768, 1536, nullptr, kvb, nullptr, nullptr);
    // 4. attention (MFMA); out -> aoh cols 0..767 (stride 832); paff over dead lnX
    attn_mfma<<<1536, 256, 0, stream>>>(qb, kvb, aoh, paff);
    // 5. fusion prep (h-sum reduce + colmax + nu/den/winners)
    fusion_prep2<<<dim3(128, 4), 256, 0, stream>>>(paff, aff, den, winners);
    // 6. lora-z down (gelu, row^4096) -> aoh cols 768..831; merged (wo|up) GEMM + resid
    gemm_bt<128, 64, 2, 1, EPI_GELU, 4096><<<64, 128, 0, stream>>>(
        lnZ, dT, 8192, 64, 768, 832, nullptr, aoh + 768, nullptr, nullptr);
    gemm_bt<128, 128, 2, 2, EPI_RESID_Z, 0><<<384, 256, 0, stream>>>(
        aoh, wtoU, 8192, 768, 832, 768, out, nullptr, x0, x1);
    // 7. fusion apply (x rows only; z rows already final in out)
    fusion_apply_x<<<32768, 192, 0, stream>>>(x0, x1, aff, den, winners, out);
    // 8. fused LN2 + mlp lora (in-place on out)
    ln2_mlp<<<1280, 256, 0, stream>>>(out, ln2w, ln2b, mdT, muT);
}